// Round 1
// baseline (1818.497 us; speedup 1.0000x reference)
//
#include <hip/hip_runtime.h>
#include <math.h>

// ---- problem constants ----
#define NB    2
#define HHH   64
#define WWW   128
#define F1    123      // 117 + 6
#define HC    512      // heads*hid
#define NE    131072
#define PB    8194     // nodes per batch (8192 + 2 poles)
#define NNODE (NB*PB)  // 16388
#define NPOS  (NB*HHH*WWW) // 16384
#define TGT   39
#define EMBED 128
#define KCONV 4608     // 512*9

static inline int ceildiv(int a, int b){ return (a + b - 1) / b; }

__device__ __forceinline__ float leakyf(float x, float s){ return x >= 0.f ? x : s * x; }

// ---------------- build node features ----------------
__global__ void k_build_nodes(const float* __restrict__ x, const float* __restrict__ xc,
                              float* __restrict__ nodes) {
  int idx = blockIdx.x * blockDim.x + threadIdx.x;
  if (idx >= NNODE * F1) return;
  int node = idx / F1, c = idx - node * F1;
  int b = node / PB, loc = node - b * PB;
  float v = 0.f;
  if (loc >= 2) {
    int p = loc - 2;
    v = (c < 117) ? x[((size_t)(b * 117 + c)) * 8192 + p]
                  : xc[((size_t)(b * 6 + (c - 117))) * 8192 + p];
  }
  nodes[idx] = v;
}

// ---------------- CSR build ----------------
__global__ void k_hist(const int* __restrict__ dst, int* __restrict__ cnt) {
  int e = blockIdx.x * blockDim.x + threadIdx.x;
  if (e >= NE) return;
  atomicAdd(&cnt[dst[e]], 1);
}

__global__ void k_scan(const int* __restrict__ cnt, int* __restrict__ rowptr, int n) {
  __shared__ int part[512];
  int t = threadIdx.x;
  int chunk = (n + 511) >> 9;
  int beg = t * chunk, end = min(beg + chunk, n);
  int s = 0;
  for (int i = beg; i < end; i++) s += cnt[i];
  part[t] = s;
  __syncthreads();
  int own = s;
  for (int off = 1; off < 512; off <<= 1) {
    int v = 0;
    if (t >= off) v = part[t - off];
    __syncthreads();
    part[t] += v;
    __syncthreads();
  }
  int run = part[t] - own;   // exclusive prefix
  for (int i = beg; i < end; i++) { rowptr[i] = run; run += cnt[i]; }
  if (t == 511) rowptr[n] = part[511];
}

__global__ void k_copy_int(const int* __restrict__ a, int* __restrict__ b, int n) {
  int i = blockIdx.x * blockDim.x + threadIdx.x;
  if (i < n) b[i] = a[i];
}

__global__ void k_scatter(const int* __restrict__ dst, int* __restrict__ cursor,
                          int* __restrict__ colidx) {
  int e = blockIdx.x * blockDim.x + threadIdx.x;
  if (e >= NE) return;
  int pos = atomicAdd(&cursor[dst[e]], 1);
  colidx[pos] = e;
}

// loop_attr[n][k] = mean over incoming edges of edge_attr (0-safe divide)
__global__ void k_loop_attr(const float* __restrict__ eattr, const int* __restrict__ rowptr,
                            const int* __restrict__ colidx, float* __restrict__ lattr) {
  int idx = blockIdx.x * blockDim.x + threadIdx.x;
  if (idx >= NNODE * 8) return;
  int nn = idx >> 3, k = idx & 7;
  int b = rowptr[nn], e = rowptr[nn + 1];
  float s = 0.f;
  for (int i = b; i < e; i++) s += eattr[(size_t)colidx[i] * 8 + k];
  int c = e - b;
  lattr[idx] = s / (float)max(c, 1);
}

// ---------------- edge attention precompute ----------------
// M[k*4+h] = sum_c W_edge[k, h*128+c] * att_edge[h,c]
__global__ void k_medge(const float* __restrict__ We, const float* __restrict__ ae,
                        float* __restrict__ M) {
  int t = threadIdx.x;
  if (t >= 32) return;
  int k = t >> 2, h = t & 3;
  float s = 0.f;
  for (int c = 0; c < 128; c++) s += We[k * 512 + h * 128 + c] * ae[h * 128 + c];
  M[t] = s;
}

// out[e*4+h] = attr[e,:8] . M[:,h]
__global__ void k_aedge(const float* __restrict__ attr, const float* __restrict__ M,
                        float* __restrict__ out, int n) {
  int idx = blockIdx.x * blockDim.x + threadIdx.x;
  if (idx >= n * 4) return;
  int e = idx >> 2, h = idx & 3;
  float s = 0.f;
#pragma unroll
  for (int k = 0; k < 8; k++) s += attr[(size_t)e * 8 + k] * M[k * 4 + h];
  out[idx] = s;
}

// a_src[n,h] = xp[n,h,:].att_src[h,:];  a_dst likewise — one wave per node
__global__ void k_attn_dots(const float* __restrict__ xp, const float* __restrict__ as,
                            const float* __restrict__ ad, float* __restrict__ a_src,
                            float* __restrict__ a_dst) {
  int gw = (blockIdx.x * blockDim.x + threadIdx.x) >> 6;
  int lane = threadIdx.x & 63;
  if (gw >= NNODE) return;
  int h = lane >> 4;
  int c0 = (lane & 15) * 8;
  const float* xr = xp + (size_t)gw * HC + h * 128 + c0;
  const float* asr = as + h * 128 + c0;
  const float* adr = ad + h * 128 + c0;
  float s1 = 0.f, s2 = 0.f;
#pragma unroll
  for (int i = 0; i < 8; i++) { float v = xr[i]; s1 += v * asr[i]; s2 += v * adr[i]; }
  for (int off = 1; off < 16; off <<= 1) { s1 += __shfl_xor(s1, off); s2 += __shfl_xor(s2, off); }
  if ((lane & 15) == 0) { a_src[gw * 4 + h] = s1; a_dst[gw * 4 + h] = s2; }
}

// ---------------- GAT aggregation: per-node online softmax + message sum ----------------
__global__ __launch_bounds__(256) void k_aggregate(
    const float* __restrict__ xp, const float* __restrict__ a_src,
    const float* __restrict__ a_dst, const float* __restrict__ a_edge,
    const float* __restrict__ a_eloop, const int* __restrict__ srcv,
    const int* __restrict__ rowptr, const int* __restrict__ colidx,
    const float* __restrict__ bias, float* __restrict__ outp) {
  int n = blockIdx.x;
  int tid = threadIdx.x;
  __shared__ float sh_w[64][4];
  __shared__ int   sh_s[64];
  __shared__ float sh_m[4], sh_l[4], sh_r[4];
  int beg = rowptr[n], deg = rowptr[n + 1] - beg;
  int total = deg + 1;  // + self loop
  if (tid < 4) { sh_m[tid] = -1e30f; sh_l[tid] = 0.f; }
  float acc0 = 0.f, acc1 = 0.f;
  int c0 = tid, c1 = tid + 256;
  int h0 = tid >> 7, h1 = 2 + h0;
  __syncthreads();
  for (int base = 0; base < total; base += 64) {
    int cnt = min(64, total - base);
    if (tid < cnt * 4) {
      int le = tid >> 2, h = tid & 3;
      int ge = base + le;
      int sn; float ae;
      if (ge < deg) { int eid = colidx[beg + ge]; sn = srcv[eid]; ae = a_edge[(size_t)eid * 4 + h]; }
      else          { sn = n; ae = a_eloop[(size_t)n * 4 + h]; }
      float al = a_src[(size_t)sn * 4 + h] + a_dst[(size_t)n * 4 + h] + ae;
      al = leakyf(al, 0.2f);
      sh_w[le][h] = al;
      if (h == 0) sh_s[le] = sn;
    }
    __syncthreads();
    if (tid < 4) {
      int h = tid;
      float m = sh_m[h];
      float cm = -1e30f;
      for (int e = 0; e < cnt; e++) cm = fmaxf(cm, sh_w[e][h]);
      float nm = fmaxf(m, cm);
      float r = expf(m - nm);
      float l = sh_l[h] * r;
      for (int e = 0; e < cnt; e++) { float ex = expf(sh_w[e][h] - nm); sh_w[e][h] = ex; l += ex; }
      sh_m[h] = nm; sh_l[h] = l; sh_r[h] = r;
    }
    __syncthreads();
    acc0 *= sh_r[h0]; acc1 *= sh_r[h1];
    for (int e = 0; e < cnt; e++) {
      const float* xs = xp + (size_t)sh_s[e] * HC;
      acc0 += xs[c0] * sh_w[e][h0];
      acc1 += xs[c1] * sh_w[e][h1];
    }
    __syncthreads();
  }
  float v0 = acc0 / sh_l[h0] + bias[c0];
  float v1 = acc1 / sh_l[h1] + bias[c1];
  outp[(size_t)n * HC + c0] = leakyf(v0, 0.01f);
  outp[(size_t)n * HC + c1] = leakyf(v1, 0.01f);
}

// ---------------- conv weight reorder: W2[(off*512+c)*128+n] = w[n,c,di,dj] ----------------
__global__ void k_reorder_w(const float* __restrict__ w, float* __restrict__ w2) {
  int idx = blockIdx.x * blockDim.x + threadIdx.x;
  if (idx >= KCONV * EMBED) return;
  int n = idx & 127;
  int k = idx >> 7;
  int offt = k >> 9, c = k & 511;
  w2[idx] = w[(size_t)n * KCONV + c * 9 + offt];
}

// ---------------- generic tiled fp32 GEMM ----------------
// MODE 0: A1 row-major [M, lda1]
// MODE 1: MLP1 — A cols < K1 from A1 with node row remap (r -> r+2+2*(r>>13)); cols >= K1 from A2
// MODE 2: conv implicit im2col — A1 = h2 node features; k = (tap<<9)|c
template <int MODE>
__device__ __forceinline__ float loadA(const float* __restrict__ A1, int lda1,
                                       const float* __restrict__ A2, int lda2,
                                       int K1, int r, int k) {
  if constexpr (MODE == 0) {
    return A1[(size_t)r * lda1 + k];
  } else if constexpr (MODE == 1) {
    if (k < K1) {
      int rr = r + 2 + ((r >> 13) << 1);
      return A1[(size_t)rr * lda1 + k];
    }
    return A2[(size_t)r * lda2 + (k - K1)];
  } else {
    int offt = k >> 9, c = k & 511;
    int di = offt / 3, dj = offt - di * 3;
    int b = r >> 13, pos = r & 8191;
    int i = pos >> 7, j = pos & 127;
    int rr = i + di, cc = j + dj;
    int gr, gc;
    if (rr == 0)       { gr = 1;      gc = (63 + cc) & 127; }
    else if (rr == 65) { gr = 62;     gc = (63 + cc) & 127; }
    else               { gr = rr - 1; gc = (cc + 127) & 127; }
    int node = b * PB + 2 + gr * WWW + gc;
    return A1[(size_t)node * HC + c];
  }
}

template <int MODE>
__global__ __launch_bounds__(256) void gemm_k(
    int M, int N, int K, int K1,
    const float* __restrict__ A1, int lda1,
    const float* __restrict__ A2, int lda2,
    const float* __restrict__ B,
    const float* __restrict__ bias,
    const float* __restrict__ bnscale,
    const float* __restrict__ bnshift,
    float slope,
    float* __restrict__ C, int ldc) {
  __shared__ float As[16][65];
  __shared__ float Bs[16][65];
  int tid = threadIdx.x;
  int row0 = blockIdx.y * 64;
  int col0 = blockIdx.x * 64;
  float acc[4][4] = {};
  int tx = tid & 15, ty = tid >> 4;
  int am = tid >> 2;           // A row within tile
  int ak = (tid & 3) * 4;      // A k within tile (4 consecutive)
  int bk = tid >> 4;           // B k within tile
  int bn = (tid & 15) * 4;     // B n within tile (4 consecutive)
  for (int k0 = 0; k0 < K; k0 += 16) {
    {
      int r = row0 + am;
#pragma unroll
      for (int i = 0; i < 4; i++) {
        int k = k0 + ak + i;
        float v = 0.f;
        if (r < M && k < K) v = loadA<MODE>(A1, lda1, A2, lda2, K1, r, k);
        As[ak + i][am] = v;
      }
    }
    {
#pragma unroll
      for (int i = 0; i < 4; i++) {
        int k = k0 + bk;
        int n = col0 + bn + i;
        float v = 0.f;
        if (k < K && n < N) v = B[(size_t)k * N + n];
        Bs[bk][bn + i] = v;
      }
    }
    __syncthreads();
#pragma unroll
    for (int kk = 0; kk < 16; kk++) {
      float a[4], b[4];
#pragma unroll
      for (int i = 0; i < 4; i++) a[i] = As[kk][ty * 4 + i];
#pragma unroll
      for (int j = 0; j < 4; j++) b[j] = Bs[kk][tx * 4 + j];
#pragma unroll
      for (int i = 0; i < 4; i++)
#pragma unroll
        for (int j = 0; j < 4; j++)
          acc[i][j] += a[i] * b[j];
    }
    __syncthreads();
  }
#pragma unroll
  for (int i = 0; i < 4; i++) {
    int r = row0 + ty * 4 + i;
    if (r >= M) continue;
#pragma unroll
    for (int j = 0; j < 4; j++) {
      int n = col0 + tx * 4 + j;
      if (n >= N) continue;
      float v = acc[i][j];
      if (bias) v += bias[n];
      if (bnscale) v = v * (bnscale[n] * rsqrtf(1.f + 1e-5f)) + bnshift[n];
      v = leakyf(v, slope);
      C[(size_t)r * ldc + n] = v;
    }
  }
}

// ---------------- final: out[b,t,i,j] = z3[(b*8192+p), t] + x[b, 78+t, p] ----------------
__global__ void k_final(const float* __restrict__ z3, const float* __restrict__ x,
                        float* __restrict__ outp) {
  int idx = blockIdx.x * blockDim.x + threadIdx.x;
  if (idx >= NPOS * TGT) return;
  int b = idx / (TGT * 8192);
  int rem = idx - b * (TGT * 8192);
  int t = rem >> 13;
  int p = rem & 8191;
  outp[idx] = z3[((size_t)(b * 8192 + p)) * TGT + t] + x[((size_t)(b * 117 + 78 + t)) * 8192 + p];
}

// ================================================================
extern "C" void kernel_launch(void* const* d_in, const int* in_sizes, int n_in,
                              void* d_out, int out_size, void* d_ws, size_t ws_size,
                              hipStream_t stream) {
  const float* x     = (const float*)d_in[0];
  const float* xcons = (const float*)d_in[1];
  const int*   eidx  = (const int*)d_in[2];
  const float* eattr = (const float*)d_in[3];
  const float* g1W  = (const float*)d_in[4];
  const float* g1as = (const float*)d_in[5];
  const float* g1ad = (const float*)d_in[6];
  const float* g1We = (const float*)d_in[7];
  const float* g1ae = (const float*)d_in[8];
  const float* g1b  = (const float*)d_in[9];
  const float* g2W  = (const float*)d_in[10];
  const float* g2as = (const float*)d_in[11];
  const float* g2ad = (const float*)d_in[12];
  const float* g2We = (const float*)d_in[13];
  const float* g2ae = (const float*)d_in[14];
  const float* g2b  = (const float*)d_in[15];
  const float* convw= (const float*)d_in[16];
  const float* convb= (const float*)d_in[17];
  const float* bng  = (const float*)d_in[18];
  const float* bnb  = (const float*)d_in[19];
  const float* mw1  = (const float*)d_in[20];
  const float* mb1  = (const float*)d_in[21];
  const float* mw2  = (const float*)d_in[22];
  const float* mb2  = (const float*)d_in[23];
  const float* mw3  = (const float*)d_in[24];
  const float* mb3  = (const float*)d_in[25];
  float* outp = (float*)d_out;
  (void)in_sizes; (void)n_in; (void)out_size; (void)ws_size;

  const int* esrc = eidx;
  const int* edst = eidx + NE;

  char* basep = (char*)d_ws;
  size_t off = 0;
  auto alloc = [&](size_t bytes) -> void* {
    void* p = basep + off;
    off += (bytes + 255) & ~(size_t)255;
    return p;
  };
  float* nodes  = (float*)alloc((size_t)NNODE * F1 * sizeof(float));
  float* xp     = (float*)alloc((size_t)NNODE * HC * sizeof(float));
  float* h1     = (float*)alloc((size_t)NNODE * HC * sizeof(float));
  float* h2     = (float*)alloc((size_t)NNODE * HC * sizeof(float));
  float* asrc   = (float*)alloc((size_t)NNODE * 4 * sizeof(float));
  float* adst   = (float*)alloc((size_t)NNODE * 4 * sizeof(float));
  float* aedge  = (float*)alloc((size_t)NE * 4 * sizeof(float));
  float* aeloop = (float*)alloc((size_t)NNODE * 4 * sizeof(float));
  float* lattr  = (float*)alloc((size_t)NNODE * 8 * sizeof(float));
  float* Medge  = (float*)alloc(32 * sizeof(float));
  float* convo  = (float*)alloc((size_t)NPOS * EMBED * sizeof(float));
  float* w2c    = (float*)alloc((size_t)KCONV * EMBED * sizeof(float));
  int* cnt      = (int*)alloc((size_t)NNODE * sizeof(int));
  int* rowptr   = (int*)alloc((size_t)(NNODE + 1) * sizeof(int));
  int* cursor   = (int*)alloc((size_t)NNODE * sizeof(int));
  int* colidx   = (int*)alloc((size_t)NE * sizeof(int));
  float* z1 = xp;     // reuse: xp dead after layer-2 aggregation
  float* z2 = h1;     // reuse: h1 dead after layer-2 xp GEMM
  float* z3 = nodes;  // reuse: nodes dead after layer-1 xp GEMM

  hipMemsetAsync(cnt, 0, NNODE * sizeof(int), stream);
  k_build_nodes<<<ceildiv(NNODE * F1, 256), 256, 0, stream>>>(x, xcons, nodes);
  k_hist<<<ceildiv(NE, 256), 256, 0, stream>>>(edst, cnt);
  k_scan<<<1, 512, 0, stream>>>(cnt, rowptr, NNODE);
  k_copy_int<<<ceildiv(NNODE, 256), 256, 0, stream>>>(rowptr, cursor, NNODE);
  k_scatter<<<ceildiv(NE, 256), 256, 0, stream>>>(edst, cursor, colidx);
  k_loop_attr<<<ceildiv(NNODE * 8, 256), 256, 0, stream>>>(eattr, rowptr, colidx, lattr);

  // ---- GAT layer 1 ----
  k_medge<<<1, 64, 0, stream>>>(g1We, g1ae, Medge);
  k_aedge<<<ceildiv(NE * 4, 256), 256, 0, stream>>>(eattr, Medge, aedge, NE);
  k_aedge<<<ceildiv(NNODE * 4, 256), 256, 0, stream>>>(lattr, Medge, aeloop, NNODE);
  {
    dim3 g(ceildiv(HC, 64), ceildiv(NNODE, 64));
    gemm_k<0><<<g, 256, 0, stream>>>(NNODE, HC, F1, 0, nodes, F1, nullptr, 0, g1W,
                                     nullptr, nullptr, nullptr, 1.0f, xp, HC);
  }
  k_attn_dots<<<ceildiv(NNODE, 4), 256, 0, stream>>>(xp, g1as, g1ad, asrc, adst);
  k_aggregate<<<NNODE, 256, 0, stream>>>(xp, asrc, adst, aedge, aeloop, esrc, rowptr,
                                         colidx, g1b, h1);

  // ---- GAT layer 2 ----
  k_medge<<<1, 64, 0, stream>>>(g2We, g2ae, Medge);
  k_aedge<<<ceildiv(NE * 4, 256), 256, 0, stream>>>(eattr, Medge, aedge, NE);
  k_aedge<<<ceildiv(NNODE * 4, 256), 256, 0, stream>>>(lattr, Medge, aeloop, NNODE);
  {
    dim3 g(ceildiv(HC, 64), ceildiv(NNODE, 64));
    gemm_k<0><<<g, 256, 0, stream>>>(NNODE, HC, HC, 0, h1, HC, nullptr, 0, g2W,
                                     nullptr, nullptr, nullptr, 1.0f, xp, HC);
  }
  k_attn_dots<<<ceildiv(NNODE, 4), 256, 0, stream>>>(xp, g2as, g2ad, asrc, adst);
  k_aggregate<<<NNODE, 256, 0, stream>>>(xp, asrc, adst, aedge, aeloop, esrc, rowptr,
                                         colidx, g2b, h2);

  // ---- conv (implicit im2col GEMM) + BN + leaky ----
  k_reorder_w<<<ceildiv(KCONV * EMBED, 256), 256, 0, stream>>>(convw, w2c);
  {
    dim3 g(ceildiv(EMBED, 64), ceildiv(NPOS, 64));
    gemm_k<2><<<g, 256, 0, stream>>>(NPOS, EMBED, KCONV, 0, h2, HC, nullptr, 0, w2c,
                                     convb, bng, bnb, 0.01f, convo, EMBED);
  }

  // ---- MLP ----
  {
    dim3 g(ceildiv(512, 64), ceildiv(NPOS, 64));
    gemm_k<1><<<g, 256, 0, stream>>>(NPOS, 512, 640, 512, h2, HC, convo, EMBED, mw1,
                                     mb1, nullptr, nullptr, 0.01f, z1, 512);
  }
  {
    dim3 g(ceildiv(256, 64), ceildiv(NPOS, 64));
    gemm_k<0><<<g, 256, 0, stream>>>(NPOS, 256, 512, 0, z1, 512, nullptr, 0, mw2,
                                     mb2, nullptr, nullptr, 0.01f, z2, 256);
  }
  {
    dim3 g(ceildiv(TGT, 64), ceildiv(NPOS, 64));
    gemm_k<0><<<g, 256, 0, stream>>>(NPOS, TGT, 256, 0, z2, 256, nullptr, 0, mw3,
                                     mb3, nullptr, nullptr, 1.0f, z3, TGT);
  }

  k_final<<<ceildiv(NPOS * TGT, 256), 256, 0, stream>>>(z3, x, outp);
}

// Round 3
// 528.075 us; speedup vs baseline: 3.4436x; 3.4436x over previous
//
#include <hip/hip_runtime.h>
#include <math.h>
#include <type_traits>

// ---- problem constants ----
#define NB    2
#define HHH   64
#define WWW   128
#define F1    123      // 117 + 6
#define HC    512      // heads*hid
#define NE    131072
#define PB    8194     // nodes per batch (8192 + 2 poles)
#define NNODE (NB*PB)  // 16388
#define NPOS  (NB*HHH*WWW) // 16384
#define TGT   39
#define EMBED 128
#define KCONV 4608     // 512*9
#define LMROWS (2*66*130)

static inline int ceildiv(int a, int b){ return (a + b - 1) / b; }

typedef short v8s __attribute__((ext_vector_type(8)));
typedef float v4f __attribute__((ext_vector_type(4)));

__device__ __forceinline__ float leakyf(float x, float s){ return x >= 0.f ? x : s * x; }

__device__ __forceinline__ unsigned short f2b(float f) {
  unsigned u = __builtin_bit_cast(unsigned, f);
  u = (u + 0x7FFFu + ((u >> 16) & 1u)) >> 16;
  return (unsigned short)u;
}
__device__ __forceinline__ float b2f(unsigned short h) {
  unsigned u = ((unsigned)h) << 16;
  return __builtin_bit_cast(float, u);
}

// ---------------- build node features (bf16, K padded 123->128) ----------------
__global__ void k_build_nodes(const float* __restrict__ x, const float* __restrict__ xc,
                              unsigned short* __restrict__ nodes) {
  int idx = blockIdx.x * blockDim.x + threadIdx.x;
  if (idx >= NNODE * 128) return;
  int node = idx >> 7, c = idx & 127;
  int b = node / PB, loc = node - b * PB;
  float v = 0.f;
  if (loc >= 2 && c < F1) {
    int p = loc - 2;
    v = (c < 117) ? x[((size_t)(b * 117 + c)) * 8192 + p]
                  : xc[((size_t)(b * 6 + (c - 117))) * 8192 + p];
  }
  nodes[idx] = f2b(v);
}

// ---------------- CSR build ----------------
__global__ void k_hist(const int* __restrict__ dst, int* __restrict__ cnt) {
  int e = blockIdx.x * blockDim.x + threadIdx.x;
  if (e >= NE) return;
  atomicAdd(&cnt[dst[e]], 1);
}

__global__ void k_scan(const int* __restrict__ cnt, int* __restrict__ rowptr, int n) {
  __shared__ int part[512];
  int t = threadIdx.x;
  int chunk = (n + 511) >> 9;
  int beg = t * chunk, end = min(beg + chunk, n);
  int s = 0;
  for (int i = beg; i < end; i++) s += cnt[i];
  part[t] = s;
  __syncthreads();
  int own = s;
  for (int off = 1; off < 512; off <<= 1) {
    int v = 0;
    if (t >= off) v = part[t - off];
    __syncthreads();
    part[t] += v;
    __syncthreads();
  }
  int run = part[t] - own;   // exclusive prefix
  for (int i = beg; i < end; i++) { rowptr[i] = run; run += cnt[i]; }
  if (t == 511) rowptr[n] = part[511];
}

__global__ void k_copy_int(const int* __restrict__ a, int* __restrict__ b, int n) {
  int i = blockIdx.x * blockDim.x + threadIdx.x;
  if (i < n) b[i] = a[i];
}

__global__ void k_scatter(const int* __restrict__ dst, int* __restrict__ cursor,
                          int* __restrict__ colidx) {
  int e = blockIdx.x * blockDim.x + threadIdx.x;
  if (e >= NE) return;
  int pos = atomicAdd(&cursor[dst[e]], 1);
  colidx[pos] = e;
}

// loop_attr[n][k] = mean over incoming edges of edge_attr (0-safe divide)
__global__ void k_loop_attr(const float* __restrict__ eattr, const int* __restrict__ rowptr,
                            const int* __restrict__ colidx, float* __restrict__ lattr) {
  int idx = blockIdx.x * blockDim.x + threadIdx.x;
  if (idx >= NNODE * 8) return;
  int nn = idx >> 3, k = idx & 7;
  int b = rowptr[nn], e = rowptr[nn + 1];
  float s = 0.f;
  for (int i = b; i < e; i++) s += eattr[(size_t)colidx[i] * 8 + k];
  int c = e - b;
  lattr[idx] = s / (float)max(c, 1);
}

// ---------------- edge attention precompute ----------------
__global__ void k_medge(const float* __restrict__ We, const float* __restrict__ ae,
                        float* __restrict__ M) {
  int t = threadIdx.x;
  if (t >= 32) return;
  int k = t >> 2, h = t & 3;
  float s = 0.f;
  for (int c = 0; c < 128; c++) s += We[k * 512 + h * 128 + c] * ae[h * 128 + c];
  M[t] = s;
}

__global__ void k_aedge(const float* __restrict__ attr, const float* __restrict__ M,
                        float* __restrict__ out, int n) {
  int idx = blockIdx.x * blockDim.x + threadIdx.x;
  if (idx >= n * 4) return;
  int e = idx >> 2, h = idx & 3;
  float s = 0.f;
#pragma unroll
  for (int k = 0; k < 8; k++) s += attr[(size_t)e * 8 + k] * M[k * 4 + h];
  out[idx] = s;
}

// a_src[n,h] = xp[n,h,:].att_src[h,:] from bf16 xp — one wave per node
__global__ void k_attn_dots(const unsigned short* __restrict__ xp, const float* __restrict__ as,
                            const float* __restrict__ ad, float* __restrict__ a_src,
                            float* __restrict__ a_dst) {
  int gw = (blockIdx.x * blockDim.x + threadIdx.x) >> 6;
  int lane = threadIdx.x & 63;
  if (gw >= NNODE) return;
  int h = lane >> 4;
  int c0 = (lane & 15) * 8;
  const unsigned short* xr = xp + (size_t)gw * HC + h * 128 + c0;
  const float* asr = as + h * 128 + c0;
  const float* adr = ad + h * 128 + c0;
  float s1 = 0.f, s2 = 0.f;
#pragma unroll
  for (int i = 0; i < 8; i++) { float v = b2f(xr[i]); s1 += v * asr[i]; s2 += v * adr[i]; }
  for (int off = 1; off < 16; off <<= 1) { s1 += __shfl_xor(s1, off); s2 += __shfl_xor(s2, off); }
  if ((lane & 15) == 0) { a_src[gw * 4 + h] = s1; a_dst[gw * 4 + h] = s2; }
}

// ---------------- GAT aggregation: per-node online softmax + message sum ----------------
__global__ __launch_bounds__(256) void k_aggregate(
    const unsigned short* __restrict__ xp, const float* __restrict__ a_src,
    const float* __restrict__ a_dst, const float* __restrict__ a_edge,
    const float* __restrict__ a_eloop, const int* __restrict__ srcv,
    const int* __restrict__ rowptr, const int* __restrict__ colidx,
    const float* __restrict__ bias, unsigned short* __restrict__ outp) {
  int n = blockIdx.x;
  int tid = threadIdx.x;
  __shared__ float sh_w[64][4];
  __shared__ int   sh_s[64];
  __shared__ float sh_m[4], sh_l[4], sh_r[4];
  int beg = rowptr[n], deg = rowptr[n + 1] - beg;
  int total = deg + 1;  // + self loop
  if (tid < 4) { sh_m[tid] = -1e30f; sh_l[tid] = 0.f; }
  float acc0 = 0.f, acc1 = 0.f;
  int c0 = tid, c1 = tid + 256;
  int h0 = tid >> 7, h1 = 2 + h0;
  __syncthreads();
  for (int base = 0; base < total; base += 64) {
    int cnt = min(64, total - base);
    if (tid < cnt * 4) {
      int le = tid >> 2, h = tid & 3;
      int ge = base + le;
      int sn; float ae;
      if (ge < deg) { int eid = colidx[beg + ge]; sn = srcv[eid]; ae = a_edge[(size_t)eid * 4 + h]; }
      else          { sn = n; ae = a_eloop[(size_t)n * 4 + h]; }
      float al = a_src[(size_t)sn * 4 + h] + a_dst[(size_t)n * 4 + h] + ae;
      al = leakyf(al, 0.2f);
      sh_w[le][h] = al;
      if (h == 0) sh_s[le] = sn;
    }
    __syncthreads();
    if (tid < 4) {
      int h = tid;
      float m = sh_m[h];
      float cm = -1e30f;
      for (int e = 0; e < cnt; e++) cm = fmaxf(cm, sh_w[e][h]);
      float nm = fmaxf(m, cm);
      float r = expf(m - nm);
      float l = sh_l[h] * r;
      for (int e = 0; e < cnt; e++) { float ex = expf(sh_w[e][h] - nm); sh_w[e][h] = ex; l += ex; }
      sh_m[h] = nm; sh_l[h] = l; sh_r[h] = r;
    }
    __syncthreads();
    acc0 *= sh_r[h0]; acc1 *= sh_r[h1];
    for (int e = 0; e < cnt; e++) {
      const unsigned short* xs = xp + (size_t)sh_s[e] * HC;
      acc0 += b2f(xs[c0]) * sh_w[e][h0];
      acc1 += b2f(xs[c1]) * sh_w[e][h1];
    }
    __syncthreads();
  }
  float v0 = acc0 / sh_l[h0] + bias[c0];
  float v1 = acc1 / sh_l[h1] + bias[c1];
  outp[(size_t)n * HC + c0] = f2b(leakyf(v0, 0.01f));
  outp[(size_t)n * HC + c1] = f2b(leakyf(v1, 0.01f));
}

// ---------------- weight prep: Bt[n][k] = bf16(src[k*N+n]), K padded ----------------
__global__ void k_bt(const float* __restrict__ src, unsigned short* __restrict__ bt,
                     int N, int Ks, int Kd) {
  int idx = blockIdx.x * blockDim.x + threadIdx.x;
  if (idx >= N * Kd) return;
  int n = idx / Kd, k = idx - n * Kd;
  bt[idx] = (k < Ks) ? f2b(src[(size_t)k * N + n]) : (unsigned short)0;
}

// conv weights: bt[n][k], k = tap*512+c  <- convw[n][c][di][dj]
__global__ void k_convbt(const float* __restrict__ w, unsigned short* __restrict__ bt) {
  int idx = blockIdx.x * blockDim.x + threadIdx.x;
  if (idx >= EMBED * KCONV) return;
  int n = idx / KCONV, k = idx - n * KCONV;
  int tap = k >> 9, c = k & 511;
  bt[idx] = f2b(w[(size_t)n * KCONV + c * 9 + tap]);
}

// ---------------- materialize padded local map (bf16) ----------------
// lmb[b][rr][cc][c], rr in [0,66), cc in [0,130)
__global__ void k_lm(const unsigned short* __restrict__ h2, unsigned short* __restrict__ lmb) {
  int idx = blockIdx.x * blockDim.x + threadIdx.x;
  if (idx >= LMROWS * 512) return;
  int c = idx & 511;
  int prow = idx >> 9;
  int cc = prow % 130;
  int t = prow / 130;
  int rr = t % 66, b = t / 66;
  int gr, gc;
  if (rr == 0)       { gr = 1;      gc = (63 + cc) & 127; }
  else if (rr == 65) { gr = 62;     gc = (63 + cc) & 127; }
  else               { gr = rr - 1; gc = (cc + 127) & 127; }
  lmb[idx] = h2[((size_t)(b * PB + 2 + gr * WWW + gc)) * HC + c];
}

// zin[:, 0:512] = g rows (h2 without poles)
__global__ void k_zin_g(const unsigned short* __restrict__ h2, unsigned short* __restrict__ zin) {
  int idx = blockIdx.x * blockDim.x + threadIdx.x;
  if (idx >= NPOS * 512) return;
  int r = idx >> 9, c = idx & 511;
  int b = r >> 13, pos = r & 8191;
  zin[(size_t)r * 640 + c] = h2[((size_t)(b * PB + 2 + pos)) * HC + c];
}

// ---------------- bf16 MFMA GEMM ----------------
// C[M,N] = epi(A[M,K] @ B[K,N]); A bf16 row-major (or conv-implicit), Bt bf16 [N][K].
// Block: 256 threads = 4 waves in 2x2; wave tile (WM*16) x (WN*16); block tile BM x BN.
// MODE 0: A direct. MODE 1: conv — A = lmb, row for (r, tap=k>>9).
template<int MODE, int WM, int WN, typename OutT>
__global__ __launch_bounds__(256) void mgemm(
    int M, int N, int K,
    const unsigned short* __restrict__ A, int lda,
    const unsigned short* __restrict__ Bt,
    const float* __restrict__ bias,
    const float* __restrict__ bnscale, const float* __restrict__ bnshift,
    float slope,
    OutT* __restrict__ C, int ldc)
{
  constexpr int BM = WM * 32;
  constexpr int BN = WN * 32;
  constexpr int LDS_S = 40;  // padded row stride (elems) for 32-elem rows: 80B, conflict-free b128
  __shared__ unsigned short As[BM * LDS_S];
  __shared__ unsigned short Bs[BN * LDS_S];
  int tid = threadIdx.x;
  int wid = tid >> 6, lane = tid & 63;
  int wr = wid >> 1, wc = wid & 1;
  int l15 = lane & 15, l4 = lane >> 4;
  int row0 = blockIdx.y * BM, col0 = blockIdx.x * BN;
  v4f acc[WM][WN];
#pragma unroll
  for (int m = 0; m < WM; m++)
#pragma unroll
    for (int n = 0; n < WN; n++) acc[m][n] = (v4f)0.f;

  for (int k0 = 0; k0 < K; k0 += 32) {
    // stage A: BM rows x 32 elems = BM*4 16B chunks
    int tap = 0, di = 0, dj = 0;
    if constexpr (MODE == 1) { tap = k0 >> 9; di = tap / 3; dj = tap - di * 3; }
    for (int c = tid; c < BM * 4; c += 256) {
      int r = c >> 2, seg = c & 3;
      int gr = row0 + r;
      v8s v = (v8s)0;
      if (gr < M) {
        size_t off;
        if constexpr (MODE == 0) {
          off = (size_t)gr * lda + k0 + seg * 8;
        } else {
          int b = gr >> 13, pos = gr & 8191, i = pos >> 7, j = pos & 127;
          int arow = (b * 66 + i + di) * 130 + (j + dj);
          off = (size_t)arow * 512 + (k0 & 511) + seg * 8;
        }
        v = *(const v8s*)(A + off);
      }
      *(v8s*)(As + r * LDS_S + seg * 8) = v;
    }
    // stage B (Bt is [N][K] row-major)
    for (int c = tid; c < BN * 4; c += 256) {
      int r = c >> 2, seg = c & 3;
      int gn = col0 + r;
      v8s v = (v8s)0;
      if (gn < N) v = *(const v8s*)(Bt + (size_t)gn * K + k0 + seg * 8);
      *(v8s*)(Bs + r * LDS_S + seg * 8) = v;
    }
    __syncthreads();
    v8s a[WM], b[WN];
#pragma unroll
    for (int m = 0; m < WM; m++)
      a[m] = *(const v8s*)(As + (wr * WM * 16 + m * 16 + l15) * LDS_S + l4 * 8);
#pragma unroll
    for (int n = 0; n < WN; n++)
      b[n] = *(const v8s*)(Bs + (wc * WN * 16 + n * 16 + l15) * LDS_S + l4 * 8);
#pragma unroll
    for (int m = 0; m < WM; m++)
#pragma unroll
      for (int n = 0; n < WN; n++)
        acc[m][n] = __builtin_amdgcn_mfma_f32_16x16x32_bf16(a[m], b[n], acc[m][n], 0, 0, 0);
    __syncthreads();
  }
  // epilogue: C row = (lane>>4)*4 + q, col = lane&15 (m89-verified)
#pragma unroll
  for (int m = 0; m < WM; m++) {
#pragma unroll
    for (int q = 0; q < 4; q++) {
      int r = row0 + wr * WM * 16 + m * 16 + l4 * 4 + q;
      if (r >= M) continue;
#pragma unroll
      for (int n = 0; n < WN; n++) {
        int cc = col0 + wc * WN * 16 + n * 16 + l15;
        if (cc >= N) continue;
        float v = acc[m][n][q];
        if (bias) v += bias[cc];
        if (bnscale) v = v * (bnscale[cc] * rsqrtf(1.f + 1e-5f)) + bnshift[cc];
        v = leakyf(v, slope);
        if constexpr (std::is_same<OutT, float>::value) {
          C[(size_t)r * ldc + cc] = v;
        } else {
          C[(size_t)r * ldc + cc] = f2b(v);
        }
      }
    }
  }
}

// ---------------- final: out[b,t,i,j] = z3[(b*8192+p), t] + x[b, 78+t, p] ----------------
__global__ void k_final(const float* __restrict__ z3, const float* __restrict__ x,
                        float* __restrict__ outp) {
  int idx = blockIdx.x * blockDim.x + threadIdx.x;
  if (idx >= NPOS * TGT) return;
  int b = idx / (TGT * 8192);
  int rem = idx - b * (TGT * 8192);
  int t = rem >> 13;
  int p = rem & 8191;
  outp[idx] = z3[((size_t)(b * 8192 + p)) * TGT + t] + x[((size_t)(b * 117 + 78 + t)) * 8192 + p];
}

// ================================================================
extern "C" void kernel_launch(void* const* d_in, const int* in_sizes, int n_in,
                              void* d_out, int out_size, void* d_ws, size_t ws_size,
                              hipStream_t stream) {
  const float* x     = (const float*)d_in[0];
  const float* xcons = (const float*)d_in[1];
  const int*   eidx  = (const int*)d_in[2];
  const float* eattr = (const float*)d_in[3];
  const float* g1W  = (const float*)d_in[4];
  const float* g1as = (const float*)d_in[5];
  const float* g1ad = (const float*)d_in[6];
  const float* g1We = (const float*)d_in[7];
  const float* g1ae = (const float*)d_in[8];
  const float* g1b  = (const float*)d_in[9];
  const float* g2W  = (const float*)d_in[10];
  const float* g2as = (const float*)d_in[11];
  const float* g2ad = (const float*)d_in[12];
  const float* g2We = (const float*)d_in[13];
  const float* g2ae = (const float*)d_in[14];
  const float* g2b  = (const float*)d_in[15];
  const float* convw= (const float*)d_in[16];
  const float* convb= (const float*)d_in[17];
  const float* bng  = (const float*)d_in[18];
  const float* bnb  = (const float*)d_in[19];
  const float* mw1  = (const float*)d_in[20];
  const float* mb1  = (const float*)d_in[21];
  const float* mw2  = (const float*)d_in[22];
  const float* mb2  = (const float*)d_in[23];
  const float* mw3  = (const float*)d_in[24];
  const float* mb3  = (const float*)d_in[25];
  float* outp = (float*)d_out;
  (void)in_sizes; (void)n_in; (void)out_size; (void)ws_size;

  const int* esrc = eidx;
  const int* edst = eidx + NE;

  char* basep = (char*)d_ws;
  size_t off = 0;
  auto alloc = [&](size_t bytes) -> void* {
    void* p = basep + off;
    off += (bytes + 255) & ~(size_t)255;
    return p;
  };
  unsigned short* nodesb = (unsigned short*)alloc((size_t)NNODE * 128 * 2);
  unsigned short* xpb    = (unsigned short*)alloc((size_t)NNODE * HC * 2);
  unsigned short* h1b    = (unsigned short*)alloc((size_t)NNODE * HC * 2);
  unsigned short* h2b    = (unsigned short*)alloc((size_t)NNODE * HC * 2);
  unsigned short* lmb    = (unsigned short*)alloc((size_t)LMROWS * 512 * 2);
  unsigned short* zin    = (unsigned short*)alloc((size_t)NPOS * 640 * 2);
  float* asrc   = (float*)alloc((size_t)NNODE * 4 * sizeof(float));
  float* adst   = (float*)alloc((size_t)NNODE * 4 * sizeof(float));
  float* aedge  = (float*)alloc((size_t)NE * 4 * sizeof(float));
  float* aeloop = (float*)alloc((size_t)NNODE * 4 * sizeof(float));
  float* lattr  = (float*)alloc((size_t)NNODE * 8 * sizeof(float));
  float* Medge  = (float*)alloc(32 * sizeof(float));
  unsigned short* g1Wt  = (unsigned short*)alloc((size_t)512 * 128 * 2);
  unsigned short* g2Wt  = (unsigned short*)alloc((size_t)512 * 512 * 2);
  unsigned short* convWt= (unsigned short*)alloc((size_t)EMBED * KCONV * 2);
  unsigned short* mw1t  = (unsigned short*)alloc((size_t)512 * 640 * 2);
  unsigned short* mw2t  = (unsigned short*)alloc((size_t)256 * 512 * 2);
  unsigned short* mw3t  = (unsigned short*)alloc((size_t)TGT * 256 * 2);
  int* cnt      = (int*)alloc((size_t)NNODE * sizeof(int));
  int* rowptr   = (int*)alloc((size_t)(NNODE + 1) * sizeof(int));
  int* cursor   = (int*)alloc((size_t)NNODE * sizeof(int));
  int* colidx   = (int*)alloc((size_t)NE * sizeof(int));
  unsigned short* z1b = xpb;             // xpb dead after GAT2 aggregation
  unsigned short* z2b = h1b;             // h1b dead after GAT2 xp GEMM
  float*          z3  = (float*)nodesb;  // nodesb dead after GAT1 xp GEMM

  hipMemsetAsync(cnt, 0, NNODE * sizeof(int), stream);
  k_build_nodes<<<ceildiv(NNODE * 128, 256), 256, 0, stream>>>(x, xcons, nodesb);
  k_hist<<<ceildiv(NE, 256), 256, 0, stream>>>(edst, cnt);
  k_scan<<<1, 512, 0, stream>>>(cnt, rowptr, NNODE);
  k_copy_int<<<ceildiv(NNODE, 256), 256, 0, stream>>>(rowptr, cursor, NNODE);
  k_scatter<<<ceildiv(NE, 256), 256, 0, stream>>>(edst, cursor, colidx);
  k_loop_attr<<<ceildiv(NNODE * 8, 256), 256, 0, stream>>>(eattr, rowptr, colidx, lattr);

  // weight prep
  k_bt<<<ceildiv(512 * 128, 256), 256, 0, stream>>>(g1W, g1Wt, 512, F1, 128);
  k_bt<<<ceildiv(512 * 512, 256), 256, 0, stream>>>(g2W, g2Wt, 512, 512, 512);
  k_convbt<<<ceildiv(EMBED * KCONV, 256), 256, 0, stream>>>(convw, convWt);
  k_bt<<<ceildiv(512 * 640, 256), 256, 0, stream>>>(mw1, mw1t, 512, 640, 640);
  k_bt<<<ceildiv(256 * 512, 256), 256, 0, stream>>>(mw2, mw2t, 256, 512, 512);
  k_bt<<<ceildiv(TGT * 256, 256), 256, 0, stream>>>(mw3, mw3t, TGT, 256, 256);

  // ---- GAT layer 1 ----
  k_medge<<<1, 64, 0, stream>>>(g1We, g1ae, Medge);
  k_aedge<<<ceildiv(NE * 4, 256), 256, 0, stream>>>(eattr, Medge, aedge, NE);
  k_aedge<<<ceildiv(NNODE * 4, 256), 256, 0, stream>>>(lattr, Medge, aeloop, NNODE);
  {
    dim3 g(4, ceildiv(NNODE, 128));
    mgemm<0, 4, 4, unsigned short><<<g, 256, 0, stream>>>(
        NNODE, HC, 128, nodesb, 128, g1Wt, nullptr, nullptr, nullptr, 1.0f, xpb, HC);
  }
  k_attn_dots<<<ceildiv(NNODE, 4), 256, 0, stream>>>(xpb, g1as, g1ad, asrc, adst);
  k_aggregate<<<NNODE, 256, 0, stream>>>(xpb, asrc, adst, aedge, aeloop, esrc, rowptr,
                                         colidx, g1b, h1b);

  // ---- GAT layer 2 ----
  k_medge<<<1, 64, 0, stream>>>(g2We, g2ae, Medge);
  k_aedge<<<ceildiv(NE * 4, 256), 256, 0, stream>>>(eattr, Medge, aedge, NE);
  k_aedge<<<ceildiv(NNODE * 4, 256), 256, 0, stream>>>(lattr, Medge, aeloop, NNODE);
  {
    dim3 g(4, ceildiv(NNODE, 128));
    mgemm<0, 4, 4, unsigned short><<<g, 256, 0, stream>>>(
        NNODE, HC, HC, h1b, HC, g2Wt, nullptr, nullptr, nullptr, 1.0f, xpb, HC);
  }
  k_attn_dots<<<ceildiv(NNODE, 4), 256, 0, stream>>>(xpb, g2as, g2ad, asrc, adst);
  k_aggregate<<<NNODE, 256, 0, stream>>>(xpb, asrc, adst, aedge, aeloop, esrc, rowptr,
                                         colidx, g2b, h2b);

  // ---- conv: materialize padded local map, implicit-GEMM + BN + leaky into zin[:,512:640]
  k_lm<<<ceildiv(LMROWS * 512, 256), 256, 0, stream>>>(h2b, lmb);
  k_zin_g<<<ceildiv(NPOS * 512, 256), 256, 0, stream>>>(h2b, zin);
  {
    dim3 g(1, ceildiv(NPOS, 64));   // BM=64, BN=128 -> 256 blocks
    mgemm<1, 2, 4, unsigned short><<<g, 256, 0, stream>>>(
        NPOS, EMBED, KCONV, lmb, 512, convWt, convb, bng, bnb, 0.01f, zin + 512, 640);
  }

  // ---- MLP ----
  {
    dim3 g(4, ceildiv(NPOS, 128));
    mgemm<0, 4, 4, unsigned short><<<g, 256, 0, stream>>>(
        NPOS, 512, 640, zin, 640, mw1t, mb1, nullptr, nullptr, 0.01f, z1b, 512);
  }
  {
    dim3 g(2, ceildiv(NPOS, 128));
    mgemm<0, 4, 4, unsigned short><<<g, 256, 0, stream>>>(
        NPOS, 256, 512, z1b, 512, mw2t, mb2, nullptr, nullptr, 0.01f, z2b, 256);
  }
  {
    dim3 g(1, ceildiv(NPOS, 128));
    mgemm<0, 4, 2, float><<<g, 256, 0, stream>>>(
        NPOS, TGT, 256, z2b, 256, mw3t, mb3, nullptr, nullptr, 1.0f, z3, TGT);
  }

  k_final<<<ceildiv(NPOS * TGT, 256), 256, 0, stream>>>(z3, x, outp);
}

// Round 4
// 421.494 us; speedup vs baseline: 4.3144x; 1.2529x over previous
//
#include <hip/hip_runtime.h>
#include <math.h>
#include <type_traits>

// ---- problem constants ----
#define NB    2
#define HHH   64
#define WWW   128
#define F1    123      // 117 + 6
#define HC    512      // heads*hid
#define NE    131072
#define PB    8194     // nodes per batch (8192 + 2 poles)
#define NNODE (NB*PB)  // 16388
#define NPOS  (NB*HHH*WWW) // 16384
#define TGT   39
#define EMBED 128
#define KCONV 4608     // 512*9
#define LMROWS (2*66*130)

static inline int ceildiv(int a, int b){ return (a + b - 1) / b; }

typedef short v8s __attribute__((ext_vector_type(8)));
typedef float v4f __attribute__((ext_vector_type(4)));

__device__ __forceinline__ float leakyf(float x, float s){ return x >= 0.f ? x : s * x; }

__device__ __forceinline__ unsigned short f2b(float f) {
  unsigned u = __builtin_bit_cast(unsigned, f);
  u = (u + 0x7FFFu + ((u >> 16) & 1u)) >> 16;
  return (unsigned short)u;
}
__device__ __forceinline__ float b2f(unsigned short h) {
  unsigned u = ((unsigned)h) << 16;
  return __builtin_bit_cast(float, u);
}

// async global->LDS, 16 bytes per lane (dest = wave-uniform base + lane*16)
__device__ __forceinline__ void gload_lds16(const void* g, void* l) {
  __builtin_amdgcn_global_load_lds((const __attribute__((address_space(1))) void*)g,
                                   (__attribute__((address_space(3))) void*)l, 16, 0, 0);
}

// ---------------- build node features (bf16, K padded 123->128) ----------------
__global__ void k_build_nodes(const float* __restrict__ x, const float* __restrict__ xc,
                              unsigned short* __restrict__ nodes) {
  int idx = blockIdx.x * blockDim.x + threadIdx.x;
  if (idx >= NNODE * 128) return;
  int node = idx >> 7, c = idx & 127;
  int b = node / PB, loc = node - b * PB;
  float v = 0.f;
  if (loc >= 2 && c < F1) {
    int p = loc - 2;
    v = (c < 117) ? x[((size_t)(b * 117 + c)) * 8192 + p]
                  : xc[((size_t)(b * 6 + (c - 117))) * 8192 + p];
  }
  nodes[idx] = f2b(v);
}

// ---------------- CSR build ----------------
__global__ void k_hist(const int* __restrict__ dst, int* __restrict__ cnt) {
  int e = blockIdx.x * blockDim.x + threadIdx.x;
  if (e >= NE) return;
  atomicAdd(&cnt[dst[e]], 1);
}

__global__ void k_scan(const int* __restrict__ cnt, int* __restrict__ rowptr, int n) {
  __shared__ int part[512];
  int t = threadIdx.x;
  int chunk = (n + 511) >> 9;
  int beg = t * chunk, end = min(beg + chunk, n);
  int s = 0;
  for (int i = beg; i < end; i++) s += cnt[i];
  part[t] = s;
  __syncthreads();
  int own = s;
  for (int off = 1; off < 512; off <<= 1) {
    int v = 0;
    if (t >= off) v = part[t - off];
    __syncthreads();
    part[t] += v;
    __syncthreads();
  }
  int run = part[t] - own;   // exclusive prefix
  for (int i = beg; i < end; i++) { rowptr[i] = run; run += cnt[i]; }
  if (t == 511) rowptr[n] = part[511];
}

__global__ void k_copy_int(const int* __restrict__ a, int* __restrict__ b, int n) {
  int i = blockIdx.x * blockDim.x + threadIdx.x;
  if (i < n) b[i] = a[i];
}

__global__ void k_scatter(const int* __restrict__ dst, int* __restrict__ cursor,
                          int* __restrict__ colidx) {
  int e = blockIdx.x * blockDim.x + threadIdx.x;
  if (e >= NE) return;
  int pos = atomicAdd(&cursor[dst[e]], 1);
  colidx[pos] = e;
}

// loop_attr[n][k] = mean over incoming edges of edge_attr (0-safe divide)
__global__ void k_loop_attr(const float* __restrict__ eattr, const int* __restrict__ rowptr,
                            const int* __restrict__ colidx, float* __restrict__ lattr) {
  int idx = blockIdx.x * blockDim.x + threadIdx.x;
  if (idx >= NNODE * 8) return;
  int nn = idx >> 3, k = idx & 7;
  int b = rowptr[nn], e = rowptr[nn + 1];
  float s = 0.f;
  for (int i = b; i < e; i++) s += eattr[(size_t)colidx[i] * 8 + k];
  int c = e - b;
  lattr[idx] = s / (float)max(c, 1);
}

// ---------------- edge attention precompute ----------------
__global__ void k_medge(const float* __restrict__ We, const float* __restrict__ ae,
                        float* __restrict__ M) {
  int t = threadIdx.x;
  if (t >= 32) return;
  int k = t >> 2, h = t & 3;
  float s = 0.f;
  for (int c = 0; c < 128; c++) s += We[k * 512 + h * 128 + c] * ae[h * 128 + c];
  M[t] = s;
}

__global__ void k_aedge(const float* __restrict__ attr, const float* __restrict__ M,
                        float* __restrict__ out, int n) {
  int idx = blockIdx.x * blockDim.x + threadIdx.x;
  if (idx >= n * 4) return;
  int e = idx >> 2, h = idx & 3;
  float s = 0.f;
#pragma unroll
  for (int k = 0; k < 8; k++) s += attr[(size_t)e * 8 + k] * M[k * 4 + h];
  out[idx] = s;
}

// a_src[n,h] = xp[n,h,:].att_src[h,:] from bf16 xp — one wave per node
__global__ void k_attn_dots(const unsigned short* __restrict__ xp, const float* __restrict__ as,
                            const float* __restrict__ ad, float* __restrict__ a_src,
                            float* __restrict__ a_dst) {
  int gw = (blockIdx.x * blockDim.x + threadIdx.x) >> 6;
  int lane = threadIdx.x & 63;
  if (gw >= NNODE) return;
  int h = lane >> 4;
  int c0 = (lane & 15) * 8;
  const unsigned short* xr = xp + (size_t)gw * HC + h * 128 + c0;
  const float* asr = as + h * 128 + c0;
  const float* adr = ad + h * 128 + c0;
  float s1 = 0.f, s2 = 0.f;
#pragma unroll
  for (int i = 0; i < 8; i++) { float v = b2f(xr[i]); s1 += v * asr[i]; s2 += v * adr[i]; }
  for (int off = 1; off < 16; off <<= 1) { s1 += __shfl_xor(s1, off); s2 += __shfl_xor(s2, off); }
  if ((lane & 15) == 0) { a_src[gw * 4 + h] = s1; a_dst[gw * 4 + h] = s2; }
}

// ---------------- GAT aggregation: per-node online softmax + message sum ----------------
__global__ __launch_bounds__(256) void k_aggregate(
    const unsigned short* __restrict__ xp, const float* __restrict__ a_src,
    const float* __restrict__ a_dst, const float* __restrict__ a_edge,
    const float* __restrict__ a_eloop, const int* __restrict__ srcv,
    const int* __restrict__ rowptr, const int* __restrict__ colidx,
    const float* __restrict__ bias, unsigned short* __restrict__ outp) {
  int n = blockIdx.x;
  int tid = threadIdx.x;
  __shared__ float sh_w[64][4];
  __shared__ int   sh_s[64];
  __shared__ float sh_m[4], sh_l[4], sh_r[4];
  int beg = rowptr[n], deg = rowptr[n + 1] - beg;
  int total = deg + 1;  // + self loop
  if (tid < 4) { sh_m[tid] = -1e30f; sh_l[tid] = 0.f; }
  float acc0 = 0.f, acc1 = 0.f;
  int c0 = tid, c1 = tid + 256;
  int h0 = tid >> 7, h1 = 2 + h0;
  __syncthreads();
  for (int base = 0; base < total; base += 64) {
    int cnt = min(64, total - base);
    if (tid < cnt * 4) {
      int le = tid >> 2, h = tid & 3;
      int ge = base + le;
      int sn; float ae;
      if (ge < deg) { int eid = colidx[beg + ge]; sn = srcv[eid]; ae = a_edge[(size_t)eid * 4 + h]; }
      else          { sn = n; ae = a_eloop[(size_t)n * 4 + h]; }
      float al = a_src[(size_t)sn * 4 + h] + a_dst[(size_t)n * 4 + h] + ae;
      al = leakyf(al, 0.2f);
      sh_w[le][h] = al;
      if (h == 0) sh_s[le] = sn;
    }
    __syncthreads();
    if (tid < 4) {
      int h = tid;
      float m = sh_m[h];
      float cm = -1e30f;
      for (int e = 0; e < cnt; e++) cm = fmaxf(cm, sh_w[e][h]);
      float nm = fmaxf(m, cm);
      float r = expf(m - nm);
      float l = sh_l[h] * r;
      for (int e = 0; e < cnt; e++) { float ex = expf(sh_w[e][h] - nm); sh_w[e][h] = ex; l += ex; }
      sh_m[h] = nm; sh_l[h] = l; sh_r[h] = r;
    }
    __syncthreads();
    acc0 *= sh_r[h0]; acc1 *= sh_r[h1];
    for (int e = 0; e < cnt; e++) {
      const unsigned short* xs = xp + (size_t)sh_s[e] * HC;
      acc0 += b2f(xs[c0]) * sh_w[e][h0];
      acc1 += b2f(xs[c1]) * sh_w[e][h1];
    }
    __syncthreads();
  }
  float v0 = acc0 / sh_l[h0] + bias[c0];
  float v1 = acc1 / sh_l[h1] + bias[c1];
  outp[(size_t)n * HC + c0] = f2b(leakyf(v0, 0.01f));
  outp[(size_t)n * HC + c1] = f2b(leakyf(v1, 0.01f));
}

// ---------------- weight prep: Bt[n][k] = bf16(src[k*N+n]), K padded ----------------
__global__ void k_bt(const float* __restrict__ src, unsigned short* __restrict__ bt,
                     int N, int Ks, int Kd) {
  int idx = blockIdx.x * blockDim.x + threadIdx.x;
  if (idx >= N * Kd) return;
  int n = idx / Kd, k = idx - n * Kd;
  bt[idx] = (k < Ks) ? f2b(src[(size_t)k * N + n]) : (unsigned short)0;
}

// conv weights: bt[n][k], k = tap*512+c  <- convw[n][c][di][dj]
__global__ void k_convbt(const float* __restrict__ w, unsigned short* __restrict__ bt) {
  int idx = blockIdx.x * blockDim.x + threadIdx.x;
  if (idx >= EMBED * KCONV) return;
  int n = idx / KCONV, k = idx - n * KCONV;
  int tap = k >> 9, c = k & 511;
  bt[idx] = f2b(w[(size_t)n * KCONV + c * 9 + tap]);
}

// ---------------- materialize padded local map (bf16) ----------------
// lmb[b][rr][cc][c], rr in [0,66), cc in [0,130)
__global__ void k_lm(const unsigned short* __restrict__ h2, unsigned short* __restrict__ lmb) {
  int idx = blockIdx.x * blockDim.x + threadIdx.x;
  if (idx >= LMROWS * 512) return;
  int c = idx & 511;
  int prow = idx >> 9;
  int cc = prow % 130;
  int t = prow / 130;
  int rr = t % 66, b = t / 66;
  int gr, gc;
  if (rr == 0)       { gr = 1;      gc = (63 + cc) & 127; }
  else if (rr == 65) { gr = 62;     gc = (63 + cc) & 127; }
  else               { gr = rr - 1; gc = (cc + 127) & 127; }
  lmb[idx] = h2[((size_t)(b * PB + 2 + gr * WWW + gc)) * HC + c];
}

// zin[:, 0:512] = g rows (h2 without poles)
__global__ void k_zin_g(const unsigned short* __restrict__ h2, unsigned short* __restrict__ zin) {
  int idx = blockIdx.x * blockDim.x + threadIdx.x;
  if (idx >= NPOS * 512) return;
  int r = idx >> 9, c = idx & 511;
  int b = r >> 13, pos = r & 8191;
  zin[(size_t)r * 640 + c] = h2[((size_t)(b * PB + 2 + pos)) * HC + c];
}

// ---------------- bf16 MFMA GEMM, m97-style ----------------
// C[M,N] = epi(A[M,K] @ B[K,N]); A bf16 row-major (or conv-implicit), Bt bf16 [N][K].
// 256 threads = 4 waves (2x2). Block tile BM x BN, K-step 32.
// Staging: global_load_lds dwordx4, linear LDS (no padding), double-buffered 2-phase.
// MODE 0: A direct (row clamped to M-1). MODE 1: conv implicit im2col from lmb.
template<int MODE, int BM, int BN, typename OutT>
__global__ __launch_bounds__(256) void mgemm(
    int M, int N, int K,
    const unsigned short* __restrict__ A, int lda,
    const unsigned short* __restrict__ Bt,
    const float* __restrict__ bias,
    const float* __restrict__ bnscale, const float* __restrict__ bnshift,
    float slope,
    OutT* __restrict__ C, int ldc)
{
  constexpr int WM = BM / 32;          // 16x16 frags per wave (M)
  constexpr int WN = BN / 32;          // 16x16 frags per wave (N)
  constexpr int ACH = BM * 4;          // 16B chunks per A tile
  constexpr int BCH = BN * 4;
  __shared__ unsigned short As[2][BM * 32];
  __shared__ unsigned short Bs[2][BN * 32];
  int tid = threadIdx.x;
  int wid = tid >> 6, lane = tid & 63;
  int wr = wid >> 1, wc = wid & 1;
  int l15 = lane & 15, l4 = lane >> 4;
  int row0 = blockIdx.y * BM, col0 = blockIdx.x * BN;

  auto stage = [&](int buf, int kt) {
    int k0 = kt * 32;
    int di = 0, dj = 0;
    if constexpr (MODE == 1) { int tap = k0 >> 9; di = tap / 3; dj = tap - di * 3; }
#pragma unroll
    for (int i = 0; i < ACH / 256; i++) {
      int c = i * 256 + tid;
      int r = c >> 2, seg = c & 3;
      const unsigned short* ga;
      if constexpr (MODE == 0) {
        int gr = min(row0 + r, M - 1);
        ga = A + (size_t)gr * lda + k0 + seg * 8;
      } else {
        int gr = row0 + r;
        int b = gr >> 13, pos = gr & 8191, ii = pos >> 7, jj = pos & 127;
        int arow = (b * 66 + ii + di) * 130 + (jj + dj);
        ga = A + (size_t)arow * 512 + (k0 & 511) + seg * 8;
      }
      gload_lds16(ga, &As[buf][c * 8]);
    }
#pragma unroll
    for (int i = 0; i < BCH / 256; i++) {
      int c = i * 256 + tid;
      int r = c >> 2, seg = c & 3;
      int gn = min(col0 + r, N - 1);
      gload_lds16(Bt + (size_t)gn * K + k0 + seg * 8, &Bs[buf][c * 8]);
    }
  };

  v4f acc[WM][WN];
#pragma unroll
  for (int m = 0; m < WM; m++)
#pragma unroll
    for (int n = 0; n < WN; n++) acc[m][n] = (v4f)0.f;

  int nt = K >> 5;
  stage(0, 0);
  __syncthreads();
  int cur = 0;
  for (int t = 0; t < nt - 1; t++) {
    stage(cur ^ 1, t + 1);
    v8s a[WM], b[WN];
#pragma unroll
    for (int m = 0; m < WM; m++)
      a[m] = *(const v8s*)(&As[cur][(wr * (BM / 2) + m * 16 + l15) * 32 + l4 * 8]);
#pragma unroll
    for (int n = 0; n < WN; n++)
      b[n] = *(const v8s*)(&Bs[cur][(wc * (BN / 2) + n * 16 + l15) * 32 + l4 * 8]);
#pragma unroll
    for (int m = 0; m < WM; m++)
#pragma unroll
      for (int n = 0; n < WN; n++)
        acc[m][n] = __builtin_amdgcn_mfma_f32_16x16x32_bf16(a[m], b[n], acc[m][n], 0, 0, 0);
    __syncthreads();   // drains vmcnt -> next buffer staged; protects reuse
    cur ^= 1;
  }
  {
    v8s a[WM], b[WN];
#pragma unroll
    for (int m = 0; m < WM; m++)
      a[m] = *(const v8s*)(&As[cur][(wr * (BM / 2) + m * 16 + l15) * 32 + l4 * 8]);
#pragma unroll
    for (int n = 0; n < WN; n++)
      b[n] = *(const v8s*)(&Bs[cur][(wc * (BN / 2) + n * 16 + l15) * 32 + l4 * 8]);
#pragma unroll
    for (int m = 0; m < WM; m++)
#pragma unroll
      for (int n = 0; n < WN; n++)
        acc[m][n] = __builtin_amdgcn_mfma_f32_16x16x32_bf16(a[m], b[n], acc[m][n], 0, 0, 0);
  }
  // epilogue: C row = (lane>>4)*4 + q, col = lane&15 (m89-verified)
#pragma unroll
  for (int m = 0; m < WM; m++) {
#pragma unroll
    for (int q = 0; q < 4; q++) {
      int r = row0 + wr * (BM / 2) + m * 16 + l4 * 4 + q;
      if (r >= M) continue;
#pragma unroll
      for (int n = 0; n < WN; n++) {
        int cc = col0 + wc * (BN / 2) + n * 16 + l15;
        if (cc >= N) continue;
        float v = acc[m][n][q];
        if (bias) v += bias[cc];
        if (bnscale) v = v * (bnscale[cc] * rsqrtf(1.f + 1e-5f)) + bnshift[cc];
        v = leakyf(v, slope);
        if constexpr (std::is_same<OutT, float>::value) {
          C[(size_t)r * ldc + cc] = v;
        } else {
          C[(size_t)r * ldc + cc] = f2b(v);
        }
      }
    }
  }
}

// ---------------- final: out[b,t,i,j] = z3[(b*8192+p), t] + x[b, 78+t, p] ----------------
__global__ void k_final(const float* __restrict__ z3, const float* __restrict__ x,
                        float* __restrict__ outp) {
  int idx = blockIdx.x * blockDim.x + threadIdx.x;
  if (idx >= NPOS * TGT) return;
  int b = idx / (TGT * 8192);
  int rem = idx - b * (TGT * 8192);
  int t = rem >> 13;
  int p = rem & 8191;
  outp[idx] = z3[((size_t)(b * 8192 + p)) * TGT + t] + x[((size_t)(b * 117 + 78 + t)) * 8192 + p];
}

// ================================================================
extern "C" void kernel_launch(void* const* d_in, const int* in_sizes, int n_in,
                              void* d_out, int out_size, void* d_ws, size_t ws_size,
                              hipStream_t stream) {
  const float* x     = (const float*)d_in[0];
  const float* xcons = (const float*)d_in[1];
  const int*   eidx  = (const int*)d_in[2];
  const float* eattr = (const float*)d_in[3];
  const float* g1W  = (const float*)d_in[4];
  const float* g1as = (const float*)d_in[5];
  const float* g1ad = (const float*)d_in[6];
  const float* g1We = (const float*)d_in[7];
  const float* g1ae = (const float*)d_in[8];
  const float* g1b  = (const float*)d_in[9];
  const float* g2W  = (const float*)d_in[10];
  const float* g2as = (const float*)d_in[11];
  const float* g2ad = (const float*)d_in[12];
  const float* g2We = (const float*)d_in[13];
  const float* g2ae = (const float*)d_in[14];
  const float* g2b  = (const float*)d_in[15];
  const float* convw= (const float*)d_in[16];
  const float* convb= (const float*)d_in[17];
  const float* bng  = (const float*)d_in[18];
  const float* bnb  = (const float*)d_in[19];
  const float* mw1  = (const float*)d_in[20];
  const float* mb1  = (const float*)d_in[21];
  const float* mw2  = (const float*)d_in[22];
  const float* mb2  = (const float*)d_in[23];
  const float* mw3  = (const float*)d_in[24];
  const float* mb3  = (const float*)d_in[25];
  float* outp = (float*)d_out;
  (void)in_sizes; (void)n_in; (void)out_size; (void)ws_size;

  const int* esrc = eidx;
  const int* edst = eidx + NE;

  char* basep = (char*)d_ws;
  size_t off = 0;
  auto alloc = [&](size_t bytes) -> void* {
    void* p = basep + off;
    off += (bytes + 255) & ~(size_t)255;
    return p;
  };
  unsigned short* nodesb = (unsigned short*)alloc((size_t)NNODE * 128 * 2);
  unsigned short* xpb    = (unsigned short*)alloc((size_t)NNODE * HC * 2);
  unsigned short* h1b    = (unsigned short*)alloc((size_t)NNODE * HC * 2);
  unsigned short* h2b    = (unsigned short*)alloc((size_t)NNODE * HC * 2);
  unsigned short* lmb    = (unsigned short*)alloc((size_t)LMROWS * 512 * 2);
  unsigned short* zin    = (unsigned short*)alloc((size_t)NPOS * 640 * 2);
  float* asrc   = (float*)alloc((size_t)NNODE * 4 * sizeof(float));
  float* adst   = (float*)alloc((size_t)NNODE * 4 * sizeof(float));
  float* aedge  = (float*)alloc((size_t)NE * 4 * sizeof(float));
  float* aeloop = (float*)alloc((size_t)NNODE * 4 * sizeof(float));
  float* lattr  = (float*)alloc((size_t)NNODE * 8 * sizeof(float));
  float* Medge  = (float*)alloc(32 * sizeof(float));
  unsigned short* g1Wt  = (unsigned short*)alloc((size_t)512 * 128 * 2);
  unsigned short* g2Wt  = (unsigned short*)alloc((size_t)512 * 512 * 2);
  unsigned short* convWt= (unsigned short*)alloc((size_t)EMBED * KCONV * 2);
  unsigned short* mw1t  = (unsigned short*)alloc((size_t)512 * 640 * 2);
  unsigned short* mw2t  = (unsigned short*)alloc((size_t)256 * 512 * 2);
  unsigned short* mw3t  = (unsigned short*)alloc((size_t)TGT * 256 * 2);
  int* cnt      = (int*)alloc((size_t)NNODE * sizeof(int));
  int* rowptr   = (int*)alloc((size_t)(NNODE + 1) * sizeof(int));
  int* cursor   = (int*)alloc((size_t)NNODE * sizeof(int));
  int* colidx   = (int*)alloc((size_t)NE * sizeof(int));
  unsigned short* z1b = xpb;             // xpb dead after GAT2 aggregation
  unsigned short* z2b = h1b;             // h1b dead after GAT2 xp GEMM
  float*          z3  = (float*)nodesb;  // nodesb dead after GAT1 xp GEMM

  hipMemsetAsync(cnt, 0, NNODE * sizeof(int), stream);
  k_build_nodes<<<ceildiv(NNODE * 128, 256), 256, 0, stream>>>(x, xcons, nodesb);
  k_hist<<<ceildiv(NE, 256), 256, 0, stream>>>(edst, cnt);
  k_scan<<<1, 512, 0, stream>>>(cnt, rowptr, NNODE);
  k_copy_int<<<ceildiv(NNODE, 256), 256, 0, stream>>>(rowptr, cursor, NNODE);
  k_scatter<<<ceildiv(NE, 256), 256, 0, stream>>>(edst, cursor, colidx);
  k_loop_attr<<<ceildiv(NNODE * 8, 256), 256, 0, stream>>>(eattr, rowptr, colidx, lattr);

  // weight prep
  k_bt<<<ceildiv(512 * 128, 256), 256, 0, stream>>>(g1W, g1Wt, 512, F1, 128);
  k_bt<<<ceildiv(512 * 512, 256), 256, 0, stream>>>(g2W, g2Wt, 512, 512, 512);
  k_convbt<<<ceildiv(EMBED * KCONV, 256), 256, 0, stream>>>(convw, convWt);
  k_bt<<<ceildiv(512 * 640, 256), 256, 0, stream>>>(mw1, mw1t, 512, 640, 640);
  k_bt<<<ceildiv(256 * 512, 256), 256, 0, stream>>>(mw2, mw2t, 256, 512, 512);
  k_bt<<<ceildiv(TGT * 256, 256), 256, 0, stream>>>(mw3, mw3t, TGT, 256, 256);

  // ---- GAT layer 1 ----
  k_medge<<<1, 64, 0, stream>>>(g1We, g1ae, Medge);
  k_aedge<<<ceildiv(NE * 4, 256), 256, 0, stream>>>(eattr, Medge, aedge, NE);
  k_aedge<<<ceildiv(NNODE * 4, 256), 256, 0, stream>>>(lattr, Medge, aeloop, NNODE);
  {
    dim3 g(4, ceildiv(NNODE, 128));
    mgemm<0, 128, 128, unsigned short><<<g, 256, 0, stream>>>(
        NNODE, HC, 128, nodesb, 128, g1Wt, nullptr, nullptr, nullptr, 1.0f, xpb, HC);
  }
  k_attn_dots<<<ceildiv(NNODE, 4), 256, 0, stream>>>(xpb, g1as, g1ad, asrc, adst);
  k_aggregate<<<NNODE, 256, 0, stream>>>(xpb, asrc, adst, aedge, aeloop, esrc, rowptr,
                                         colidx, g1b, h1b);

  // ---- GAT layer 2 ----
  k_medge<<<1, 64, 0, stream>>>(g2We, g2ae, Medge);
  k_aedge<<<ceildiv(NE * 4, 256), 256, 0, stream>>>(eattr, Medge, aedge, NE);
  k_aedge<<<ceildiv(NNODE * 4, 256), 256, 0, stream>>>(lattr, Medge, aeloop, NNODE);
  {
    dim3 g(4, ceildiv(NNODE, 128));
    mgemm<0, 128, 128, unsigned short><<<g, 256, 0, stream>>>(
        NNODE, HC, HC, h1b, HC, g2Wt, nullptr, nullptr, nullptr, 1.0f, xpb, HC);
  }
  k_attn_dots<<<ceildiv(NNODE, 4), 256, 0, stream>>>(xpb, g2as, g2ad, asrc, adst);
  k_aggregate<<<NNODE, 256, 0, stream>>>(xpb, asrc, adst, aedge, aeloop, esrc, rowptr,
                                         colidx, g2b, h2b);

  // ---- conv: materialize padded local map, implicit-GEMM + BN + leaky into zin[:,512:640]
  k_lm<<<ceildiv(LMROWS * 512, 256), 256, 0, stream>>>(h2b, lmb);
  k_zin_g<<<ceildiv(NPOS * 512, 256), 256, 0, stream>>>(h2b, zin);
  {
    dim3 g(1, ceildiv(NPOS, 64));   // 256 blocks
    mgemm<1, 64, 128, unsigned short><<<g, 256, 0, stream>>>(
        NPOS, EMBED, KCONV, lmb, 512, convWt, convb, bng, bnb, 0.01f, zin + 512, 640);
  }

  // ---- MLP ----
  {
    dim3 g(4, ceildiv(NPOS, 128));
    mgemm<0, 128, 128, unsigned short><<<g, 256, 0, stream>>>(
        NPOS, 512, 640, zin, 640, mw1t, mb1, nullptr, nullptr, 0.01f, z1b, 512);
  }
  {
    dim3 g(2, ceildiv(NPOS, 64));   // 512 blocks
    mgemm<0, 64, 128, unsigned short><<<g, 256, 0, stream>>>(
        NPOS, 256, 512, z1b, 512, mw2t, mb2, nullptr, nullptr, 0.01f, z2b, 256);
  }
  {
    dim3 g(1, ceildiv(NPOS, 64));   // 256 blocks
    mgemm<0, 64, 64, float><<<g, 256, 0, stream>>>(
        NPOS, TGT, 256, z2b, 256, mw3t, mb3, nullptr, nullptr, 1.0f, z3, TGT);
  }

  k_final<<<ceildiv(NPOS * TGT, 256), 256, 0, stream>>>(z3, x, outp);
}

// Round 5
// 381.742 us; speedup vs baseline: 4.7637x; 1.1041x over previous
//
#include <hip/hip_runtime.h>
#include <math.h>
#include <type_traits>

// ---- problem constants ----
#define NB    2
#define HHH   64
#define WWW   128
#define F1    123      // 117 + 6
#define HC    512      // heads*hid
#define NE    131072
#define PB    8194     // nodes per batch (8192 + 2 poles)
#define NNODE (NB*PB)  // 16388
#define NPOS  (NB*HHH*WWW) // 16384
#define TGT   39
#define EMBED 128
#define KCONV 4608     // 512*9
#define LMROWS (2*66*130)
#define CSPLIT 3       // conv split-K chunks (3 taps each)

static inline int ceildiv(int a, int b){ return (a + b - 1) / b; }

typedef short v8s __attribute__((ext_vector_type(8)));
typedef float v4f __attribute__((ext_vector_type(4)));

__device__ __forceinline__ float leakyf(float x, float s){ return x >= 0.f ? x : s * x; }

__device__ __forceinline__ unsigned short f2b(float f) {
  unsigned u = __builtin_bit_cast(unsigned, f);
  u = (u + 0x7FFFu + ((u >> 16) & 1u)) >> 16;
  return (unsigned short)u;
}
__device__ __forceinline__ float b2f(unsigned short h) {
  unsigned u = ((unsigned)h) << 16;
  return __builtin_bit_cast(float, u);
}

// async global->LDS, 16 bytes per lane (dest = wave-uniform base + lane*16)
__device__ __forceinline__ void gload_lds16(const void* g, void* l) {
  __builtin_amdgcn_global_load_lds((const __attribute__((address_space(1))) void*)g,
                                   (__attribute__((address_space(3))) void*)l, 16, 0, 0);
}

// ---------------- build node features (bf16, K padded 123->128) ----------------
__global__ void k_build_nodes(const float* __restrict__ x, const float* __restrict__ xc,
                              unsigned short* __restrict__ nodes) {
  int idx = blockIdx.x * blockDim.x + threadIdx.x;
  if (idx >= NNODE * 128) return;
  int node = idx >> 7, c = idx & 127;
  int b = node / PB, loc = node - b * PB;
  float v = 0.f;
  if (loc >= 2 && c < F1) {
    int p = loc - 2;
    v = (c < 117) ? x[((size_t)(b * 117 + c)) * 8192 + p]
                  : xc[((size_t)(b * 6 + (c - 117))) * 8192 + p];
  }
  nodes[idx] = f2b(v);
}

// ---------------- CSR build ----------------
__global__ void k_hist(const int* __restrict__ dst, int* __restrict__ cnt) {
  int e = blockIdx.x * blockDim.x + threadIdx.x;
  if (e >= NE) return;
  atomicAdd(&cnt[dst[e]], 1);
}

__global__ void k_scan(const int* __restrict__ cnt, int* __restrict__ rowptr, int n) {
  __shared__ int part[512];
  int t = threadIdx.x;
  int chunk = (n + 511) >> 9;
  int beg = t * chunk, end = min(beg + chunk, n);
  int s = 0;
  for (int i = beg; i < end; i++) s += cnt[i];
  part[t] = s;
  __syncthreads();
  int own = s;
  for (int off = 1; off < 512; off <<= 1) {
    int v = 0;
    if (t >= off) v = part[t - off];
    __syncthreads();
    part[t] += v;
    __syncthreads();
  }
  int run = part[t] - own;   // exclusive prefix
  for (int i = beg; i < end; i++) { rowptr[i] = run; run += cnt[i]; }
  if (t == 511) rowptr[n] = part[511];
}

__global__ void k_copy_int(const int* __restrict__ a, int* __restrict__ b, int n) {
  int i = blockIdx.x * blockDim.x + threadIdx.x;
  if (i < n) b[i] = a[i];
}

__global__ void k_scatter(const int* __restrict__ dst, int* __restrict__ cursor,
                          int* __restrict__ colidx) {
  int e = blockIdx.x * blockDim.x + threadIdx.x;
  if (e >= NE) return;
  int pos = atomicAdd(&cursor[dst[e]], 1);
  colidx[pos] = e;
}

// loop_attr[n][k] = mean over incoming edges of edge_attr (0-safe divide)
__global__ void k_loop_attr(const float* __restrict__ eattr, const int* __restrict__ rowptr,
                            const int* __restrict__ colidx, float* __restrict__ lattr) {
  int idx = blockIdx.x * blockDim.x + threadIdx.x;
  if (idx >= NNODE * 8) return;
  int nn = idx >> 3, k = idx & 7;
  int b = rowptr[nn], e = rowptr[nn + 1];
  float s = 0.f;
  for (int i = b; i < e; i++) s += eattr[(size_t)colidx[i] * 8 + k];
  int c = e - b;
  lattr[idx] = s / (float)max(c, 1);
}

// ---------------- edge attention precompute ----------------
__global__ void k_medge(const float* __restrict__ We, const float* __restrict__ ae,
                        float* __restrict__ M) {
  int t = threadIdx.x;
  if (t >= 32) return;
  int k = t >> 2, h = t & 3;
  float s = 0.f;
  for (int c = 0; c < 128; c++) s += We[k * 512 + h * 128 + c] * ae[h * 128 + c];
  M[t] = s;
}

__global__ void k_aedge(const float* __restrict__ attr, const float* __restrict__ M,
                        float* __restrict__ out, int n) {
  int idx = blockIdx.x * blockDim.x + threadIdx.x;
  if (idx >= n * 4) return;
  int e = idx >> 2, h = idx & 3;
  float s = 0.f;
#pragma unroll
  for (int k = 0; k < 8; k++) s += attr[(size_t)e * 8 + k] * M[k * 4 + h];
  out[idx] = s;
}

// a_src[n,h] = xp[n,h,:].att_src[h,:] from bf16 xp — one wave per node
__global__ void k_attn_dots(const unsigned short* __restrict__ xp, const float* __restrict__ as,
                            const float* __restrict__ ad, float* __restrict__ a_src,
                            float* __restrict__ a_dst) {
  int gw = (blockIdx.x * blockDim.x + threadIdx.x) >> 6;
  int lane = threadIdx.x & 63;
  if (gw >= NNODE) return;
  int h = lane >> 4;
  int c0 = (lane & 15) * 8;
  const unsigned short* xr = xp + (size_t)gw * HC + h * 128 + c0;
  const float* asr = as + h * 128 + c0;
  const float* adr = ad + h * 128 + c0;
  float s1 = 0.f, s2 = 0.f;
#pragma unroll
  for (int i = 0; i < 8; i++) { float v = b2f(xr[i]); s1 += v * asr[i]; s2 += v * adr[i]; }
  for (int off = 1; off < 16; off <<= 1) { s1 += __shfl_xor(s1, off); s2 += __shfl_xor(s2, off); }
  if ((lane & 15) == 0) { a_src[gw * 4 + h] = s1; a_dst[gw * 4 + h] = s2; }
}

// ---------------- GAT aggregation: per-node online softmax + message sum ----------------
__global__ __launch_bounds__(256) void k_aggregate(
    const unsigned short* __restrict__ xp, const float* __restrict__ a_src,
    const float* __restrict__ a_dst, const float* __restrict__ a_edge,
    const float* __restrict__ a_eloop, const int* __restrict__ srcv,
    const int* __restrict__ rowptr, const int* __restrict__ colidx,
    const float* __restrict__ bias, unsigned short* __restrict__ outp) {
  int n = blockIdx.x;
  int tid = threadIdx.x;
  __shared__ float sh_w[64][4];
  __shared__ int   sh_s[64];
  __shared__ float sh_m[4], sh_l[4], sh_r[4];
  int beg = rowptr[n], deg = rowptr[n + 1] - beg;
  int total = deg + 1;  // + self loop
  if (tid < 4) { sh_m[tid] = -1e30f; sh_l[tid] = 0.f; }
  float acc0 = 0.f, acc1 = 0.f;
  int c0 = tid, c1 = tid + 256;
  int h0 = tid >> 7, h1 = 2 + h0;
  __syncthreads();
  for (int base = 0; base < total; base += 64) {
    int cnt = min(64, total - base);
    if (tid < cnt * 4) {
      int le = tid >> 2, h = tid & 3;
      int ge = base + le;
      int sn; float ae;
      if (ge < deg) { int eid = colidx[beg + ge]; sn = srcv[eid]; ae = a_edge[(size_t)eid * 4 + h]; }
      else          { sn = n; ae = a_eloop[(size_t)n * 4 + h]; }
      float al = a_src[(size_t)sn * 4 + h] + a_dst[(size_t)n * 4 + h] + ae;
      al = leakyf(al, 0.2f);
      sh_w[le][h] = al;
      if (h == 0) sh_s[le] = sn;
    }
    __syncthreads();
    if (tid < 4) {
      int h = tid;
      float m = sh_m[h];
      float cm = -1e30f;
      for (int e = 0; e < cnt; e++) cm = fmaxf(cm, sh_w[e][h]);
      float nm = fmaxf(m, cm);
      float r = expf(m - nm);
      float l = sh_l[h] * r;
      for (int e = 0; e < cnt; e++) { float ex = expf(sh_w[e][h] - nm); sh_w[e][h] = ex; l += ex; }
      sh_m[h] = nm; sh_l[h] = l; sh_r[h] = r;
    }
    __syncthreads();
    acc0 *= sh_r[h0]; acc1 *= sh_r[h1];
    for (int e = 0; e < cnt; e++) {
      const unsigned short* xs = xp + (size_t)sh_s[e] * HC;
      acc0 += b2f(xs[c0]) * sh_w[e][h0];
      acc1 += b2f(xs[c1]) * sh_w[e][h1];
    }
    __syncthreads();
  }
  float v0 = acc0 / sh_l[h0] + bias[c0];
  float v1 = acc1 / sh_l[h1] + bias[c1];
  outp[(size_t)n * HC + c0] = f2b(leakyf(v0, 0.01f));
  outp[(size_t)n * HC + c1] = f2b(leakyf(v1, 0.01f));
}

// ---------------- weight prep: Bt[n][k] = bf16(src[k*N+n]), K padded ----------------
__global__ void k_bt(const float* __restrict__ src, unsigned short* __restrict__ bt,
                     int N, int Ks, int Kd) {
  int idx = blockIdx.x * blockDim.x + threadIdx.x;
  if (idx >= N * Kd) return;
  int n = idx / Kd, k = idx - n * Kd;
  bt[idx] = (k < Ks) ? f2b(src[(size_t)k * N + n]) : (unsigned short)0;
}

// conv weights: bt[n][k], k = tap*512+c  <- convw[n][c][di][dj]
__global__ void k_convbt(const float* __restrict__ w, unsigned short* __restrict__ bt) {
  int idx = blockIdx.x * blockDim.x + threadIdx.x;
  if (idx >= EMBED * KCONV) return;
  int n = idx / KCONV, k = idx - n * KCONV;
  int tap = k >> 9, c = k & 511;
  bt[idx] = f2b(w[(size_t)n * KCONV + c * 9 + tap]);
}

// ---------------- materialize padded local map (bf16) ----------------
// lmb[b][rr][cc][c], rr in [0,66), cc in [0,130)
__global__ void k_lm(const unsigned short* __restrict__ h2, unsigned short* __restrict__ lmb) {
  int idx = blockIdx.x * blockDim.x + threadIdx.x;
  if (idx >= LMROWS * 512) return;
  int c = idx & 511;
  int prow = idx >> 9;
  int cc = prow % 130;
  int t = prow / 130;
  int rr = t % 66, b = t / 66;
  int gr, gc;
  if (rr == 0)       { gr = 1;      gc = (63 + cc) & 127; }
  else if (rr == 65) { gr = 62;     gc = (63 + cc) & 127; }
  else               { gr = rr - 1; gc = (cc + 127) & 127; }
  lmb[idx] = h2[((size_t)(b * PB + 2 + gr * WWW + gc)) * HC + c];
}

// zin[:, 0:512] = g rows (h2 without poles)
__global__ void k_zin_g(const unsigned short* __restrict__ h2, unsigned short* __restrict__ zin) {
  int idx = blockIdx.x * blockDim.x + threadIdx.x;
  if (idx >= NPOS * 512) return;
  int r = idx >> 9, c = idx & 511;
  int b = r >> 13, pos = r & 8191;
  zin[(size_t)r * 640 + c] = h2[((size_t)(b * PB + 2 + pos)) * HC + c];
}

// ---------------- bf16 MFMA GEMM, m97-style ----------------
// C[M,N] = epi(A[M,K] @ B[K,N]); A bf16 row-major (or conv-implicit), Bt bf16 [N][K-rowstride ldb].
// 256 threads = 4 waves (2x2). Block tile BM x BN, K-step 32.
// Staging: global_load_lds dwordx4, linear LDS, double-buffered.
// MODE 0: A direct (row clamped). MODE 1: conv implicit im2col from lmb.
// MODE 2: conv split-K — blockIdx.x = K-chunk; K arg = per-chunk K; C += chunk*M*ldc; no epilogue.
template<int MODE, int BM, int BN, typename OutT>
__global__ __launch_bounds__(256) void mgemm(
    int M, int N, int K, int ldb,
    const unsigned short* __restrict__ A, int lda,
    const unsigned short* __restrict__ Bt,
    const float* __restrict__ bias,
    const float* __restrict__ bnscale, const float* __restrict__ bnshift,
    float slope,
    OutT* __restrict__ C, int ldc)
{
  constexpr int WM = BM / 32;          // 16x16 frags per wave (M)
  constexpr int WN = BN / 32;          // 16x16 frags per wave (N)
  constexpr int ACH = BM * 4;          // 16B chunks per A tile
  constexpr int BCH = BN * 4;
  __shared__ unsigned short As[2][BM * 32];
  __shared__ unsigned short Bs[2][BN * 32];
  int tid = threadIdx.x;
  int wid = tid >> 6, lane = tid & 63;
  int wr = wid >> 1, wc = wid & 1;
  int l15 = lane & 15, l4 = lane >> 4;
  int row0 = blockIdx.y * BM;
  int col0, koff;
  if constexpr (MODE == 2) { col0 = 0; koff = blockIdx.x * K; C += (size_t)blockIdx.x * M * ldc; }
  else { col0 = blockIdx.x * BN; koff = 0; }

  auto stage = [&](int buf, int kt) {
    int k0 = kt * 32;
    int kg = koff + k0;
    int di = 0, dj = 0;
    if constexpr (MODE >= 1) { int tap = kg >> 9; di = tap / 3; dj = tap - di * 3; }
#pragma unroll
    for (int i = 0; i < ACH / 256; i++) {
      int c = i * 256 + tid;
      int r = c >> 2, seg = c & 3;
      const unsigned short* ga;
      if constexpr (MODE == 0) {
        int gr = min(row0 + r, M - 1);
        ga = A + (size_t)gr * lda + k0 + seg * 8;
      } else {
        int gr = row0 + r;
        int b = gr >> 13, pos = gr & 8191, ii = pos >> 7, jj = pos & 127;
        int arow = (b * 66 + ii + di) * 130 + (jj + dj);
        ga = A + (size_t)arow * 512 + (kg & 511) + seg * 8;
      }
      gload_lds16(ga, &As[buf][c * 8]);
    }
#pragma unroll
    for (int i = 0; i < BCH / 256; i++) {
      int c = i * 256 + tid;
      int r = c >> 2, seg = c & 3;
      int gn = min(col0 + r, N - 1);
      gload_lds16(Bt + (size_t)gn * ldb + kg + seg * 8, &Bs[buf][c * 8]);
    }
  };

  v4f acc[WM][WN];
#pragma unroll
  for (int m = 0; m < WM; m++)
#pragma unroll
    for (int n = 0; n < WN; n++) acc[m][n] = (v4f)0.f;

  int nt = K >> 5;
  stage(0, 0);
  __syncthreads();
  int cur = 0;
  for (int t = 0; t < nt - 1; t++) {
    stage(cur ^ 1, t + 1);
    v8s a[WM], b[WN];
#pragma unroll
    for (int m = 0; m < WM; m++)
      a[m] = *(const v8s*)(&As[cur][(wr * (BM / 2) + m * 16 + l15) * 32 + l4 * 8]);
#pragma unroll
    for (int n = 0; n < WN; n++)
      b[n] = *(const v8s*)(&Bs[cur][(wc * (BN / 2) + n * 16 + l15) * 32 + l4 * 8]);
#pragma unroll
    for (int m = 0; m < WM; m++)
#pragma unroll
      for (int n = 0; n < WN; n++)
        acc[m][n] = __builtin_amdgcn_mfma_f32_16x16x32_bf16(a[m], b[n], acc[m][n], 0, 0, 0);
    __syncthreads();   // drains vmcnt -> next buffer staged; protects reuse
    cur ^= 1;
  }
  {
    v8s a[WM], b[WN];
#pragma unroll
    for (int m = 0; m < WM; m++)
      a[m] = *(const v8s*)(&As[cur][(wr * (BM / 2) + m * 16 + l15) * 32 + l4 * 8]);
#pragma unroll
    for (int n = 0; n < WN; n++)
      b[n] = *(const v8s*)(&Bs[cur][(wc * (BN / 2) + n * 16 + l15) * 32 + l4 * 8]);
#pragma unroll
    for (int m = 0; m < WM; m++)
#pragma unroll
      for (int n = 0; n < WN; n++)
        acc[m][n] = __builtin_amdgcn_mfma_f32_16x16x32_bf16(a[m], b[n], acc[m][n], 0, 0, 0);
  }
  // epilogue: C row = (lane>>4)*4 + q, col = lane&15 (m89-verified)
#pragma unroll
  for (int m = 0; m < WM; m++) {
#pragma unroll
    for (int q = 0; q < 4; q++) {
      int r = row0 + wr * (BM / 2) + m * 16 + l4 * 4 + q;
      if (r >= M) continue;
#pragma unroll
      for (int n = 0; n < WN; n++) {
        int cc = col0 + wc * (BN / 2) + n * 16 + l15;
        if (cc >= N) continue;
        float v = acc[m][n][q];
        if constexpr (MODE != 2) {
          if (bias) v += bias[cc];
          if (bnscale) v = v * (bnscale[cc] * rsqrtf(1.f + 1e-5f)) + bnshift[cc];
          v = leakyf(v, slope);
        }
        if constexpr (std::is_same<OutT, float>::value) {
          C[(size_t)r * ldc + cc] = v;
        } else {
          C[(size_t)r * ldc + cc] = f2b(v);
        }
      }
    }
  }
}

// ---------------- conv split-K reduce: sum partials + bias + BN + leaky -> zin[:,512:640] ----------------
__global__ void k_creduce(const float* __restrict__ p, const float* __restrict__ convb,
                          const float* __restrict__ bng, const float* __restrict__ bnb,
                          unsigned short* __restrict__ zin) {
  int idx = blockIdx.x * blockDim.x + threadIdx.x;   // over NPOS*32 (x4 floats)
  if (idx >= NPOS * 32) return;
  int r = idx >> 5, c4 = (idx & 31) * 4;
  const float4* p0 = (const float4*)(p + (size_t)r * 128 + c4);
  const float4* p1 = (const float4*)(p + (size_t)(NPOS + r) * 128 + c4);
  const float4* p2 = (const float4*)(p + (size_t)(2 * NPOS + r) * 128 + c4);
  float4 a = *p0, b = *p1, c = *p2;
  unsigned short* o = zin + (size_t)r * 640 + 512 + c4;
#pragma unroll
  for (int j = 0; j < 4; j++) {
    float v = ((const float*)&a)[j] + ((const float*)&b)[j] + ((const float*)&c)[j];
    int cc = c4 + j;
    v += convb[cc];
    v = v * (bng[cc] * rsqrtf(1.f + 1e-5f)) + bnb[cc];
    o[j] = f2b(leakyf(v, 0.01f));
  }
}

// ---------------- final: out[b,t,i,j] = z3[(b*8192+p), t] + x[b, 78+t, p] ----------------
__global__ void k_final(const float* __restrict__ z3, const float* __restrict__ x,
                        float* __restrict__ outp) {
  int idx = blockIdx.x * blockDim.x + threadIdx.x;
  if (idx >= NPOS * TGT) return;
  int b = idx / (TGT * 8192);
  int rem = idx - b * (TGT * 8192);
  int t = rem >> 13;
  int p = rem & 8191;
  outp[idx] = z3[((size_t)(b * 8192 + p)) * TGT + t] + x[((size_t)(b * 117 + 78 + t)) * 8192 + p];
}

// ================================================================
extern "C" void kernel_launch(void* const* d_in, const int* in_sizes, int n_in,
                              void* d_out, int out_size, void* d_ws, size_t ws_size,
                              hipStream_t stream) {
  const float* x     = (const float*)d_in[0];
  const float* xcons = (const float*)d_in[1];
  const int*   eidx  = (const int*)d_in[2];
  const float* eattr = (const float*)d_in[3];
  const float* g1W  = (const float*)d_in[4];
  const float* g1as = (const float*)d_in[5];
  const float* g1ad = (const float*)d_in[6];
  const float* g1We = (const float*)d_in[7];
  const float* g1ae = (const float*)d_in[8];
  const float* g1b  = (const float*)d_in[9];
  const float* g2W  = (const float*)d_in[10];
  const float* g2as = (const float*)d_in[11];
  const float* g2ad = (const float*)d_in[12];
  const float* g2We = (const float*)d_in[13];
  const float* g2ae = (const float*)d_in[14];
  const float* g2b  = (const float*)d_in[15];
  const float* convw= (const float*)d_in[16];
  const float* convb= (const float*)d_in[17];
  const float* bng  = (const float*)d_in[18];
  const float* bnb  = (const float*)d_in[19];
  const float* mw1  = (const float*)d_in[20];
  const float* mb1  = (const float*)d_in[21];
  const float* mw2  = (const float*)d_in[22];
  const float* mb2  = (const float*)d_in[23];
  const float* mw3  = (const float*)d_in[24];
  const float* mb3  = (const float*)d_in[25];
  float* outp = (float*)d_out;
  (void)in_sizes; (void)n_in; (void)out_size; (void)ws_size;

  const int* esrc = eidx;
  const int* edst = eidx + NE;

  char* basep = (char*)d_ws;
  size_t off = 0;
  auto alloc = [&](size_t bytes) -> void* {
    void* p = basep + off;
    off += (bytes + 255) & ~(size_t)255;
    return p;
  };
  unsigned short* nodesb = (unsigned short*)alloc((size_t)NNODE * 128 * 2);
  unsigned short* xpb    = (unsigned short*)alloc((size_t)NNODE * HC * 2);
  unsigned short* h1b    = (unsigned short*)alloc((size_t)NNODE * HC * 2);
  unsigned short* h2b    = (unsigned short*)alloc((size_t)NNODE * HC * 2);
  unsigned short* lmb    = (unsigned short*)alloc((size_t)LMROWS * 512 * 2);
  unsigned short* zin    = (unsigned short*)alloc((size_t)NPOS * 640 * 2);
  float* cpart  = (float*)alloc((size_t)CSPLIT * NPOS * 128 * sizeof(float));
  float* asrc   = (float*)alloc((size_t)NNODE * 4 * sizeof(float));
  float* adst   = (float*)alloc((size_t)NNODE * 4 * sizeof(float));
  float* aedge  = (float*)alloc((size_t)NE * 4 * sizeof(float));
  float* aeloop = (float*)alloc((size_t)NNODE * 4 * sizeof(float));
  float* lattr  = (float*)alloc((size_t)NNODE * 8 * sizeof(float));
  float* Medge  = (float*)alloc(32 * sizeof(float));
  unsigned short* g1Wt  = (unsigned short*)alloc((size_t)512 * 128 * 2);
  unsigned short* g2Wt  = (unsigned short*)alloc((size_t)512 * 512 * 2);
  unsigned short* convWt= (unsigned short*)alloc((size_t)EMBED * KCONV * 2);
  unsigned short* mw1t  = (unsigned short*)alloc((size_t)512 * 640 * 2);
  unsigned short* mw2t  = (unsigned short*)alloc((size_t)256 * 512 * 2);
  unsigned short* mw3t  = (unsigned short*)alloc((size_t)TGT * 256 * 2);
  int* cnt      = (int*)alloc((size_t)NNODE * sizeof(int));
  int* rowptr   = (int*)alloc((size_t)(NNODE + 1) * sizeof(int));
  int* cursor   = (int*)alloc((size_t)NNODE * sizeof(int));
  int* colidx   = (int*)alloc((size_t)NE * sizeof(int));
  unsigned short* z1b = xpb;             // xpb dead after GAT2 aggregation
  unsigned short* z2b = h1b;             // h1b dead after GAT2 xp GEMM
  float*          z3  = (float*)nodesb;  // nodesb dead after GAT1 xp GEMM

  hipMemsetAsync(cnt, 0, NNODE * sizeof(int), stream);
  k_build_nodes<<<ceildiv(NNODE * 128, 256), 256, 0, stream>>>(x, xcons, nodesb);
  k_hist<<<ceildiv(NE, 256), 256, 0, stream>>>(edst, cnt);
  k_scan<<<1, 512, 0, stream>>>(cnt, rowptr, NNODE);
  k_copy_int<<<ceildiv(NNODE, 256), 256, 0, stream>>>(rowptr, cursor, NNODE);
  k_scatter<<<ceildiv(NE, 256), 256, 0, stream>>>(edst, cursor, colidx);
  k_loop_attr<<<ceildiv(NNODE * 8, 256), 256, 0, stream>>>(eattr, rowptr, colidx, lattr);

  // weight prep
  k_bt<<<ceildiv(512 * 128, 256), 256, 0, stream>>>(g1W, g1Wt, 512, F1, 128);
  k_bt<<<ceildiv(512 * 512, 256), 256, 0, stream>>>(g2W, g2Wt, 512, 512, 512);
  k_convbt<<<ceildiv(EMBED * KCONV, 256), 256, 0, stream>>>(convw, convWt);
  k_bt<<<ceildiv(512 * 640, 256), 256, 0, stream>>>(mw1, mw1t, 512, 640, 640);
  k_bt<<<ceildiv(256 * 512, 256), 256, 0, stream>>>(mw2, mw2t, 256, 512, 512);
  k_bt<<<ceildiv(TGT * 256, 256), 256, 0, stream>>>(mw3, mw3t, TGT, 256, 256);

  // ---- GAT layer 1 ----
  k_medge<<<1, 64, 0, stream>>>(g1We, g1ae, Medge);
  k_aedge<<<ceildiv(NE * 4, 256), 256, 0, stream>>>(eattr, Medge, aedge, NE);
  k_aedge<<<ceildiv(NNODE * 4, 256), 256, 0, stream>>>(lattr, Medge, aeloop, NNODE);
  {
    dim3 g(4, ceildiv(NNODE, 128));
    mgemm<0, 128, 128, unsigned short><<<g, 256, 0, stream>>>(
        NNODE, HC, 128, 128, nodesb, 128, g1Wt, nullptr, nullptr, nullptr, 1.0f, xpb, HC);
  }
  k_attn_dots<<<ceildiv(NNODE, 4), 256, 0, stream>>>(xpb, g1as, g1ad, asrc, adst);
  k_aggregate<<<NNODE, 256, 0, stream>>>(xpb, asrc, adst, aedge, aeloop, esrc, rowptr,
                                         colidx, g1b, h1b);

  // ---- GAT layer 2 ----
  k_medge<<<1, 64, 0, stream>>>(g2We, g2ae, Medge);
  k_aedge<<<ceildiv(NE * 4, 256), 256, 0, stream>>>(eattr, Medge, aedge, NE);
  k_aedge<<<ceildiv(NNODE * 4, 256), 256, 0, stream>>>(lattr, Medge, aeloop, NNODE);
  {
    dim3 g(4, ceildiv(NNODE, 128));
    mgemm<0, 128, 128, unsigned short><<<g, 256, 0, stream>>>(
        NNODE, HC, HC, HC, h1b, HC, g2Wt, nullptr, nullptr, nullptr, 1.0f, xpb, HC);
  }
  k_attn_dots<<<ceildiv(NNODE, 4), 256, 0, stream>>>(xpb, g2as, g2ad, asrc, adst);
  k_aggregate<<<NNODE, 256, 0, stream>>>(xpb, asrc, adst, aedge, aeloop, esrc, rowptr,
                                         colidx, g2b, h2b);

  // ---- conv: materialize padded local map, split-K implicit-GEMM, reduce+BN+leaky ----
  k_lm<<<ceildiv(LMROWS * 512, 256), 256, 0, stream>>>(h2b, lmb);
  k_zin_g<<<ceildiv(NPOS * 512, 256), 256, 0, stream>>>(h2b, zin);
  {
    dim3 g(CSPLIT, ceildiv(NPOS, 64));   // 3 x 256 = 768 blocks, 3/CU
    mgemm<2, 64, 128, float><<<g, 256, 0, stream>>>(
        NPOS, EMBED, KCONV / CSPLIT, KCONV, lmb, 512, convWt,
        nullptr, nullptr, nullptr, 1.0f, cpart, EMBED);
  }
  k_creduce<<<ceildiv(NPOS * 32, 256), 256, 0, stream>>>(cpart, convb, bng, bnb, zin);

  // ---- MLP ----
  {
    dim3 g(4, ceildiv(NPOS, 128));
    mgemm<0, 128, 128, unsigned short><<<g, 256, 0, stream>>>(
        NPOS, 512, 640, 640, zin, 640, mw1t, mb1, nullptr, nullptr, 0.01f, z1b, 512);
  }
  {
    dim3 g(2, ceildiv(NPOS, 64));   // 512 blocks
    mgemm<0, 64, 128, unsigned short><<<g, 256, 0, stream>>>(
        NPOS, 256, 512, 512, z1b, 512, mw2t, mb2, nullptr, nullptr, 0.01f, z2b, 256);
  }
  {
    dim3 g(1, ceildiv(NPOS, 64));   // 256 blocks
    mgemm<0, 64, 64, float><<<g, 256, 0, stream>>>(
        NPOS, TGT, 256, 256, z2b, 256, mw3t, mb3, nullptr, nullptr, 1.0f, z3, TGT);
  }

  k_final<<<ceildiv(NPOS * TGT, 256), 256, 0, stream>>>(z3, x, outp);
}

// Round 6
// 353.621 us; speedup vs baseline: 5.1425x; 1.0795x over previous
//
#include <hip/hip_runtime.h>
#include <math.h>
#include <type_traits>

// ---- problem constants ----
#define NB    2
#define HHH   64
#define WWW   128
#define F1    123      // 117 + 6
#define HC    512      // heads*hid
#define NE    131072
#define PB    8194     // nodes per batch (8192 + 2 poles)
#define NNODE (NB*PB)  // 16388
#define NPOS  (NB*HHH*WWW) // 16384
#define TGT   39
#define EMBED 128
#define KCONV 4608     // 512*9
#define LMROWS (2*66*130)
#define CSPLIT 3       // conv split-K chunks (3 taps each)

static inline int ceildiv(int a, int b){ return (a + b - 1) / b; }

typedef short v8s __attribute__((ext_vector_type(8)));
typedef float v4f __attribute__((ext_vector_type(4)));

__device__ __forceinline__ float leakyf(float x, float s){ return x >= 0.f ? x : s * x; }

__device__ __forceinline__ unsigned short f2b(float f) {
  unsigned u = __builtin_bit_cast(unsigned, f);
  u = (u + 0x7FFFu + ((u >> 16) & 1u)) >> 16;
  return (unsigned short)u;
}
__device__ __forceinline__ float b2f(unsigned short h) {
  unsigned u = ((unsigned)h) << 16;
  return __builtin_bit_cast(float, u);
}

// async global->LDS, 16 bytes per lane (dest = wave-uniform base + lane*16)
__device__ __forceinline__ void gload_lds16(const void* g, void* l) {
  __builtin_amdgcn_global_load_lds((const __attribute__((address_space(1))) void*)g,
                                   (__attribute__((address_space(3))) void*)l, 16, 0, 0);
}

// ---------------- build node features (bf16, K padded 123->128) ----------------
// LDS tile transpose: block = (batch, 64 positions); coalesced fp32 reads.
__global__ __launch_bounds__(256) void k_build_nodes(const float* __restrict__ x,
                                                     const float* __restrict__ xc,
                                                     unsigned short* __restrict__ nodes) {
  __shared__ unsigned short lds[64][130];
  int blk = blockIdx.x;             // NB*128 blocks
  int b = blk >> 7, p0 = (blk & 127) * 64;
  int tid = threadIdx.x;
  int pi = tid & 63, cg = tid >> 6;
  for (int c = cg; c < 128; c += 4) {
    float v = 0.f;
    int p = p0 + pi;
    if (c < 117)      v = x[((size_t)(b * 117 + c)) * 8192 + p];
    else if (c < 123) v = xc[((size_t)(b * 6 + (c - 117))) * 8192 + p];
    lds[pi][c] = f2b(v);
  }
  // zero pole rows once per batch
  if ((blk & 127) == 0 && tid < 32) {
    int rr = tid >> 4, sg = tid & 15;
    *(v8s*)(nodes + ((size_t)(b * PB + rr)) * 128 + sg * 8) = (v8s)0;
  }
  __syncthreads();
  int seg = tid & 15, r0 = tid >> 4;
  for (int rr = r0; rr < 64; rr += 16) {
    int node = b * PB + 2 + p0 + rr;
    *(v8s*)(nodes + (size_t)node * 128 + seg * 8) = *(const v8s*)(&lds[rr][seg * 8]);
  }
}

// ---------------- CSR build ----------------
__global__ void k_hist(const int* __restrict__ dst, int* __restrict__ cnt) {
  int e = blockIdx.x * blockDim.x + threadIdx.x;
  if (e >= NE) return;
  atomicAdd(&cnt[dst[e]], 1);
}

__global__ void k_scan(const int* __restrict__ cnt, int* __restrict__ rowptr, int n) {
  __shared__ int part[512];
  int t = threadIdx.x;
  int chunk = (n + 511) >> 9;
  int beg = t * chunk, end = min(beg + chunk, n);
  int s = 0;
  for (int i = beg; i < end; i++) s += cnt[i];
  part[t] = s;
  __syncthreads();
  int own = s;
  for (int off = 1; off < 512; off <<= 1) {
    int v = 0;
    if (t >= off) v = part[t - off];
    __syncthreads();
    part[t] += v;
    __syncthreads();
  }
  int run = part[t] - own;   // exclusive prefix
  for (int i = beg; i < end; i++) { rowptr[i] = run; run += cnt[i]; }
  if (t == 511) rowptr[n] = part[511];
}

__global__ void k_copy_int(const int* __restrict__ a, int* __restrict__ b, int n) {
  int i = blockIdx.x * blockDim.x + threadIdx.x;
  if (i < n) b[i] = a[i];
}

__global__ void k_scatter(const int* __restrict__ dst, int* __restrict__ cursor,
                          int* __restrict__ colidx) {
  int e = blockIdx.x * blockDim.x + threadIdx.x;
  if (e >= NE) return;
  int pos = atomicAdd(&cursor[dst[e]], 1);
  colidx[pos] = e;
}

// loop_attr[n][k] = mean over incoming edges of edge_attr (0-safe divide)
__global__ void k_loop_attr(const float* __restrict__ eattr, const int* __restrict__ rowptr,
                            const int* __restrict__ colidx, float* __restrict__ lattr) {
  int idx = blockIdx.x * blockDim.x + threadIdx.x;
  if (idx >= NNODE * 8) return;
  int nn = idx >> 3, k = idx & 7;
  int b = rowptr[nn], e = rowptr[nn + 1];
  float s = 0.f;
  for (int i = b; i < e; i++) s += eattr[(size_t)colidx[i] * 8 + k];
  int c = e - b;
  lattr[idx] = s / (float)max(c, 1);
}

// ---------------- edge attention precompute ----------------
__global__ void k_medge(const float* __restrict__ We, const float* __restrict__ ae,
                        float* __restrict__ M) {
  int t = threadIdx.x;
  if (t >= 32) return;
  int k = t >> 2, h = t & 3;
  float s = 0.f;
  for (int c = 0; c < 128; c++) s += We[k * 512 + h * 128 + c] * ae[h * 128 + c];
  M[t] = s;
}

__global__ void k_aedge(const float* __restrict__ attr, const float* __restrict__ M,
                        float* __restrict__ out, int n) {
  int idx = blockIdx.x * blockDim.x + threadIdx.x;
  if (idx >= n * 4) return;
  int e = idx >> 2, h = idx & 3;
  float s = 0.f;
#pragma unroll
  for (int k = 0; k < 8; k++) s += attr[(size_t)e * 8 + k] * M[k * 4 + h];
  out[idx] = s;
}

// a_src[n,h] = xp[n,h,:].att_src[h,:] from bf16 xp — one wave per node, 16B loads
__global__ void k_attn_dots(const unsigned short* __restrict__ xp, const float* __restrict__ as,
                            const float* __restrict__ ad, float* __restrict__ a_src,
                            float* __restrict__ a_dst) {
  int gw = (blockIdx.x * blockDim.x + threadIdx.x) >> 6;
  int lane = threadIdx.x & 63;
  if (gw >= NNODE) return;
  int h = lane >> 4;
  int c0 = (lane & 15) * 8;
  v8s v = *(const v8s*)(xp + (size_t)gw * HC + h * 128 + c0);
  const float* asr = as + h * 128 + c0;
  const float* adr = ad + h * 128 + c0;
  float s1 = 0.f, s2 = 0.f;
#pragma unroll
  for (int i = 0; i < 8; i++) {
    float f = b2f((unsigned short)v[i]);
    s1 += f * asr[i]; s2 += f * adr[i];
  }
  for (int off = 1; off < 16; off <<= 1) { s1 += __shfl_xor(s1, off); s2 += __shfl_xor(s2, off); }
  if ((lane & 15) == 0) { a_src[gw * 4 + h] = s1; a_dst[gw * 4 + h] = s2; }
}

// ---------------- GAT aggregation v2 ----------------
// One block per node. Each wave holds the FULL 512-ch row (64 lanes x ushort8),
// waves stride over edges; wave-parallel online softmax (wave h = head h);
// cross-wave combine via LDS partials.
__global__ __launch_bounds__(256) void k_aggregate(
    const unsigned short* __restrict__ xp, const float* __restrict__ a_src,
    const float* __restrict__ a_dst, const float* __restrict__ a_edge,
    const float* __restrict__ a_eloop, const int* __restrict__ srcv,
    const int* __restrict__ rowptr, const int* __restrict__ colidx,
    const float* __restrict__ bias, unsigned short* __restrict__ outp) {
  int n = blockIdx.x;
  int tid = threadIdx.x;
  int wid = tid >> 6, lane = tid & 63;
  __shared__ float sh_w[64][4];
  __shared__ int   sh_s[64];
  __shared__ float sh_m[4], sh_l[4], sh_r[4];
  __shared__ float pacc[4][512];
  int beg = rowptr[n], deg = rowptr[n + 1] - beg;
  int total = deg + 1;  // + self loop
  if (tid < 4) { sh_m[tid] = -1e30f; sh_l[tid] = 0.f; }
  float acc[8] = {0.f, 0.f, 0.f, 0.f, 0.f, 0.f, 0.f, 0.f};
  int c0 = lane * 8;       // this lane's 8 channels
  int hh = lane >> 4;      // head of those channels
  float adn = a_dst[(size_t)n * 4 + (tid & 3)];  // used only by alpha threads
  __syncthreads();
  for (int base = 0; base < total; base += 64) {
    int cnt = min(64, total - base);
    // ---- raw alpha ----
    if (tid < cnt * 4) {
      int le = tid >> 2, h = tid & 3;
      int ge = base + le;
      int sn; float ae;
      if (ge < deg) { int eid = colidx[beg + ge]; sn = srcv[eid]; ae = a_edge[(size_t)eid * 4 + h]; }
      else          { sn = n; ae = a_eloop[(size_t)n * 4 + h]; }
      float al = a_src[(size_t)sn * 4 + h] + adn + ae;
      sh_w[le][h] = leakyf(al, 0.2f);
      if (h == 0) sh_s[le] = sn;
    }
    __syncthreads();
    // ---- online softmax: wave wid handles head wid ----
    {
      int h = wid;
      float a = (lane < cnt) ? sh_w[lane][h] : -1e30f;
      float cm = a;
#pragma unroll
      for (int off = 1; off < 64; off <<= 1) cm = fmaxf(cm, __shfl_xor(cm, off));
      float m_old = sh_m[h];
      float nm = fmaxf(m_old, cm);
      float ex = (lane < cnt) ? __expf(a - nm) : 0.f;
      float s = ex;
#pragma unroll
      for (int off = 1; off < 64; off <<= 1) s += __shfl_xor(s, off);
      if (lane < cnt) sh_w[lane][h] = ex;
      if (lane == 0) {
        float r = __expf(m_old - nm);
        sh_r[h] = r; sh_m[h] = nm; sh_l[h] = sh_l[h] * r + s;
      }
    }
    __syncthreads();
    // ---- gather: wave strides over edges, 16B row loads ----
    float r = sh_r[hh];
#pragma unroll
    for (int j = 0; j < 8; j++) acc[j] *= r;
    for (int e = wid; e < cnt; e += 4) {
      int sn = sh_s[e];
      float wt = sh_w[e][hh];
      v8s v = *(const v8s*)(xp + (size_t)sn * HC + c0);
#pragma unroll
      for (int j = 0; j < 8; j++) acc[j] += wt * b2f((unsigned short)v[j]);
    }
    __syncthreads();   // sh_w reused next chunk
  }
  // ---- cross-wave combine ----
  *(v4f*)(&pacc[wid][c0])     = *(const v4f*)(&acc[0]);
  *(v4f*)(&pacc[wid][c0 + 4]) = *(const v4f*)(&acc[4]);
  __syncthreads();
  int c = tid * 2;
  float l = sh_l[c >> 7];
  float v0 = (pacc[0][c] + pacc[1][c] + pacc[2][c] + pacc[3][c]) / l + bias[c];
  float v1 = (pacc[0][c+1] + pacc[1][c+1] + pacc[2][c+1] + pacc[3][c+1]) / l + bias[c+1];
  unsigned o = (unsigned)f2b(leakyf(v0, 0.01f)) | ((unsigned)f2b(leakyf(v1, 0.01f)) << 16);
  *(unsigned*)(outp + (size_t)n * HC + c) = o;
}

// ---------------- weight prep: Bt[n][k] = bf16(src[k*N+n]), K padded ----------------
__global__ void k_bt(const float* __restrict__ src, unsigned short* __restrict__ bt,
                     int N, int Ks, int Kd) {
  int idx = blockIdx.x * blockDim.x + threadIdx.x;
  if (idx >= N * Kd) return;
  int n = idx / Kd, k = idx - n * Kd;
  bt[idx] = (k < Ks) ? f2b(src[(size_t)k * N + n]) : (unsigned short)0;
}

// conv weights: bt[n][k], k = tap*512+c  <- convw[n][c][di][dj]
__global__ void k_convbt(const float* __restrict__ w, unsigned short* __restrict__ bt) {
  int idx = blockIdx.x * blockDim.x + threadIdx.x;
  if (idx >= EMBED * KCONV) return;
  int n = idx / KCONV, k = idx - n * KCONV;
  int tap = k >> 9, c = k & 511;
  bt[idx] = f2b(w[(size_t)n * KCONV + c * 9 + tap]);
}

// ---------------- materialize padded local map (bf16), 16B/lane ----------------
__global__ void k_lm(const unsigned short* __restrict__ h2, unsigned short* __restrict__ lmb) {
  int idx = blockIdx.x * blockDim.x + threadIdx.x;
  if (idx >= LMROWS * 64) return;
  int c8 = (idx & 63) * 8;
  int prow = idx >> 6;
  int cc = prow % 130;
  int t = prow / 130;
  int rr = t % 66, b = t / 66;
  int gr, gc;
  if (rr == 0)       { gr = 1;      gc = (63 + cc) & 127; }
  else if (rr == 65) { gr = 62;     gc = (63 + cc) & 127; }
  else               { gr = rr - 1; gc = (cc + 127) & 127; }
  *(v8s*)(lmb + (size_t)prow * 512 + c8) =
      *(const v8s*)(h2 + ((size_t)(b * PB + 2 + gr * WWW + gc)) * HC + c8);
}

// zin[:, 0:512] = g rows (h2 without poles), 16B/lane
__global__ void k_zin_g(const unsigned short* __restrict__ h2, unsigned short* __restrict__ zin) {
  int idx = blockIdx.x * blockDim.x + threadIdx.x;
  if (idx >= NPOS * 64) return;
  int r = idx >> 6, c8 = (idx & 63) * 8;
  int b = r >> 13, pos = r & 8191;
  *(v8s*)(zin + (size_t)r * 640 + c8) =
      *(const v8s*)(h2 + ((size_t)(b * PB + 2 + pos)) * HC + c8);
}

// ---------------- bf16 MFMA GEMM, m97-style ----------------
// MODE 0: A direct (row clamped). MODE 1: conv implicit im2col from lmb.
// MODE 2: conv split-K — blockIdx.x = K-chunk; K arg = per-chunk K; C += chunk*M*ldc; no epilogue.
template<int MODE, int BM, int BN, typename OutT>
__global__ __launch_bounds__(256) void mgemm(
    int M, int N, int K, int ldb,
    const unsigned short* __restrict__ A, int lda,
    const unsigned short* __restrict__ Bt,
    const float* __restrict__ bias,
    const float* __restrict__ bnscale, const float* __restrict__ bnshift,
    float slope,
    OutT* __restrict__ C, int ldc)
{
  constexpr int WM = BM / 32;          // 16x16 frags per wave (M)
  constexpr int WN = BN / 32;          // 16x16 frags per wave (N)
  constexpr int ACH = BM * 4;          // 16B chunks per A tile
  constexpr int BCH = BN * 4;
  __shared__ unsigned short As[2][BM * 32];
  __shared__ unsigned short Bs[2][BN * 32];
  int tid = threadIdx.x;
  int wid = tid >> 6, lane = tid & 63;
  int wr = wid >> 1, wc = wid & 1;
  int l15 = lane & 15, l4 = lane >> 4;
  int row0 = blockIdx.y * BM;
  int col0, koff;
  if constexpr (MODE == 2) { col0 = 0; koff = blockIdx.x * K; C += (size_t)blockIdx.x * M * ldc; }
  else { col0 = blockIdx.x * BN; koff = 0; }

  auto stage = [&](int buf, int kt) {
    int k0 = kt * 32;
    int kg = koff + k0;
    int di = 0, dj = 0;
    if constexpr (MODE >= 1) { int tap = kg >> 9; di = tap / 3; dj = tap - di * 3; }
#pragma unroll
    for (int i = 0; i < ACH / 256; i++) {
      int c = i * 256 + tid;
      int r = c >> 2, seg = c & 3;
      const unsigned short* ga;
      if constexpr (MODE == 0) {
        int gr = min(row0 + r, M - 1);
        ga = A + (size_t)gr * lda + k0 + seg * 8;
      } else {
        int gr = row0 + r;
        int b = gr >> 13, pos = gr & 8191, ii = pos >> 7, jj = pos & 127;
        int arow = (b * 66 + ii + di) * 130 + (jj + dj);
        ga = A + (size_t)arow * 512 + (kg & 511) + seg * 8;
      }
      gload_lds16(ga, &As[buf][c * 8]);
    }
#pragma unroll
    for (int i = 0; i < BCH / 256; i++) {
      int c = i * 256 + tid;
      int r = c >> 2, seg = c & 3;
      int gn = min(col0 + r, N - 1);
      gload_lds16(Bt + (size_t)gn * ldb + kg + seg * 8, &Bs[buf][c * 8]);
    }
  };

  v4f acc[WM][WN];
#pragma unroll
  for (int m = 0; m < WM; m++)
#pragma unroll
    for (int n = 0; n < WN; n++) acc[m][n] = (v4f)0.f;

  int nt = K >> 5;
  stage(0, 0);
  __syncthreads();
  int cur = 0;
  for (int t = 0; t < nt - 1; t++) {
    stage(cur ^ 1, t + 1);
    v8s a[WM], b[WN];
#pragma unroll
    for (int m = 0; m < WM; m++)
      a[m] = *(const v8s*)(&As[cur][(wr * (BM / 2) + m * 16 + l15) * 32 + l4 * 8]);
#pragma unroll
    for (int n = 0; n < WN; n++)
      b[n] = *(const v8s*)(&Bs[cur][(wc * (BN / 2) + n * 16 + l15) * 32 + l4 * 8]);
#pragma unroll
    for (int m = 0; m < WM; m++)
#pragma unroll
      for (int n = 0; n < WN; n++)
        acc[m][n] = __builtin_amdgcn_mfma_f32_16x16x32_bf16(a[m], b[n], acc[m][n], 0, 0, 0);
    __syncthreads();   // drains vmcnt -> next buffer staged; protects reuse
    cur ^= 1;
  }
  {
    v8s a[WM], b[WN];
#pragma unroll
    for (int m = 0; m < WM; m++)
      a[m] = *(const v8s*)(&As[cur][(wr * (BM / 2) + m * 16 + l15) * 32 + l4 * 8]);
#pragma unroll
    for (int n = 0; n < WN; n++)
      b[n] = *(const v8s*)(&Bs[cur][(wc * (BN / 2) + n * 16 + l15) * 32 + l4 * 8]);
#pragma unroll
    for (int m = 0; m < WM; m++)
#pragma unroll
      for (int n = 0; n < WN; n++)
        acc[m][n] = __builtin_amdgcn_mfma_f32_16x16x32_bf16(a[m], b[n], acc[m][n], 0, 0, 0);
  }
  // epilogue: C row = (lane>>4)*4 + q, col = lane&15 (m89-verified)
#pragma unroll
  for (int m = 0; m < WM; m++) {
#pragma unroll
    for (int q = 0; q < 4; q++) {
      int r = row0 + wr * (BM / 2) + m * 16 + l4 * 4 + q;
      if (r >= M) continue;
#pragma unroll
      for (int n = 0; n < WN; n++) {
        int cc = col0 + wc * (BN / 2) + n * 16 + l15;
        if (cc >= N) continue;
        float v = acc[m][n][q];
        if constexpr (MODE != 2) {
          if (bias) v += bias[cc];
          if (bnscale) v = v * (bnscale[cc] * rsqrtf(1.f + 1e-5f)) + bnshift[cc];
          v = leakyf(v, slope);
        }
        if constexpr (std::is_same<OutT, float>::value) {
          C[(size_t)r * ldc + cc] = v;
        } else {
          C[(size_t)r * ldc + cc] = f2b(v);
        }
      }
    }
  }
}

// ---------------- conv split-K reduce: sum partials + bias + BN + leaky -> zin[:,512:640] ----------------
__global__ void k_creduce(const float* __restrict__ p, const float* __restrict__ convb,
                          const float* __restrict__ bng, const float* __restrict__ bnb,
                          unsigned short* __restrict__ zin) {
  int idx = blockIdx.x * blockDim.x + threadIdx.x;   // over NPOS*32 (x4 floats)
  if (idx >= NPOS * 32) return;
  int r = idx >> 5, c4 = (idx & 31) * 4;
  const float4* p0 = (const float4*)(p + (size_t)r * 128 + c4);
  const float4* p1 = (const float4*)(p + (size_t)(NPOS + r) * 128 + c4);
  const float4* p2 = (const float4*)(p + (size_t)(2 * NPOS + r) * 128 + c4);
  float4 a = *p0, b = *p1, c = *p2;
  unsigned short* o = zin + (size_t)r * 640 + 512 + c4;
#pragma unroll
  for (int j = 0; j < 4; j++) {
    float v = ((const float*)&a)[j] + ((const float*)&b)[j] + ((const float*)&c)[j];
    int cc = c4 + j;
    v += convb[cc];
    v = v * (bng[cc] * rsqrtf(1.f + 1e-5f)) + bnb[cc];
    o[j] = f2b(leakyf(v, 0.01f));
  }
}

// ---------------- final: out[b,t,i,j] = z3[(b*8192+p), t] + x[b, 78+t, p] ----------------
__global__ void k_final(const float* __restrict__ z3, const float* __restrict__ x,
                        float* __restrict__ outp) {
  int idx = blockIdx.x * blockDim.x + threadIdx.x;
  if (idx >= NPOS * TGT) return;
  int b = idx / (TGT * 8192);
  int rem = idx - b * (TGT * 8192);
  int t = rem >> 13;
  int p = rem & 8191;
  outp[idx] = z3[((size_t)(b * 8192 + p)) * TGT + t] + x[((size_t)(b * 117 + 78 + t)) * 8192 + p];
}

// ================================================================
extern "C" void kernel_launch(void* const* d_in, const int* in_sizes, int n_in,
                              void* d_out, int out_size, void* d_ws, size_t ws_size,
                              hipStream_t stream) {
  const float* x     = (const float*)d_in[0];
  const float* xcons = (const float*)d_in[1];
  const int*   eidx  = (const int*)d_in[2];
  const float* eattr = (const float*)d_in[3];
  const float* g1W  = (const float*)d_in[4];
  const float* g1as = (const float*)d_in[5];
  const float* g1ad = (const float*)d_in[6];
  const float* g1We = (const float*)d_in[7];
  const float* g1ae = (const float*)d_in[8];
  const float* g1b  = (const float*)d_in[9];
  const float* g2W  = (const float*)d_in[10];
  const float* g2as = (const float*)d_in[11];
  const float* g2ad = (const float*)d_in[12];
  const float* g2We = (const float*)d_in[13];
  const float* g2ae = (const float*)d_in[14];
  const float* g2b  = (const float*)d_in[15];
  const float* convw= (const float*)d_in[16];
  const float* convb= (const float*)d_in[17];
  const float* bng  = (const float*)d_in[18];
  const float* bnb  = (const float*)d_in[19];
  const float* mw1  = (const float*)d_in[20];
  const float* mb1  = (const float*)d_in[21];
  const float* mw2  = (const float*)d_in[22];
  const float* mb2  = (const float*)d_in[23];
  const float* mw3  = (const float*)d_in[24];
  const float* mb3  = (const float*)d_in[25];
  float* outp = (float*)d_out;
  (void)in_sizes; (void)n_in; (void)out_size; (void)ws_size;

  const int* esrc = eidx;
  const int* edst = eidx + NE;

  char* basep = (char*)d_ws;
  size_t off = 0;
  auto alloc = [&](size_t bytes) -> void* {
    void* p = basep + off;
    off += (bytes + 255) & ~(size_t)255;
    return p;
  };
  unsigned short* nodesb = (unsigned short*)alloc((size_t)NNODE * 128 * 2);
  unsigned short* xpb    = (unsigned short*)alloc((size_t)NNODE * HC * 2);
  unsigned short* h1b    = (unsigned short*)alloc((size_t)NNODE * HC * 2);
  unsigned short* h2b    = (unsigned short*)alloc((size_t)NNODE * HC * 2);
  unsigned short* lmb    = (unsigned short*)alloc((size_t)LMROWS * 512 * 2);
  unsigned short* zin    = (unsigned short*)alloc((size_t)NPOS * 640 * 2);
  float* cpart  = (float*)alloc((size_t)CSPLIT * NPOS * 128 * sizeof(float));
  float* asrc   = (float*)alloc((size_t)NNODE * 4 * sizeof(float));
  float* adst   = (float*)alloc((size_t)NNODE * 4 * sizeof(float));
  float* aedge  = (float*)alloc((size_t)NE * 4 * sizeof(float));
  float* aeloop = (float*)alloc((size_t)NNODE * 4 * sizeof(float));
  float* lattr  = (float*)alloc((size_t)NNODE * 8 * sizeof(float));
  float* Medge  = (float*)alloc(32 * sizeof(float));
  unsigned short* g1Wt  = (unsigned short*)alloc((size_t)512 * 128 * 2);
  unsigned short* g2Wt  = (unsigned short*)alloc((size_t)512 * 512 * 2);
  unsigned short* convWt= (unsigned short*)alloc((size_t)EMBED * KCONV * 2);
  unsigned short* mw1t  = (unsigned short*)alloc((size_t)512 * 640 * 2);
  unsigned short* mw2t  = (unsigned short*)alloc((size_t)256 * 512 * 2);
  unsigned short* mw3t  = (unsigned short*)alloc((size_t)TGT * 256 * 2);
  int* cnt      = (int*)alloc((size_t)NNODE * sizeof(int));
  int* rowptr   = (int*)alloc((size_t)(NNODE + 1) * sizeof(int));
  int* cursor   = (int*)alloc((size_t)NNODE * sizeof(int));
  int* colidx   = (int*)alloc((size_t)NE * sizeof(int));
  unsigned short* z1b = xpb;             // xpb dead after GAT2 aggregation
  unsigned short* z2b = h1b;             // h1b dead after GAT2 xp GEMM
  float*          z3  = (float*)nodesb;  // nodesb dead after GAT1 xp GEMM

  hipMemsetAsync(cnt, 0, NNODE * sizeof(int), stream);
  k_build_nodes<<<NB * 128, 256, 0, stream>>>(x, xcons, nodesb);
  k_hist<<<ceildiv(NE, 256), 256, 0, stream>>>(edst, cnt);
  k_scan<<<1, 512, 0, stream>>>(cnt, rowptr, NNODE);
  k_copy_int<<<ceildiv(NNODE, 256), 256, 0, stream>>>(rowptr, cursor, NNODE);
  k_scatter<<<ceildiv(NE, 256), 256, 0, stream>>>(edst, cursor, colidx);
  k_loop_attr<<<ceildiv(NNODE * 8, 256), 256, 0, stream>>>(eattr, rowptr, colidx, lattr);

  // weight prep
  k_bt<<<ceildiv(512 * 128, 256), 256, 0, stream>>>(g1W, g1Wt, 512, F1, 128);
  k_bt<<<ceildiv(512 * 512, 256), 256, 0, stream>>>(g2W, g2Wt, 512, 512, 512);
  k_convbt<<<ceildiv(EMBED * KCONV, 256), 256, 0, stream>>>(convw, convWt);
  k_bt<<<ceildiv(512 * 640, 256), 256, 0, stream>>>(mw1, mw1t, 512, 640, 640);
  k_bt<<<ceildiv(256 * 512, 256), 256, 0, stream>>>(mw2, mw2t, 256, 512, 512);
  k_bt<<<ceildiv(TGT * 256, 256), 256, 0, stream>>>(mw3, mw3t, TGT, 256, 256);

  // ---- GAT layer 1 ----
  k_medge<<<1, 64, 0, stream>>>(g1We, g1ae, Medge);
  k_aedge<<<ceildiv(NE * 4, 256), 256, 0, stream>>>(eattr, Medge, aedge, NE);
  k_aedge<<<ceildiv(NNODE * 4, 256), 256, 0, stream>>>(lattr, Medge, aeloop, NNODE);
  {
    dim3 g(4, ceildiv(NNODE, 128));
    mgemm<0, 128, 128, unsigned short><<<g, 256, 0, stream>>>(
        NNODE, HC, 128, 128, nodesb, 128, g1Wt, nullptr, nullptr, nullptr, 1.0f, xpb, HC);
  }
  k_attn_dots<<<ceildiv(NNODE, 4), 256, 0, stream>>>(xpb, g1as, g1ad, asrc, adst);
  k_aggregate<<<NNODE, 256, 0, stream>>>(xpb, asrc, adst, aedge, aeloop, esrc, rowptr,
                                         colidx, g1b, h1b);

  // ---- GAT layer 2 ----
  k_medge<<<1, 64, 0, stream>>>(g2We, g2ae, Medge);
  k_aedge<<<ceildiv(NE * 4, 256), 256, 0, stream>>>(eattr, Medge, aedge, NE);
  k_aedge<<<ceildiv(NNODE * 4, 256), 256, 0, stream>>>(lattr, Medge, aeloop, NNODE);
  {
    dim3 g(4, ceildiv(NNODE, 128));
    mgemm<0, 128, 128, unsigned short><<<g, 256, 0, stream>>>(
        NNODE, HC, HC, HC, h1b, HC, g2Wt, nullptr, nullptr, nullptr, 1.0f, xpb, HC);
  }
  k_attn_dots<<<ceildiv(NNODE, 4), 256, 0, stream>>>(xpb, g2as, g2ad, asrc, adst);
  k_aggregate<<<NNODE, 256, 0, stream>>>(xpb, asrc, adst, aedge, aeloop, esrc, rowptr,
                                         colidx, g2b, h2b);

  // ---- conv: materialize padded local map, split-K implicit-GEMM, reduce+BN+leaky ----
  k_lm<<<ceildiv(LMROWS * 64, 256), 256, 0, stream>>>(h2b, lmb);
  k_zin_g<<<ceildiv(NPOS * 64, 256), 256, 0, stream>>>(h2b, zin);
  {
    dim3 g(CSPLIT, ceildiv(NPOS, 64));   // 3 x 256 = 768 blocks, 3/CU
    mgemm<2, 64, 128, float><<<g, 256, 0, stream>>>(
        NPOS, EMBED, KCONV / CSPLIT, KCONV, lmb, 512, convWt,
        nullptr, nullptr, nullptr, 1.0f, cpart, EMBED);
  }
  k_creduce<<<ceildiv(NPOS * 32, 256), 256, 0, stream>>>(cpart, convb, bng, bnb, zin);

  // ---- MLP ----
  {
    dim3 g(4, ceildiv(NPOS, 128));
    mgemm<0, 128, 128, unsigned short><<<g, 256, 0, stream>>>(
        NPOS, 512, 640, 640, zin, 640, mw1t, mb1, nullptr, nullptr, 0.01f, z1b, 512);
  }
  {
    dim3 g(2, ceildiv(NPOS, 64));   // 512 blocks
    mgemm<0, 64, 128, unsigned short><<<g, 256, 0, stream>>>(
        NPOS, 256, 512, 512, z1b, 512, mw2t, mb2, nullptr, nullptr, 0.01f, z2b, 256);
  }
  {
    dim3 g(1, ceildiv(NPOS, 64));   // 256 blocks
    mgemm<0, 64, 64, float><<<g, 256, 0, stream>>>(
        NPOS, TGT, 256, 256, z2b, 256, mw3t, mb3, nullptr, nullptr, 1.0f, z3, TGT);
  }

  k_final<<<ceildiv(NPOS * TGT, 256), 256, 0, stream>>>(z3, x, outp);
}

// Round 7
// 349.874 us; speedup vs baseline: 5.1976x; 1.0107x over previous
//
#include <hip/hip_runtime.h>
#include <math.h>
#include <type_traits>

// ---- problem constants ----
#define NB    2
#define HHH   64
#define WWW   128
#define F1    123      // 117 + 6
#define HC    512      // heads*hid
#define NE    131072
#define PB    8194     // nodes per batch (8192 + 2 poles)
#define NNODE (NB*PB)  // 16388
#define NPOS  (NB*HHH*WWW) // 16384
#define TGT   39
#define EMBED 128
#define KCONV 4608     // 512*9
#define LMROWS (2*66*130)
#define CSPLIT 3       // conv split-K chunks (3 taps each)

static inline int ceildiv(int a, int b){ return (a + b - 1) / b; }

typedef short v8s __attribute__((ext_vector_type(8)));
typedef float v4f __attribute__((ext_vector_type(4)));

__device__ __forceinline__ float leakyf(float x, float s){ return x >= 0.f ? x : s * x; }

__device__ __forceinline__ unsigned short f2b(float f) {
  unsigned u = __builtin_bit_cast(unsigned, f);
  u = (u + 0x7FFFu + ((u >> 16) & 1u)) >> 16;
  return (unsigned short)u;
}
__device__ __forceinline__ float b2f(unsigned short h) {
  unsigned u = ((unsigned)h) << 16;
  return __builtin_bit_cast(float, u);
}

// async global->LDS, 16 bytes per lane (dest = wave-uniform base + lane*16)
__device__ __forceinline__ void gload_lds16(const void* g, void* l) {
  __builtin_amdgcn_global_load_lds((const __attribute__((address_space(1))) void*)g,
                                   (__attribute__((address_space(3))) void*)l, 16, 0, 0);
}

// ---------------- build node features (bf16, K padded 123->128) ----------------
__global__ __launch_bounds__(256) void k_build_nodes(const float* __restrict__ x,
                                                     const float* __restrict__ xc,
                                                     unsigned short* __restrict__ nodes) {
  __shared__ unsigned short lds[64][130];
  int blk = blockIdx.x;             // NB*128 blocks
  int b = blk >> 7, p0 = (blk & 127) * 64;
  int tid = threadIdx.x;
  int pi = tid & 63, cg = tid >> 6;
  for (int c = cg; c < 128; c += 4) {
    float v = 0.f;
    int p = p0 + pi;
    if (c < 117)      v = x[((size_t)(b * 117 + c)) * 8192 + p];
    else if (c < 123) v = xc[((size_t)(b * 6 + (c - 117))) * 8192 + p];
    lds[pi][c] = f2b(v);
  }
  // zero pole rows once per batch
  if ((blk & 127) == 0 && tid < 32) {
    int rr = tid >> 4, sg = tid & 15;
    *(v8s*)(nodes + ((size_t)(b * PB + rr)) * 128 + sg * 8) = (v8s)0;
  }
  __syncthreads();
  int seg = tid & 15, r0 = tid >> 4;
  for (int rr = r0; rr < 64; rr += 16) {
    int node = b * PB + 2 + p0 + rr;
    *(v8s*)(nodes + (size_t)node * 128 + seg * 8) = *(const v8s*)(&lds[rr][seg * 8]);
  }
}

// ---------------- CSR build ----------------
__global__ void k_hist(const int* __restrict__ dst, int* __restrict__ cnt) {
  int e = blockIdx.x * blockDim.x + threadIdx.x;
  if (e >= NE) return;
  atomicAdd(&cnt[dst[e]], 1);
}

__global__ void k_scan(const int* __restrict__ cnt, int* __restrict__ rowptr, int n) {
  __shared__ int part[512];
  int t = threadIdx.x;
  int chunk = (n + 511) >> 9;
  int beg = t * chunk, end = min(beg + chunk, n);
  int s = 0;
  for (int i = beg; i < end; i++) s += cnt[i];
  part[t] = s;
  __syncthreads();
  int own = s;
  for (int off = 1; off < 512; off <<= 1) {
    int v = 0;
    if (t >= off) v = part[t - off];
    __syncthreads();
    part[t] += v;
    __syncthreads();
  }
  int run = part[t] - own;   // exclusive prefix
  for (int i = beg; i < end; i++) { rowptr[i] = run; run += cnt[i]; }
  if (t == 511) rowptr[n] = part[511];
}

__global__ void k_copy_int(const int* __restrict__ a, int* __restrict__ b, int n) {
  int i = blockIdx.x * blockDim.x + threadIdx.x;
  if (i < n) b[i] = a[i];
}

__global__ void k_scatter(const int* __restrict__ dst, int* __restrict__ cursor,
                          int* __restrict__ colidx) {
  int e = blockIdx.x * blockDim.x + threadIdx.x;
  if (e >= NE) return;
  int pos = atomicAdd(&cursor[dst[e]], 1);
  colidx[pos] = e;
}

// loop_attr[n][k] = mean over incoming edges of edge_attr (0-safe divide)
__global__ void k_loop_attr(const float* __restrict__ eattr, const int* __restrict__ rowptr,
                            const int* __restrict__ colidx, float* __restrict__ lattr) {
  int idx = blockIdx.x * blockDim.x + threadIdx.x;
  if (idx >= NNODE * 8) return;
  int nn = idx >> 3, k = idx & 7;
  int b = rowptr[nn], e = rowptr[nn + 1];
  float s = 0.f;
  for (int i = b; i < e; i++) s += eattr[(size_t)colidx[i] * 8 + k];
  int c = e - b;
  lattr[idx] = s / (float)max(c, 1);
}

// ---------------- edge attention precompute ----------------
__global__ void k_medge(const float* __restrict__ We, const float* __restrict__ ae,
                        float* __restrict__ M) {
  int t = threadIdx.x;
  if (t >= 32) return;
  int k = t >> 2, h = t & 3;
  float s = 0.f;
  for (int c = 0; c < 128; c++) s += We[k * 512 + h * 128 + c] * ae[h * 128 + c];
  M[t] = s;
}

__global__ void k_aedge(const float* __restrict__ attr, const float* __restrict__ M,
                        float* __restrict__ out, int n) {
  int idx = blockIdx.x * blockDim.x + threadIdx.x;
  if (idx >= n * 4) return;
  int e = idx >> 2, h = idx & 3;
  float s = 0.f;
#pragma unroll
  for (int k = 0; k < 8; k++) s += attr[(size_t)e * 8 + k] * M[k * 4 + h];
  out[idx] = s;
}

// a_src[n,h] = xp[n,h,:].att_src[h,:] from bf16 xp — one wave per node, 16B loads
__global__ void k_attn_dots(const unsigned short* __restrict__ xp, const float* __restrict__ as,
                            const float* __restrict__ ad, float* __restrict__ a_src,
                            float* __restrict__ a_dst) {
  int gw = (blockIdx.x * blockDim.x + threadIdx.x) >> 6;
  int lane = threadIdx.x & 63;
  if (gw >= NNODE) return;
  int h = lane >> 4;
  int c0 = (lane & 15) * 8;
  v8s v = *(const v8s*)(xp + (size_t)gw * HC + h * 128 + c0);
  const float* asr = as + h * 128 + c0;
  const float* adr = ad + h * 128 + c0;
  float s1 = 0.f, s2 = 0.f;
#pragma unroll
  for (int i = 0; i < 8; i++) {
    float f = b2f((unsigned short)v[i]);
    s1 += f * asr[i]; s2 += f * adr[i];
  }
  for (int off = 1; off < 16; off <<= 1) { s1 += __shfl_xor(s1, off); s2 += __shfl_xor(s2, off); }
  if ((lane & 15) == 0) { a_src[gw * 4 + h] = s1; a_dst[gw * 4 + h] = s2; }
}

// ---------------- GAT aggregation v2 ----------------
// One block per node; waves stride over edges with full-row 16B loads;
// wave-parallel online softmax; cross-wave combine via LDS.
// ldo/pole: pole=1 -> skip pole nodes, remap row to b*8192+(loc-2) (GAT2 -> zin).
__global__ __launch_bounds__(256) void k_aggregate(
    const unsigned short* __restrict__ xp, const float* __restrict__ a_src,
    const float* __restrict__ a_dst, const float* __restrict__ a_edge,
    const float* __restrict__ a_eloop, const int* __restrict__ srcv,
    const int* __restrict__ rowptr, const int* __restrict__ colidx,
    const float* __restrict__ bias, unsigned short* __restrict__ outp,
    int ldo, int pole) {
  int n = blockIdx.x;
  int tid = threadIdx.x;
  int wid = tid >> 6, lane = tid & 63;
  __shared__ float sh_w[64][4];
  __shared__ int   sh_s[64];
  __shared__ float sh_m[4], sh_l[4], sh_r[4];
  __shared__ float pacc[4][512];
  if (pole) {
    int b = n / PB, loc = n - b * PB;
    if (loc < 2) return;
    outp += (size_t)(b * 8192 + loc - 2) * ldo;
  } else {
    outp += (size_t)n * ldo;
  }
  int beg = rowptr[n], deg = rowptr[n + 1] - beg;
  int total = deg + 1;  // + self loop
  if (tid < 4) { sh_m[tid] = -1e30f; sh_l[tid] = 0.f; }
  float acc[8] = {0.f, 0.f, 0.f, 0.f, 0.f, 0.f, 0.f, 0.f};
  int c0 = lane * 8;       // this lane's 8 channels
  int hh = lane >> 4;      // head of those channels
  float adn = a_dst[(size_t)n * 4 + (tid & 3)];  // used only by alpha threads
  __syncthreads();
  for (int base = 0; base < total; base += 64) {
    int cnt = min(64, total - base);
    // ---- raw alpha ----
    if (tid < cnt * 4) {
      int le = tid >> 2, h = tid & 3;
      int ge = base + le;
      int sn; float ae;
      if (ge < deg) { int eid = colidx[beg + ge]; sn = srcv[eid]; ae = a_edge[(size_t)eid * 4 + h]; }
      else          { sn = n; ae = a_eloop[(size_t)n * 4 + h]; }
      float al = a_src[(size_t)sn * 4 + h] + adn + ae;
      sh_w[le][h] = leakyf(al, 0.2f);
      if (h == 0) sh_s[le] = sn;
    }
    __syncthreads();
    // ---- online softmax: wave wid handles head wid ----
    {
      int h = wid;
      float a = (lane < cnt) ? sh_w[lane][h] : -1e30f;
      float cm = a;
#pragma unroll
      for (int off = 1; off < 64; off <<= 1) cm = fmaxf(cm, __shfl_xor(cm, off));
      float m_old = sh_m[h];
      float nm = fmaxf(m_old, cm);
      float ex = (lane < cnt) ? __expf(a - nm) : 0.f;
      float s = ex;
#pragma unroll
      for (int off = 1; off < 64; off <<= 1) s += __shfl_xor(s, off);
      if (lane < cnt) sh_w[lane][h] = ex;
      if (lane == 0) {
        float r = __expf(m_old - nm);
        sh_r[h] = r; sh_m[h] = nm; sh_l[h] = sh_l[h] * r + s;
      }
    }
    __syncthreads();
    // ---- gather: wave strides over edges, 16B row loads ----
    float r = sh_r[hh];
#pragma unroll
    for (int j = 0; j < 8; j++) acc[j] *= r;
    for (int e = wid; e < cnt; e += 4) {
      int sn = sh_s[e];
      float wt = sh_w[e][hh];
      v8s v = *(const v8s*)(xp + (size_t)sn * HC + c0);
#pragma unroll
      for (int j = 0; j < 8; j++) acc[j] += wt * b2f((unsigned short)v[j]);
    }
    __syncthreads();   // sh_w reused next chunk
  }
  // ---- cross-wave combine ----
  *(v4f*)(&pacc[wid][c0])     = *(const v4f*)(&acc[0]);
  *(v4f*)(&pacc[wid][c0 + 4]) = *(const v4f*)(&acc[4]);
  __syncthreads();
  int c = tid * 2;
  float l = sh_l[c >> 7];
  float v0 = (pacc[0][c] + pacc[1][c] + pacc[2][c] + pacc[3][c]) / l + bias[c];
  float v1 = (pacc[0][c+1] + pacc[1][c+1] + pacc[2][c+1] + pacc[3][c+1]) / l + bias[c+1];
  unsigned o = (unsigned)f2b(leakyf(v0, 0.01f)) | ((unsigned)f2b(leakyf(v1, 0.01f)) << 16);
  *(unsigned*)(outp + c) = o;
}

// ---------------- weight prep: Bt[n][k] = bf16(src[k*N+n]), K padded ----------------
__global__ void k_bt(const float* __restrict__ src, unsigned short* __restrict__ bt,
                     int N, int Ks, int Kd) {
  int idx = blockIdx.x * blockDim.x + threadIdx.x;
  if (idx >= N * Kd) return;
  int n = idx / Kd, k = idx - n * Kd;
  bt[idx] = (k < Ks) ? f2b(src[(size_t)k * N + n]) : (unsigned short)0;
}

// conv weights: bt[n][k], k = tap*512+c  <- convw[n][c][di][dj]
__global__ void k_convbt(const float* __restrict__ w, unsigned short* __restrict__ bt) {
  int idx = blockIdx.x * blockDim.x + threadIdx.x;
  if (idx >= EMBED * KCONV) return;
  int n = idx / KCONV, k = idx - n * KCONV;
  int tap = k >> 9, c = k & 511;
  bt[idx] = f2b(w[(size_t)n * KCONV + c * 9 + tap]);
}

// ---------------- materialize padded local map (bf16) from zin[:,0:512], 16B/lane ----------------
__global__ void k_lm(const unsigned short* __restrict__ zin, unsigned short* __restrict__ lmb) {
  int idx = blockIdx.x * blockDim.x + threadIdx.x;
  if (idx >= LMROWS * 64) return;
  int c8 = (idx & 63) * 8;
  int prow = idx >> 6;
  int cc = prow % 130;
  int t = prow / 130;
  int rr = t % 66, b = t / 66;
  int gr, gc;
  if (rr == 0)       { gr = 1;      gc = (63 + cc) & 127; }
  else if (rr == 65) { gr = 62;     gc = (63 + cc) & 127; }
  else               { gr = rr - 1; gc = (cc + 127) & 127; }
  *(v8s*)(lmb + (size_t)prow * 512 + c8) =
      *(const v8s*)(zin + ((size_t)(b * 8192 + gr * WWW + gc)) * 640 + c8);
}

// ---------------- bf16 MFMA GEMM, m97-style + LDS XOR swizzle (T2, rule #21) ----------------
// LDS chunk layout: chunk q = r*4 + (seg ^ (r&3)) holds global 16B-chunk (r, seg).
// Staging pre-swizzles the GLOBAL source (linear gload_lds dest); reads XOR the slot.
// MODE 0: A direct (row clamped). MODE 2: conv split-K over blockIdx.x chunks.
template<int MODE, int BM, int BN, typename OutT>
__global__ __launch_bounds__(256) void mgemm(
    int M, int N, int K, int ldb,
    const unsigned short* __restrict__ A, int lda,
    const unsigned short* __restrict__ Bt,
    const float* __restrict__ bias,
    const float* __restrict__ bnscale, const float* __restrict__ bnshift,
    float slope,
    OutT* __restrict__ C, int ldc)
{
  constexpr int WM = BM / 32;          // 16x16 frags per wave (M)
  constexpr int WN = BN / 32;          // 16x16 frags per wave (N)
  constexpr int ACH = BM * 4;          // 16B chunks per A tile
  constexpr int BCH = BN * 4;
  __shared__ unsigned short As[2][BM * 32];
  __shared__ unsigned short Bs[2][BN * 32];
  int tid = threadIdx.x;
  int wid = tid >> 6, lane = tid & 63;
  int wr = wid >> 1, wc = wid & 1;
  int l15 = lane & 15, l4 = lane >> 4;
  int slot8 = (l4 ^ (l15 & 3)) * 8;    // swizzled k-slot for fragment reads
  int row0 = blockIdx.y * BM;
  int col0, koff;
  if constexpr (MODE == 2) { col0 = 0; koff = blockIdx.x * K; C += (size_t)blockIdx.x * M * ldc; }
  else { col0 = blockIdx.x * BN; koff = 0; }

  auto stage = [&](int buf, int kt) {
    int k0 = kt * 32;
    int kg = koff + k0;
    int di = 0, dj = 0;
    if constexpr (MODE >= 1) { int tap = kg >> 9; di = tap / 3; dj = tap - di * 3; }
#pragma unroll
    for (int i = 0; i < ACH / 256; i++) {
      int c = i * 256 + tid;
      int r = c >> 2;
      int seg = (c & 3) ^ (r & 3);     // source pre-swizzle
      const unsigned short* ga;
      if constexpr (MODE == 0) {
        int gr = min(row0 + r, M - 1);
        ga = A + (size_t)gr * lda + k0 + seg * 8;
      } else {
        int gr = row0 + r;
        int b = gr >> 13, pos = gr & 8191, ii = pos >> 7, jj = pos & 127;
        int arow = (b * 66 + ii + di) * 130 + (jj + dj);
        ga = A + (size_t)arow * 512 + (kg & 511) + seg * 8;
      }
      gload_lds16(ga, &As[buf][c * 8]);
    }
#pragma unroll
    for (int i = 0; i < BCH / 256; i++) {
      int c = i * 256 + tid;
      int r = c >> 2;
      int seg = (c & 3) ^ (r & 3);     // source pre-swizzle
      int gn = min(col0 + r, N - 1);
      gload_lds16(Bt + (size_t)gn * ldb + kg + seg * 8, &Bs[buf][c * 8]);
    }
  };

  v4f acc[WM][WN];
#pragma unroll
  for (int m = 0; m < WM; m++)
#pragma unroll
    for (int n = 0; n < WN; n++) acc[m][n] = (v4f)0.f;

  int nt = K >> 5;
  stage(0, 0);
  __syncthreads();
  int cur = 0;
  for (int t = 0; t < nt - 1; t++) {
    stage(cur ^ 1, t + 1);
    v8s a[WM], b[WN];
#pragma unroll
    for (int m = 0; m < WM; m++)
      a[m] = *(const v8s*)(&As[cur][(wr * (BM / 2) + m * 16 + l15) * 32 + slot8]);
#pragma unroll
    for (int n = 0; n < WN; n++)
      b[n] = *(const v8s*)(&Bs[cur][(wc * (BN / 2) + n * 16 + l15) * 32 + slot8]);
#pragma unroll
    for (int m = 0; m < WM; m++)
#pragma unroll
      for (int n = 0; n < WN; n++)
        acc[m][n] = __builtin_amdgcn_mfma_f32_16x16x32_bf16(a[m], b[n], acc[m][n], 0, 0, 0);
    __syncthreads();   // drains vmcnt -> next buffer staged; protects reuse
    cur ^= 1;
  }
  {
    v8s a[WM], b[WN];
#pragma unroll
    for (int m = 0; m < WM; m++)
      a[m] = *(const v8s*)(&As[cur][(wr * (BM / 2) + m * 16 + l15) * 32 + slot8]);
#pragma unroll
    for (int n = 0; n < WN; n++)
      b[n] = *(const v8s*)(&Bs[cur][(wc * (BN / 2) + n * 16 + l15) * 32 + slot8]);
#pragma unroll
    for (int m = 0; m < WM; m++)
#pragma unroll
      for (int n = 0; n < WN; n++)
        acc[m][n] = __builtin_amdgcn_mfma_f32_16x16x32_bf16(a[m], b[n], acc[m][n], 0, 0, 0);
  }
  // epilogue: C row = (lane>>4)*4 + q, col = lane&15 (m89-verified)
#pragma unroll
  for (int m = 0; m < WM; m++) {
#pragma unroll
    for (int q = 0; q < 4; q++) {
      int r = row0 + wr * (BM / 2) + m * 16 + l4 * 4 + q;
      if (r >= M) continue;
#pragma unroll
      for (int n = 0; n < WN; n++) {
        int cc = col0 + wc * (BN / 2) + n * 16 + l15;
        if (cc >= N) continue;
        float v = acc[m][n][q];
        if constexpr (MODE != 2) {
          if (bias) v += bias[cc];
          if (bnscale) v = v * (bnscale[cc] * rsqrtf(1.f + 1e-5f)) + bnshift[cc];
          v = leakyf(v, slope);
        }
        if constexpr (std::is_same<OutT, float>::value) {
          C[(size_t)r * ldc + cc] = v;
        } else {
          C[(size_t)r * ldc + cc] = f2b(v);
        }
      }
    }
  }
}

// ---------------- conv split-K reduce: sum partials + bias + BN + leaky -> zin[:,512:640] ----------------
__global__ void k_creduce(const float* __restrict__ p, const float* __restrict__ convb,
                          const float* __restrict__ bng, const float* __restrict__ bnb,
                          unsigned short* __restrict__ zin) {
  int idx = blockIdx.x * blockDim.x + threadIdx.x;   // over NPOS*32 (x4 floats)
  if (idx >= NPOS * 32) return;
  int r = idx >> 5, c4 = (idx & 31) * 4;
  const float4* p0 = (const float4*)(p + (size_t)r * 128 + c4);
  const float4* p1 = (const float4*)(p + (size_t)(NPOS + r) * 128 + c4);
  const float4* p2 = (const float4*)(p + (size_t)(2 * NPOS + r) * 128 + c4);
  float4 a = *p0, b = *p1, c = *p2;
  unsigned short* o = zin + (size_t)r * 640 + 512 + c4;
#pragma unroll
  for (int j = 0; j < 4; j++) {
    float v = ((const float*)&a)[j] + ((const float*)&b)[j] + ((const float*)&c)[j];
    int cc = c4 + j;
    v += convb[cc];
    v = v * (bng[cc] * rsqrtf(1.f + 1e-5f)) + bnb[cc];
    o[j] = f2b(leakyf(v, 0.01f));
  }
}

// ---------------- final: out[b,t,i,j] = z3[(b*8192+p), t] + x[b, 78+t, p] ----------------
__global__ void k_final(const float* __restrict__ z3, const float* __restrict__ x,
                        float* __restrict__ outp) {
  int idx = blockIdx.x * blockDim.x + threadIdx.x;
  if (idx >= NPOS * TGT) return;
  int b = idx / (TGT * 8192);
  int rem = idx - b * (TGT * 8192);
  int t = rem >> 13;
  int p = rem & 8191;
  outp[idx] = z3[((size_t)(b * 8192 + p)) * TGT + t] + x[((size_t)(b * 117 + 78 + t)) * 8192 + p];
}

// ================================================================
extern "C" void kernel_launch(void* const* d_in, const int* in_sizes, int n_in,
                              void* d_out, int out_size, void* d_ws, size_t ws_size,
                              hipStream_t stream) {
  const float* x     = (const float*)d_in[0];
  const float* xcons = (const float*)d_in[1];
  const int*   eidx  = (const int*)d_in[2];
  const float* eattr = (const float*)d_in[3];
  const float* g1W  = (const float*)d_in[4];
  const float* g1as = (const float*)d_in[5];
  const float* g1ad = (const float*)d_in[6];
  const float* g1We = (const float*)d_in[7];
  const float* g1ae = (const float*)d_in[8];
  const float* g1b  = (const float*)d_in[9];
  const float* g2W  = (const float*)d_in[10];
  const float* g2as = (const float*)d_in[11];
  const float* g2ad = (const float*)d_in[12];
  const float* g2We = (const float*)d_in[13];
  const float* g2ae = (const float*)d_in[14];
  const float* g2b  = (const float*)d_in[15];
  const float* convw= (const float*)d_in[16];
  const float* convb= (const float*)d_in[17];
  const float* bng  = (const float*)d_in[18];
  const float* bnb  = (const float*)d_in[19];
  const float* mw1  = (const float*)d_in[20];
  const float* mb1  = (const float*)d_in[21];
  const float* mw2  = (const float*)d_in[22];
  const float* mb2  = (const float*)d_in[23];
  const float* mw3  = (const float*)d_in[24];
  const float* mb3  = (const float*)d_in[25];
  float* outp = (float*)d_out;
  (void)in_sizes; (void)n_in; (void)out_size; (void)ws_size;

  const int* esrc = eidx;
  const int* edst = eidx + NE;

  char* basep = (char*)d_ws;
  size_t off = 0;
  auto alloc = [&](size_t bytes) -> void* {
    void* p = basep + off;
    off += (bytes + 255) & ~(size_t)255;
    return p;
  };
  unsigned short* nodesb = (unsigned short*)alloc((size_t)NNODE * 128 * 2);
  unsigned short* xpb    = (unsigned short*)alloc((size_t)NNODE * HC * 2);
  unsigned short* h1b    = (unsigned short*)alloc((size_t)NNODE * HC * 2);
  unsigned short* lmb    = (unsigned short*)alloc((size_t)LMROWS * 512 * 2);
  unsigned short* zin    = (unsigned short*)alloc((size_t)NPOS * 640 * 2);
  float* cpart  = (float*)alloc((size_t)CSPLIT * NPOS * 128 * sizeof(float));
  float* asrc   = (float*)alloc((size_t)NNODE * 4 * sizeof(float));
  float* adst   = (float*)alloc((size_t)NNODE * 4 * sizeof(float));
  float* aedge  = (float*)alloc((size_t)NE * 4 * sizeof(float));
  float* aeloop = (float*)alloc((size_t)NNODE * 4 * sizeof(float));
  float* lattr  = (float*)alloc((size_t)NNODE * 8 * sizeof(float));
  float* Medge  = (float*)alloc(32 * sizeof(float));
  unsigned short* g1Wt  = (unsigned short*)alloc((size_t)512 * 128 * 2);
  unsigned short* g2Wt  = (unsigned short*)alloc((size_t)512 * 512 * 2);
  unsigned short* convWt= (unsigned short*)alloc((size_t)EMBED * KCONV * 2);
  unsigned short* mw1t  = (unsigned short*)alloc((size_t)512 * 640 * 2);
  unsigned short* mw2t  = (unsigned short*)alloc((size_t)256 * 512 * 2);
  unsigned short* mw3t  = (unsigned short*)alloc((size_t)TGT * 256 * 2);
  int* cnt      = (int*)alloc((size_t)NNODE * sizeof(int));
  int* rowptr   = (int*)alloc((size_t)(NNODE + 1) * sizeof(int));
  int* cursor   = (int*)alloc((size_t)NNODE * sizeof(int));
  int* colidx   = (int*)alloc((size_t)NE * sizeof(int));
  unsigned short* z1b = xpb;             // xpb dead after GAT2 aggregation
  unsigned short* z2b = h1b;             // h1b dead after GAT2 xp GEMM
  float*          z3  = (float*)nodesb;  // nodesb dead after GAT1 xp GEMM

  hipMemsetAsync(cnt, 0, NNODE * sizeof(int), stream);
  k_build_nodes<<<NB * 128, 256, 0, stream>>>(x, xcons, nodesb);
  k_hist<<<ceildiv(NE, 256), 256, 0, stream>>>(edst, cnt);
  k_scan<<<1, 512, 0, stream>>>(cnt, rowptr, NNODE);
  k_copy_int<<<ceildiv(NNODE, 256), 256, 0, stream>>>(rowptr, cursor, NNODE);
  k_scatter<<<ceildiv(NE, 256), 256, 0, stream>>>(edst, cursor, colidx);
  k_loop_attr<<<ceildiv(NNODE * 8, 256), 256, 0, stream>>>(eattr, rowptr, colidx, lattr);

  // weight prep
  k_bt<<<ceildiv(512 * 128, 256), 256, 0, stream>>>(g1W, g1Wt, 512, F1, 128);
  k_bt<<<ceildiv(512 * 512, 256), 256, 0, stream>>>(g2W, g2Wt, 512, 512, 512);
  k_convbt<<<ceildiv(EMBED * KCONV, 256), 256, 0, stream>>>(convw, convWt);
  k_bt<<<ceildiv(512 * 640, 256), 256, 0, stream>>>(mw1, mw1t, 512, 640, 640);
  k_bt<<<ceildiv(256 * 512, 256), 256, 0, stream>>>(mw2, mw2t, 256, 512, 512);
  k_bt<<<ceildiv(TGT * 256, 256), 256, 0, stream>>>(mw3, mw3t, TGT, 256, 256);

  // ---- GAT layer 1 ----
  k_medge<<<1, 64, 0, stream>>>(g1We, g1ae, Medge);
  k_aedge<<<ceildiv(NE * 4, 256), 256, 0, stream>>>(eattr, Medge, aedge, NE);
  k_aedge<<<ceildiv(NNODE * 4, 256), 256, 0, stream>>>(lattr, Medge, aeloop, NNODE);
  {
    dim3 g(4, ceildiv(NNODE, 128));
    mgemm<0, 128, 128, unsigned short><<<g, 256, 0, stream>>>(
        NNODE, HC, 128, 128, nodesb, 128, g1Wt, nullptr, nullptr, nullptr, 1.0f, xpb, HC);
  }
  k_attn_dots<<<ceildiv(NNODE, 4), 256, 0, stream>>>(xpb, g1as, g1ad, asrc, adst);
  k_aggregate<<<NNODE, 256, 0, stream>>>(xpb, asrc, adst, aedge, aeloop, esrc, rowptr,
                                         colidx, g1b, h1b, HC, 0);

  // ---- GAT layer 2 (aggregation writes zin[:,0:512] directly, poles dropped) ----
  k_medge<<<1, 64, 0, stream>>>(g2We, g2ae, Medge);
  k_aedge<<<ceildiv(NE * 4, 256), 256, 0, stream>>>(eattr, Medge, aedge, NE);
  k_aedge<<<ceildiv(NNODE * 4, 256), 256, 0, stream>>>(lattr, Medge, aeloop, NNODE);
  {
    dim3 g(4, ceildiv(NNODE, 128));
    mgemm<0, 128, 128, unsigned short><<<g, 256, 0, stream>>>(
        NNODE, HC, HC, HC, h1b, HC, g2Wt, nullptr, nullptr, nullptr, 1.0f, xpb, HC);
  }
  k_attn_dots<<<ceildiv(NNODE, 4), 256, 0, stream>>>(xpb, g2as, g2ad, asrc, adst);
  k_aggregate<<<NNODE, 256, 0, stream>>>(xpb, asrc, adst, aedge, aeloop, esrc, rowptr,
                                         colidx, g2b, zin, 640, 1);

  // ---- conv: materialize padded local map, split-K implicit-GEMM, reduce+BN+leaky ----
  k_lm<<<ceildiv(LMROWS * 64, 256), 256, 0, stream>>>(zin, lmb);
  {
    dim3 g(CSPLIT, ceildiv(NPOS, 64));   // 3 x 256 = 768 blocks, 3/CU
    mgemm<2, 64, 128, float><<<g, 256, 0, stream>>>(
        NPOS, EMBED, KCONV / CSPLIT, KCONV, lmb, 512, convWt,
        nullptr, nullptr, nullptr, 1.0f, cpart, EMBED);
  }
  k_creduce<<<ceildiv(NPOS * 32, 256), 256, 0, stream>>>(cpart, convb, bng, bnb, zin);

  // ---- MLP ----
  {
    dim3 g(4, ceildiv(NPOS, 128));
    mgemm<0, 128, 128, unsigned short><<<g, 256, 0, stream>>>(
        NPOS, 512, 640, 640, zin, 640, mw1t, mb1, nullptr, nullptr, 0.01f, z1b, 512);
  }
  {
    dim3 g(2, ceildiv(NPOS, 64));   // 512 blocks
    mgemm<0, 64, 128, unsigned short><<<g, 256, 0, stream>>>(
        NPOS, 256, 512, 512, z1b, 512, mw2t, mb2, nullptr, nullptr, 0.01f, z2b, 256);
  }
  {
    dim3 g(1, ceildiv(NPOS, 64));   // 256 blocks
    mgemm<0, 64, 64, float><<<g, 256, 0, stream>>>(
        NPOS, TGT, 256, 256, z2b, 256, mw3t, mb3, nullptr, nullptr, 1.0f, z3, TGT);
  }

  k_final<<<ceildiv(NPOS * TGT, 256), 256, 0, stream>>>(z3, x, outp);
}

// Round 8
// 330.977 us; speedup vs baseline: 5.4943x; 1.0571x over previous
//
#include <hip/hip_runtime.h>
#include <math.h>
#include <type_traits>

// ---- problem constants ----
#define NB    2
#define HHH   64
#define WWW   128
#define F1    123      // 117 + 6
#define HC    512      // heads*hid
#define NE    131072
#define PB    8194     // nodes per batch (8192 + 2 poles)
#define NNODE (NB*PB)  // 16388
#define NPOS  (NB*HHH*WWW) // 16384
#define TGT   39
#define EMBED 128
#define KCONV 4608     // 512*9
#define NTAPK 1152     // 9*128 tap-major conv output width

static inline int ceildiv(int a, int b){ return (a + b - 1) / b; }

typedef short v8s __attribute__((ext_vector_type(8)));
typedef float v4f __attribute__((ext_vector_type(4)));

__device__ __forceinline__ float leakyf(float x, float s){ return x >= 0.f ? x : s * x; }

__device__ __forceinline__ unsigned short f2b(float f) {
  unsigned u = __builtin_bit_cast(unsigned, f);
  u = (u + 0x7FFFu + ((u >> 16) & 1u)) >> 16;
  return (unsigned short)u;
}
__device__ __forceinline__ float b2f(unsigned short h) {
  unsigned u = ((unsigned)h) << 16;
  return __builtin_bit_cast(float, u);
}

// async global->LDS, 16 bytes per lane (dest = wave-uniform base + lane*16)
__device__ __forceinline__ void gload_lds16(const void* g, void* l) {
  __builtin_amdgcn_global_load_lds((const __attribute__((address_space(1))) void*)g,
                                   (__attribute__((address_space(3))) void*)l, 16, 0, 0);
}

// ---------------- build node features (bf16, K padded 123->128) ----------------
__global__ __launch_bounds__(256) void k_build_nodes(const float* __restrict__ x,
                                                     const float* __restrict__ xc,
                                                     unsigned short* __restrict__ nodes) {
  __shared__ unsigned short lds[64][130];
  int blk = blockIdx.x;             // NB*128 blocks
  int b = blk >> 7, p0 = (blk & 127) * 64;
  int tid = threadIdx.x;
  int pi = tid & 63, cg = tid >> 6;
  for (int c = cg; c < 128; c += 4) {
    float v = 0.f;
    int p = p0 + pi;
    if (c < 117)      v = x[((size_t)(b * 117 + c)) * 8192 + p];
    else if (c < 123) v = xc[((size_t)(b * 6 + (c - 117))) * 8192 + p];
    lds[pi][c] = f2b(v);
  }
  if ((blk & 127) == 0 && tid < 32) {
    int rr = tid >> 4, sg = tid & 15;
    *(v8s*)(nodes + ((size_t)(b * PB + rr)) * 128 + sg * 8) = (v8s)0;
  }
  __syncthreads();
  int seg = tid & 15, r0 = tid >> 4;
  for (int rr = r0; rr < 64; rr += 16) {
    int node = b * PB + 2 + p0 + rr;
    *(v8s*)(nodes + (size_t)node * 128 + seg * 8) = *(const v8s*)(&lds[rr][seg * 8]);
  }
}

// ---------------- CSR build ----------------
__global__ void k_hist(const int* __restrict__ dst, int* __restrict__ cnt) {
  int e = blockIdx.x * blockDim.x + threadIdx.x;
  if (e >= NE) return;
  atomicAdd(&cnt[dst[e]], 1);
}

__global__ void k_scan(const int* __restrict__ cnt, int* __restrict__ rowptr, int n) {
  __shared__ int part[512];
  int t = threadIdx.x;
  int chunk = (n + 511) >> 9;
  int beg = t * chunk, end = min(beg + chunk, n);
  int s = 0;
  for (int i = beg; i < end; i++) s += cnt[i];
  part[t] = s;
  __syncthreads();
  int own = s;
  for (int off = 1; off < 512; off <<= 1) {
    int v = 0;
    if (t >= off) v = part[t - off];
    __syncthreads();
    part[t] += v;
    __syncthreads();
  }
  int run = part[t] - own;   // exclusive prefix
  for (int i = beg; i < end; i++) { rowptr[i] = run; run += cnt[i]; }
  if (t == 511) rowptr[n] = part[511];
}

__global__ void k_copy_int(const int* __restrict__ a, int* __restrict__ b, int n) {
  int i = blockIdx.x * blockDim.x + threadIdx.x;
  if (i < n) b[i] = a[i];
}

__global__ void k_scatter(const int* __restrict__ dst, int* __restrict__ cursor,
                          int* __restrict__ colidx) {
  int e = blockIdx.x * blockDim.x + threadIdx.x;
  if (e >= NE) return;
  int pos = atomicAdd(&cursor[dst[e]], 1);
  colidx[pos] = e;
}

// loop_attr[n][k] = mean over incoming edges of edge_attr (0-safe divide)
__global__ void k_loop_attr(const float* __restrict__ eattr, const int* __restrict__ rowptr,
                            const int* __restrict__ colidx, float* __restrict__ lattr) {
  int idx = blockIdx.x * blockDim.x + threadIdx.x;
  if (idx >= NNODE * 8) return;
  int nn = idx >> 3, k = idx & 7;
  int b = rowptr[nn], e = rowptr[nn + 1];
  float s = 0.f;
  for (int i = b; i < e; i++) s += eattr[(size_t)colidx[i] * 8 + k];
  int c = e - b;
  lattr[idx] = s / (float)max(c, 1);
}

// ---------------- edge attention precompute ----------------
__global__ void k_medge(const float* __restrict__ We, const float* __restrict__ ae,
                        float* __restrict__ M) {
  int t = threadIdx.x;
  if (t >= 32) return;
  int k = t >> 2, h = t & 3;
  float s = 0.f;
  for (int c = 0; c < 128; c++) s += We[k * 512 + h * 128 + c] * ae[h * 128 + c];
  M[t] = s;
}

__global__ void k_aedge(const float* __restrict__ attr, const float* __restrict__ M,
                        float* __restrict__ out, int n) {
  int idx = blockIdx.x * blockDim.x + threadIdx.x;
  if (idx >= n * 4) return;
  int e = idx >> 2, h = idx & 3;
  float s = 0.f;
#pragma unroll
  for (int k = 0; k < 8; k++) s += attr[(size_t)e * 8 + k] * M[k * 4 + h];
  out[idx] = s;
}

// a_src[n,h] = xp[n,h,:].att_src[h,:] from bf16 xp — one wave per node, 16B loads
__global__ void k_attn_dots(const unsigned short* __restrict__ xp, const float* __restrict__ as,
                            const float* __restrict__ ad, float* __restrict__ a_src,
                            float* __restrict__ a_dst) {
  int gw = (blockIdx.x * blockDim.x + threadIdx.x) >> 6;
  int lane = threadIdx.x & 63;
  if (gw >= NNODE) return;
  int h = lane >> 4;
  int c0 = (lane & 15) * 8;
  v8s v = *(const v8s*)(xp + (size_t)gw * HC + h * 128 + c0);
  const float* asr = as + h * 128 + c0;
  const float* adr = ad + h * 128 + c0;
  float s1 = 0.f, s2 = 0.f;
#pragma unroll
  for (int i = 0; i < 8; i++) {
    float f = b2f((unsigned short)v[i]);
    s1 += f * asr[i]; s2 += f * adr[i];
  }
  for (int off = 1; off < 16; off <<= 1) { s1 += __shfl_xor(s1, off); s2 += __shfl_xor(s2, off); }
  if ((lane & 15) == 0) { a_src[gw * 4 + h] = s1; a_dst[gw * 4 + h] = s2; }
}

// ---------------- GAT aggregation v3: one WAVE per node, register-only ----------------
// Chunk = 16 edges. Alpha role: lane = e*4+h. Gather role: lane owns 8 ch, head = lane>>4.
// Softmax state m/l replicated in-register per head; weights via shuffles; no LDS, no barriers.
__global__ __launch_bounds__(256) void k_aggregate(
    const unsigned short* __restrict__ xp, const float* __restrict__ a_src,
    const float* __restrict__ a_dst, const float* __restrict__ a_edge,
    const float* __restrict__ a_eloop, const int* __restrict__ srcv,
    const int* __restrict__ rowptr, const int* __restrict__ colidx,
    const float* __restrict__ bias, unsigned short* __restrict__ outp,
    int ldo, int pole) {
  int wid = threadIdx.x >> 6, lane = threadIdx.x & 63;
  int n = blockIdx.x * 4 + wid;
  if (n >= NNODE) return;
  if (pole) {
    int b = n / PB, loc = n - b * PB;
    if (loc < 2) return;
    outp += (size_t)(b * 8192 + loc - 2) * ldo;
  } else {
    outp += (size_t)n * ldo;
  }
  int beg = rowptr[n], deg = rowptr[n + 1] - beg;
  int total = deg + 1;          // + self loop
  int ha = lane & 3;            // alpha-role head
  int ea = lane >> 2;           // alpha-role edge slot (0..15)
  int hh = lane >> 4;           // gather-role head
  int c0 = lane * 8;            // gather-role channels
  float adn = a_dst[(size_t)n * 4 + ha];
  float m0 = -1e30f, m1 = -1e30f, m2 = -1e30f, m3 = -1e30f;
  float l0 = 0.f, l1 = 0.f, l2 = 0.f, l3 = 0.f;
  float acc[8] = {0.f, 0.f, 0.f, 0.f, 0.f, 0.f, 0.f, 0.f};
  for (int base = 0; base < total; base += 16) {
    int cnt = min(16, total - base);
    int ge = base + ea;
    int sn = n;
    float al = -1e30f;
    if (ea < cnt) {
      float aev;
      if (ge < deg) { int eid = colidx[beg + ge]; sn = srcv[eid]; aev = a_edge[(size_t)eid * 4 + ha]; }
      else          { aev = a_eloop[(size_t)n * 4 + ha]; }
      al = leakyf(a_src[(size_t)sn * 4 + ha] + adn + aev, 0.2f);
    }
    // per-head max over edge slots
    float cm = al;
    cm = fmaxf(cm, __shfl_xor(cm, 4));
    cm = fmaxf(cm, __shfl_xor(cm, 8));
    cm = fmaxf(cm, __shfl_xor(cm, 16));
    cm = fmaxf(cm, __shfl_xor(cm, 32));
    float cm0 = __shfl(cm, 0), cm1 = __shfl(cm, 1), cm2 = __shfl(cm, 2), cm3 = __shfl(cm, 3);
    float nm0 = fmaxf(m0, cm0), nm1 = fmaxf(m1, cm1), nm2 = fmaxf(m2, cm2), nm3 = fmaxf(m3, cm3);
    float r0 = __expf(m0 - nm0), r1 = __expf(m1 - nm1), r2 = __expf(m2 - nm2), r3 = __expf(m3 - nm3);
    float nmh = ha == 0 ? nm0 : ha == 1 ? nm1 : ha == 2 ? nm2 : nm3;
    float ex = (ea < cnt) ? __expf(al - nmh) : 0.f;
    float s = ex;
    s += __shfl_xor(s, 4);
    s += __shfl_xor(s, 8);
    s += __shfl_xor(s, 16);
    s += __shfl_xor(s, 32);
    float s0 = __shfl(s, 0), s1 = __shfl(s, 1), s2 = __shfl(s, 2), s3 = __shfl(s, 3);
    l0 = l0 * r0 + s0; l1 = l1 * r1 + s1; l2 = l2 * r2 + s2; l3 = l3 * r3 + s3;
    m0 = nm0; m1 = nm1; m2 = nm2; m3 = nm3;
    float rh = hh == 0 ? r0 : hh == 1 ? r1 : hh == 2 ? r2 : r3;
#pragma unroll
    for (int j = 0; j < 8; j++) acc[j] *= rh;
    // gather: weight for edge e at lane e*4+hh; src node at lane e*4
    for (int e = 0; e < cnt; e++) {
      float wt = __shfl(ex, e * 4 + hh);
      int se = __shfl(sn, e * 4);
      v8s v = *(const v8s*)(xp + (size_t)se * HC + c0);
#pragma unroll
      for (int j = 0; j < 8; j++) acc[j] += wt * b2f((unsigned short)v[j]);
    }
  }
  float lh = hh == 0 ? l0 : hh == 1 ? l1 : hh == 2 ? l2 : l3;
  float inv = 1.f / lh;
  v8s o;
#pragma unroll
  for (int j = 0; j < 8; j++) {
    float v = acc[j] * inv + bias[c0 + j];
    o[j] = (short)f2b(leakyf(v, 0.01f));
  }
  *(v8s*)(outp + c0) = o;
}

// ---------------- weight prep: Bt[n][k] = bf16(src[k*N+n]), K padded ----------------
__global__ void k_bt(const float* __restrict__ src, unsigned short* __restrict__ bt,
                     int N, int Ks, int Kd) {
  int idx = blockIdx.x * blockDim.x + threadIdx.x;
  if (idx >= N * Kd) return;
  int n = idx / Kd, k = idx - n * Kd;
  bt[idx] = (k < Ks) ? f2b(src[(size_t)k * N + n]) : (unsigned short)0;
}

// conv weights, tap-major: bt[j][c], j = tap*128+n  <- convw[n][c][tap]
__global__ void k_convbt(const float* __restrict__ w, unsigned short* __restrict__ bt) {
  int idx = blockIdx.x * blockDim.x + threadIdx.x;
  if (idx >= NTAPK * 512) return;
  int j = idx >> 9, c = idx & 511;
  int tap = j >> 7, nn = j & 127;
  bt[idx] = f2b(w[(size_t)nn * KCONV + c * 9 + tap]);
}

// ---------------- bf16 MFMA GEMM, m97-style (linear LDS, gload_lds dbuf) ----------------
template<int BM, int BN, typename OutT>
__global__ __launch_bounds__(256) void mgemm(
    int M, int N, int K, int ldb,
    const unsigned short* __restrict__ A, int lda,
    const unsigned short* __restrict__ Bt,
    const float* __restrict__ bias,
    float slope,
    OutT* __restrict__ C, int ldc)
{
  constexpr int WM = BM / 32;
  constexpr int WN = BN / 32;
  constexpr int ACH = BM * 4;
  constexpr int BCH = BN * 4;
  __shared__ unsigned short As[2][BM * 32];
  __shared__ unsigned short Bs[2][BN * 32];
  int tid = threadIdx.x;
  int wid = tid >> 6, lane = tid & 63;
  int wr = wid >> 1, wc = wid & 1;
  int l15 = lane & 15, l4 = lane >> 4;
  int row0 = blockIdx.y * BM;
  int col0 = blockIdx.x * BN;

  auto stage = [&](int buf, int kt) {
    int k0 = kt * 32;
#pragma unroll
    for (int i = 0; i < ACH / 256; i++) {
      int c = i * 256 + tid;
      int r = c >> 2, seg = c & 3;
      int gr = min(row0 + r, M - 1);
      gload_lds16(A + (size_t)gr * lda + k0 + seg * 8, &As[buf][c * 8]);
    }
#pragma unroll
    for (int i = 0; i < BCH / 256; i++) {
      int c = i * 256 + tid;
      int r = c >> 2, seg = c & 3;
      int gn = min(col0 + r, N - 1);
      gload_lds16(Bt + (size_t)gn * ldb + k0 + seg * 8, &Bs[buf][c * 8]);
    }
  };

  v4f acc[WM][WN];
#pragma unroll
  for (int m = 0; m < WM; m++)
#pragma unroll
    for (int n = 0; n < WN; n++) acc[m][n] = (v4f)0.f;

  int nt = K >> 5;
  stage(0, 0);
  __syncthreads();
  int cur = 0;
  for (int t = 0; t < nt - 1; t++) {
    stage(cur ^ 1, t + 1);
    v8s a[WM], b[WN];
#pragma unroll
    for (int m = 0; m < WM; m++)
      a[m] = *(const v8s*)(&As[cur][(wr * (BM / 2) + m * 16 + l15) * 32 + l4 * 8]);
#pragma unroll
    for (int n = 0; n < WN; n++)
      b[n] = *(const v8s*)(&Bs[cur][(wc * (BN / 2) + n * 16 + l15) * 32 + l4 * 8]);
#pragma unroll
    for (int m = 0; m < WM; m++)
#pragma unroll
      for (int n = 0; n < WN; n++)
        acc[m][n] = __builtin_amdgcn_mfma_f32_16x16x32_bf16(a[m], b[n], acc[m][n], 0, 0, 0);
    __syncthreads();
    cur ^= 1;
  }
  {
    v8s a[WM], b[WN];
#pragma unroll
    for (int m = 0; m < WM; m++)
      a[m] = *(const v8s*)(&As[cur][(wr * (BM / 2) + m * 16 + l15) * 32 + l4 * 8]);
#pragma unroll
    for (int n = 0; n < WN; n++)
      b[n] = *(const v8s*)(&Bs[cur][(wc * (BN / 2) + n * 16 + l15) * 32 + l4 * 8]);
#pragma unroll
    for (int m = 0; m < WM; m++)
#pragma unroll
      for (int n = 0; n < WN; n++)
        acc[m][n] = __builtin_amdgcn_mfma_f32_16x16x32_bf16(a[m], b[n], acc[m][n], 0, 0, 0);
  }
#pragma unroll
  for (int m = 0; m < WM; m++) {
#pragma unroll
    for (int q = 0; q < 4; q++) {
      int r = row0 + wr * (BM / 2) + m * 16 + l4 * 4 + q;
      if (r >= M) continue;
#pragma unroll
      for (int n = 0; n < WN; n++) {
        int cc = col0 + wc * (BN / 2) + n * 16 + l15;
        if (cc >= N) continue;
        float v = acc[m][n][q];
        if (bias) v += bias[cc];
        v = leakyf(v, slope);
        if constexpr (std::is_same<OutT, float>::value) {
          C[(size_t)r * ldc + cc] = v;
        } else {
          C[(size_t)r * ldc + cc] = f2b(v);
        }
      }
    }
  }
}

// ---------------- conv tap-sum stencil: zin[:,512:640] = leaky(BN(bias + Σ_tap H[nbr,tap])) ----------------
__global__ void k_tapsum(const unsigned short* __restrict__ H,
                         const float* __restrict__ convb, const float* __restrict__ bng,
                         const float* __restrict__ bnb, unsigned short* __restrict__ zin) {
  int idx = blockIdx.x * blockDim.x + threadIdx.x;   // NPOS*16
  if (idx >= NPOS * 16) return;
  int r = idx >> 4, seg = idx & 15;
  int n0 = seg * 8;
  int b = r >> 13, pos = r & 8191, i = pos >> 7, j = pos & 127;
  float acc[8] = {0.f, 0.f, 0.f, 0.f, 0.f, 0.f, 0.f, 0.f};
#pragma unroll
  for (int tap = 0; tap < 9; tap++) {
    int di = tap / 3, dj = tap - di * 3;
    int rr = i + di, cc = j + dj;
    int gr, gc;
    if (rr == 0)       { gr = 1;      gc = (63 + cc) & 127; }
    else if (rr == 65) { gr = 62;     gc = (63 + cc) & 127; }
    else               { gr = rr - 1; gc = (cc + 127) & 127; }
    v8s v = *(const v8s*)(H + ((size_t)(b * 8192 + gr * WWW + gc)) * NTAPK + tap * 128 + n0);
#pragma unroll
    for (int q = 0; q < 8; q++) acc[q] += b2f((unsigned short)v[q]);
  }
  unsigned short* o = zin + (size_t)r * 640 + 512 + n0;
  v8s ov;
#pragma unroll
  for (int q = 0; q < 8; q++) {
    int cc = n0 + q;
    float v = acc[q] + convb[cc];
    v = v * (bng[cc] * rsqrtf(1.f + 1e-5f)) + bnb[cc];
    ov[q] = (short)f2b(leakyf(v, 0.01f));
  }
  *(v8s*)o = ov;
}

// ---------------- final: out[b,t,i,j] = z3[(b*8192+p), t] + x[b, 78+t, p] ----------------
__global__ void k_final(const float* __restrict__ z3, const float* __restrict__ x,
                        float* __restrict__ outp) {
  int idx = blockIdx.x * blockDim.x + threadIdx.x;
  if (idx >= NPOS * TGT) return;
  int b = idx / (TGT * 8192);
  int rem = idx - b * (TGT * 8192);
  int t = rem >> 13;
  int p = rem & 8191;
  outp[idx] = z3[((size_t)(b * 8192 + p)) * TGT + t] + x[((size_t)(b * 117 + 78 + t)) * 8192 + p];
}

// ================================================================
extern "C" void kernel_launch(void* const* d_in, const int* in_sizes, int n_in,
                              void* d_out, int out_size, void* d_ws, size_t ws_size,
                              hipStream_t stream) {
  const float* x     = (const float*)d_in[0];
  const float* xcons = (const float*)d_in[1];
  const int*   eidx  = (const int*)d_in[2];
  const float* eattr = (const float*)d_in[3];
  const float* g1W  = (const float*)d_in[4];
  const float* g1as = (const float*)d_in[5];
  const float* g1ad = (const float*)d_in[6];
  const float* g1We = (const float*)d_in[7];
  const float* g1ae = (const float*)d_in[8];
  const float* g1b  = (const float*)d_in[9];
  const float* g2W  = (const float*)d_in[10];
  const float* g2as = (const float*)d_in[11];
  const float* g2ad = (const float*)d_in[12];
  const float* g2We = (const float*)d_in[13];
  const float* g2ae = (const float*)d_in[14];
  const float* g2b  = (const float*)d_in[15];
  const float* convw= (const float*)d_in[16];
  const float* convb= (const float*)d_in[17];
  const float* bng  = (const float*)d_in[18];
  const float* bnb  = (const float*)d_in[19];
  const float* mw1  = (const float*)d_in[20];
  const float* mb1  = (const float*)d_in[21];
  const float* mw2  = (const float*)d_in[22];
  const float* mb2  = (const float*)d_in[23];
  const float* mw3  = (const float*)d_in[24];
  const float* mb3  = (const float*)d_in[25];
  float* outp = (float*)d_out;
  (void)in_sizes; (void)n_in; (void)out_size; (void)ws_size;

  const int* esrc = eidx;
  const int* edst = eidx + NE;

  char* basep = (char*)d_ws;
  size_t off = 0;
  auto alloc = [&](size_t bytes) -> void* {
    void* p = basep + off;
    off += (bytes + 255) & ~(size_t)255;
    return p;
  };
  unsigned short* nodesb = (unsigned short*)alloc((size_t)NNODE * 128 * 2);
  unsigned short* xpb    = (unsigned short*)alloc((size_t)NNODE * HC * 2);
  unsigned short* h1b    = (unsigned short*)alloc((size_t)NNODE * HC * 2);
  unsigned short* zin    = (unsigned short*)alloc((size_t)NPOS * 640 * 2);
  unsigned short* Hb     = (unsigned short*)alloc((size_t)NPOS * NTAPK * 2);
  float* asrc   = (float*)alloc((size_t)NNODE * 4 * sizeof(float));
  float* adst   = (float*)alloc((size_t)NNODE * 4 * sizeof(float));
  float* aedge  = (float*)alloc((size_t)NE * 4 * sizeof(float));
  float* aeloop = (float*)alloc((size_t)NNODE * 4 * sizeof(float));
  float* lattr  = (float*)alloc((size_t)NNODE * 8 * sizeof(float));
  float* Medge  = (float*)alloc(32 * sizeof(float));
  unsigned short* g1Wt  = (unsigned short*)alloc((size_t)512 * 128 * 2);
  unsigned short* g2Wt  = (unsigned short*)alloc((size_t)512 * 512 * 2);
  unsigned short* convWt= (unsigned short*)alloc((size_t)NTAPK * 512 * 2);
  unsigned short* mw1t  = (unsigned short*)alloc((size_t)512 * 640 * 2);
  unsigned short* mw2t  = (unsigned short*)alloc((size_t)256 * 512 * 2);
  unsigned short* mw3t  = (unsigned short*)alloc((size_t)TGT * 256 * 2);
  int* cnt      = (int*)alloc((size_t)NNODE * sizeof(int));
  int* rowptr   = (int*)alloc((size_t)(NNODE + 1) * sizeof(int));
  int* cursor   = (int*)alloc((size_t)NNODE * sizeof(int));
  int* colidx   = (int*)alloc((size_t)NE * sizeof(int));
  unsigned short* z1b = xpb;             // xpb dead after GAT2 aggregation
  unsigned short* z2b = h1b;             // h1b dead after GAT2 xp GEMM
  float*          z3  = (float*)nodesb;  // nodesb dead after GAT1 xp GEMM

  hipMemsetAsync(cnt, 0, NNODE * sizeof(int), stream);
  k_build_nodes<<<NB * 128, 256, 0, stream>>>(x, xcons, nodesb);
  k_hist<<<ceildiv(NE, 256), 256, 0, stream>>>(edst, cnt);
  k_scan<<<1, 512, 0, stream>>>(cnt, rowptr, NNODE);
  k_copy_int<<<ceildiv(NNODE, 256), 256, 0, stream>>>(rowptr, cursor, NNODE);
  k_scatter<<<ceildiv(NE, 256), 256, 0, stream>>>(edst, cursor, colidx);
  k_loop_attr<<<ceildiv(NNODE * 8, 256), 256, 0, stream>>>(eattr, rowptr, colidx, lattr);

  // weight prep
  k_bt<<<ceildiv(512 * 128, 256), 256, 0, stream>>>(g1W, g1Wt, 512, F1, 128);
  k_bt<<<ceildiv(512 * 512, 256), 256, 0, stream>>>(g2W, g2Wt, 512, 512, 512);
  k_convbt<<<ceildiv(NTAPK * 512, 256), 256, 0, stream>>>(convw, convWt);
  k_bt<<<ceildiv(512 * 640, 256), 256, 0, stream>>>(mw1, mw1t, 512, 640, 640);
  k_bt<<<ceildiv(256 * 512, 256), 256, 0, stream>>>(mw2, mw2t, 256, 512, 512);
  k_bt<<<ceildiv(TGT * 256, 256), 256, 0, stream>>>(mw3, mw3t, TGT, 256, 256);

  // ---- GAT layer 1 ----
  k_medge<<<1, 64, 0, stream>>>(g1We, g1ae, Medge);
  k_aedge<<<ceildiv(NE * 4, 256), 256, 0, stream>>>(eattr, Medge, aedge, NE);
  k_aedge<<<ceildiv(NNODE * 4, 256), 256, 0, stream>>>(lattr, Medge, aeloop, NNODE);
  {
    dim3 g(4, ceildiv(NNODE, 128));
    mgemm<128, 128, unsigned short><<<g, 256, 0, stream>>>(
        NNODE, HC, 128, 128, nodesb, 128, g1Wt, nullptr, 1.0f, xpb, HC);
  }
  k_attn_dots<<<ceildiv(NNODE, 4), 256, 0, stream>>>(xpb, g1as, g1ad, asrc, adst);
  k_aggregate<<<ceildiv(NNODE, 4), 256, 0, stream>>>(xpb, asrc, adst, aedge, aeloop, esrc,
                                                     rowptr, colidx, g1b, h1b, HC, 0);

  // ---- GAT layer 2 (aggregation writes zin[:,0:512] directly, poles dropped) ----
  k_medge<<<1, 64, 0, stream>>>(g2We, g2ae, Medge);
  k_aedge<<<ceildiv(NE * 4, 256), 256, 0, stream>>>(eattr, Medge, aedge, NE);
  k_aedge<<<ceildiv(NNODE * 4, 256), 256, 0, stream>>>(lattr, Medge, aeloop, NNODE);
  {
    dim3 g(4, ceildiv(NNODE, 128));
    mgemm<128, 128, unsigned short><<<g, 256, 0, stream>>>(
        NNODE, HC, HC, HC, h1b, HC, g2Wt, nullptr, 1.0f, xpb, HC);
  }
  k_attn_dots<<<ceildiv(NNODE, 4), 256, 0, stream>>>(xpb, g2as, g2ad, asrc, adst);
  k_aggregate<<<ceildiv(NNODE, 4), 256, 0, stream>>>(xpb, asrc, adst, aedge, aeloop, esrc,
                                                     rowptr, colidx, g2b, zin, 640, 1);

  // ---- conv as tap-major GEMM + stencil tap-sum ----
  {
    dim3 g(NTAPK / 128, ceildiv(NPOS, 128));   // 9 x 128 = 1152 blocks
    mgemm<128, 128, unsigned short><<<g, 256, 0, stream>>>(
        NPOS, NTAPK, 512, 512, zin, 640, convWt, nullptr, 1.0f, Hb, NTAPK);
  }
  k_tapsum<<<ceildiv(NPOS * 16, 256), 256, 0, stream>>>(Hb, convb, bng, bnb, zin);

  // ---- MLP ----
  {
    dim3 g(4, ceildiv(NPOS, 128));
    mgemm<128, 128, unsigned short><<<g, 256, 0, stream>>>(
        NPOS, 512, 640, 640, zin, 640, mw1t, mb1, 0.01f, z1b, 512);
  }
  {
    dim3 g(2, ceildiv(NPOS, 64));   // 512 blocks
    mgemm<64, 128, unsigned short><<<g, 256, 0, stream>>>(
        NPOS, 256, 512, 512, z1b, 512, mw2t, mb2, 0.01f, z2b, 256);
  }
  {
    dim3 g(1, ceildiv(NPOS, 64));   // 256 blocks
    mgemm<64, 64, float><<<g, 256, 0, stream>>>(
        NPOS, TGT, 256, 256, z2b, 256, mw3t, mb3, 1.0f, z3, TGT);
  }

  k_final<<<ceildiv(NPOS * TGT, 256), 256, 0, stream>>>(z3, x, outp);
}

// Round 9
// 322.766 us; speedup vs baseline: 5.6341x; 1.0254x over previous
//
#include <hip/hip_runtime.h>
#include <math.h>
#include <type_traits>

// ---- problem constants ----
#define NB    2
#define HHH   64
#define WWW   128
#define F1    123      // 117 + 6
#define HC    512      // heads*hid
#define NE    131072
#define PB    8194     // nodes per batch (8192 + 2 poles)
#define NNODE (NB*PB)  // 16388
#define NPOS  (NB*HHH*WWW) // 16384
#define TGT   39
#define EMBED 128
#define KCONV 4608     // 512*9
#define NTAPK 1152     // 9*128 tap-major conv output width

static inline int ceildiv(int a, int b){ return (a + b - 1) / b; }

typedef short v8s __attribute__((ext_vector_type(8)));
typedef float v4f __attribute__((ext_vector_type(4)));

__device__ __forceinline__ float leakyf(float x, float s){ return x >= 0.f ? x : s * x; }

__device__ __forceinline__ unsigned short f2b(float f) {
  unsigned u = __builtin_bit_cast(unsigned, f);
  u = (u + 0x7FFFu + ((u >> 16) & 1u)) >> 16;
  return (unsigned short)u;
}
__device__ __forceinline__ float b2f(unsigned short h) {
  unsigned u = ((unsigned)h) << 16;
  return __builtin_bit_cast(float, u);
}

// async global->LDS, 16 bytes per lane (dest = wave-uniform base + lane*16)
__device__ __forceinline__ void gload_lds16(const void* g, void* l) {
  __builtin_amdgcn_global_load_lds((const __attribute__((address_space(1))) void*)g,
                                   (__attribute__((address_space(3))) void*)l, 16, 0, 0);
}

// ---------------- build node features (bf16, K padded 123->128) ----------------
__global__ __launch_bounds__(256) void k_build_nodes(const float* __restrict__ x,
                                                     const float* __restrict__ xc,
                                                     unsigned short* __restrict__ nodes) {
  __shared__ unsigned short lds[64][130];
  int blk = blockIdx.x;             // NB*128 blocks
  int b = blk >> 7, p0 = (blk & 127) * 64;
  int tid = threadIdx.x;
  int pi = tid & 63, cg = tid >> 6;
  for (int c = cg; c < 128; c += 4) {
    float v = 0.f;
    int p = p0 + pi;
    if (c < 117)      v = x[((size_t)(b * 117 + c)) * 8192 + p];
    else if (c < 123) v = xc[((size_t)(b * 6 + (c - 117))) * 8192 + p];
    lds[pi][c] = f2b(v);
  }
  if ((blk & 127) == 0 && tid < 32) {
    int rr = tid >> 4, sg = tid & 15;
    *(v8s*)(nodes + ((size_t)(b * PB + rr)) * 128 + sg * 8) = (v8s)0;
  }
  __syncthreads();
  int seg = tid & 15, r0 = tid >> 4;
  for (int rr = r0; rr < 64; rr += 16) {
    int node = b * PB + 2 + p0 + rr;
    *(v8s*)(nodes + (size_t)node * 128 + seg * 8) = *(const v8s*)(&lds[rr][seg * 8]);
  }
}

// ---------------- CSR build ----------------
__global__ void k_hist(const int* __restrict__ dst, int* __restrict__ cnt) {
  int e = blockIdx.x * blockDim.x + threadIdx.x;
  if (e >= NE) return;
  atomicAdd(&cnt[dst[e]], 1);
}

__global__ void k_scan(const int* __restrict__ cnt, int* __restrict__ rowptr, int n) {
  __shared__ int part[512];
  int t = threadIdx.x;
  int chunk = (n + 511) >> 9;
  int beg = t * chunk, end = min(beg + chunk, n);
  int s = 0;
  for (int i = beg; i < end; i++) s += cnt[i];
  part[t] = s;
  __syncthreads();
  int own = s;
  for (int off = 1; off < 512; off <<= 1) {
    int v = 0;
    if (t >= off) v = part[t - off];
    __syncthreads();
    part[t] += v;
    __syncthreads();
  }
  int run = part[t] - own;   // exclusive prefix
  for (int i = beg; i < end; i++) { rowptr[i] = run; run += cnt[i]; }
  if (t == 511) rowptr[n] = part[511];
}

__global__ void k_copy_int(const int* __restrict__ a, int* __restrict__ b, int n) {
  int i = blockIdx.x * blockDim.x + threadIdx.x;
  if (i < n) b[i] = a[i];
}

__global__ void k_scatter(const int* __restrict__ dst, int* __restrict__ cursor,
                          int* __restrict__ colidx) {
  int e = blockIdx.x * blockDim.x + threadIdx.x;
  if (e >= NE) return;
  int pos = atomicAdd(&cursor[dst[e]], 1);
  colidx[pos] = e;
}

// loop_attr[n][k] = mean over incoming edges of edge_attr (0-safe divide)
__global__ void k_loop_attr(const float* __restrict__ eattr, const int* __restrict__ rowptr,
                            const int* __restrict__ colidx, float* __restrict__ lattr) {
  int idx = blockIdx.x * blockDim.x + threadIdx.x;
  if (idx >= NNODE * 8) return;
  int nn = idx >> 3, k = idx & 7;
  int b = rowptr[nn], e = rowptr[nn + 1];
  float s = 0.f;
  for (int i = b; i < e; i++) s += eattr[(size_t)colidx[i] * 8 + k];
  int c = e - b;
  lattr[idx] = s / (float)max(c, 1);
}

// ---------------- edge attention precompute ----------------
__global__ void k_medge(const float* __restrict__ We, const float* __restrict__ ae,
                        float* __restrict__ M) {
  int t = threadIdx.x;
  if (t >= 32) return;
  int k = t >> 2, h = t & 3;
  float s = 0.f;
  for (int c = 0; c < 128; c++) s += We[k * 512 + h * 128 + c] * ae[h * 128 + c];
  M[t] = s;
}

__global__ void k_aedge(const float* __restrict__ attr, const float* __restrict__ M,
                        float* __restrict__ out, int n) {
  int idx = blockIdx.x * blockDim.x + threadIdx.x;
  if (idx >= n * 4) return;
  int e = idx >> 2, h = idx & 3;
  float s = 0.f;
#pragma unroll
  for (int k = 0; k < 8; k++) s += attr[(size_t)e * 8 + k] * M[k * 4 + h];
  out[idx] = s;
}

// a_src[n,h] = xp[n,h,:].att_src[h,:] from bf16 xp — one wave per node, 16B loads
__global__ void k_attn_dots(const unsigned short* __restrict__ xp, const float* __restrict__ as,
                            const float* __restrict__ ad, float* __restrict__ a_src,
                            float* __restrict__ a_dst) {
  int gw = (blockIdx.x * blockDim.x + threadIdx.x) >> 6;
  int lane = threadIdx.x & 63;
  if (gw >= NNODE) return;
  int h = lane >> 4;
  int c0 = (lane & 15) * 8;
  v8s v = *(const v8s*)(xp + (size_t)gw * HC + h * 128 + c0);
  const float* asr = as + h * 128 + c0;
  const float* adr = ad + h * 128 + c0;
  float s1 = 0.f, s2 = 0.f;
#pragma unroll
  for (int i = 0; i < 8; i++) {
    float f = b2f((unsigned short)v[i]);
    s1 += f * asr[i]; s2 += f * adr[i];
  }
  for (int off = 1; off < 16; off <<= 1) { s1 += __shfl_xor(s1, off); s2 += __shfl_xor(s2, off); }
  if ((lane & 15) == 0) { a_src[gw * 4 + h] = s1; a_dst[gw * 4 + h] = s2; }
}

// ---------------- GAT aggregation v3: one WAVE per node, register-only ----------------
__global__ __launch_bounds__(256) void k_aggregate(
    const unsigned short* __restrict__ xp, const float* __restrict__ a_src,
    const float* __restrict__ a_dst, const float* __restrict__ a_edge,
    const float* __restrict__ a_eloop, const int* __restrict__ srcv,
    const int* __restrict__ rowptr, const int* __restrict__ colidx,
    const float* __restrict__ bias, unsigned short* __restrict__ outp,
    int ldo, int pole) {
  int wid = threadIdx.x >> 6, lane = threadIdx.x & 63;
  int n = blockIdx.x * 4 + wid;
  if (n >= NNODE) return;
  if (pole) {
    int b = n / PB, loc = n - b * PB;
    if (loc < 2) return;
    outp += (size_t)(b * 8192 + loc - 2) * ldo;
  } else {
    outp += (size_t)n * ldo;
  }
  int beg = rowptr[n], deg = rowptr[n + 1] - beg;
  int total = deg + 1;          // + self loop
  int ha = lane & 3;            // alpha-role head
  int ea = lane >> 2;           // alpha-role edge slot (0..15)
  int hh = lane >> 4;           // gather-role head
  int c0 = lane * 8;            // gather-role channels
  float adn = a_dst[(size_t)n * 4 + ha];
  float m0 = -1e30f, m1 = -1e30f, m2 = -1e30f, m3 = -1e30f;
  float l0 = 0.f, l1 = 0.f, l2 = 0.f, l3 = 0.f;
  float acc[8] = {0.f, 0.f, 0.f, 0.f, 0.f, 0.f, 0.f, 0.f};
  for (int base = 0; base < total; base += 16) {
    int cnt = min(16, total - base);
    int ge = base + ea;
    int sn = n;
    float al = -1e30f;
    if (ea < cnt) {
      float aev;
      if (ge < deg) { int eid = colidx[beg + ge]; sn = srcv[eid]; aev = a_edge[(size_t)eid * 4 + ha]; }
      else          { aev = a_eloop[(size_t)n * 4 + ha]; }
      al = leakyf(a_src[(size_t)sn * 4 + ha] + adn + aev, 0.2f);
    }
    float cm = al;
    cm = fmaxf(cm, __shfl_xor(cm, 4));
    cm = fmaxf(cm, __shfl_xor(cm, 8));
    cm = fmaxf(cm, __shfl_xor(cm, 16));
    cm = fmaxf(cm, __shfl_xor(cm, 32));
    float cm0 = __shfl(cm, 0), cm1 = __shfl(cm, 1), cm2 = __shfl(cm, 2), cm3 = __shfl(cm, 3);
    float nm0 = fmaxf(m0, cm0), nm1 = fmaxf(m1, cm1), nm2 = fmaxf(m2, cm2), nm3 = fmaxf(m3, cm3);
    float r0 = __expf(m0 - nm0), r1 = __expf(m1 - nm1), r2 = __expf(m2 - nm2), r3 = __expf(m3 - nm3);
    float nmh = ha == 0 ? nm0 : ha == 1 ? nm1 : ha == 2 ? nm2 : nm3;
    float ex = (ea < cnt) ? __expf(al - nmh) : 0.f;
    float s = ex;
    s += __shfl_xor(s, 4);
    s += __shfl_xor(s, 8);
    s += __shfl_xor(s, 16);
    s += __shfl_xor(s, 32);
    float s0 = __shfl(s, 0), s1 = __shfl(s, 1), s2 = __shfl(s, 2), s3 = __shfl(s, 3);
    l0 = l0 * r0 + s0; l1 = l1 * r1 + s1; l2 = l2 * r2 + s2; l3 = l3 * r3 + s3;
    m0 = nm0; m1 = nm1; m2 = nm2; m3 = nm3;
    float rh = hh == 0 ? r0 : hh == 1 ? r1 : hh == 2 ? r2 : r3;
#pragma unroll
    for (int j = 0; j < 8; j++) acc[j] *= rh;
    for (int e = 0; e < cnt; e++) {
      float wt = __shfl(ex, e * 4 + hh);
      int se = __shfl(sn, e * 4);
      v8s v = *(const v8s*)(xp + (size_t)se * HC + c0);
#pragma unroll
      for (int j = 0; j < 8; j++) acc[j] += wt * b2f((unsigned short)v[j]);
    }
  }
  float lh = hh == 0 ? l0 : hh == 1 ? l1 : hh == 2 ? l2 : l3;
  float inv = 1.f / lh;
  v8s o;
#pragma unroll
  for (int j = 0; j < 8; j++) {
    float v = acc[j] * inv + bias[c0 + j];
    o[j] = (short)f2b(leakyf(v, 0.01f));
  }
  *(v8s*)(outp + c0) = o;
}

// ---------------- weight prep: Bt[n][k] = bf16(src[k*N+n]), K padded ----------------
__global__ void k_bt(const float* __restrict__ src, unsigned short* __restrict__ bt,
                     int N, int Ks, int Kd) {
  int idx = blockIdx.x * blockDim.x + threadIdx.x;
  if (idx >= N * Kd) return;
  int n = idx / Kd, k = idx - n * Kd;
  bt[idx] = (k < Ks) ? f2b(src[(size_t)k * N + n]) : (unsigned short)0;
}

// conv weights, tap-major: bt[j][c], j = tap*128+n  <- convw[n][c][tap]
__global__ void k_convbt(const float* __restrict__ w, unsigned short* __restrict__ bt) {
  int idx = blockIdx.x * blockDim.x + threadIdx.x;
  if (idx >= NTAPK * 512) return;
  int j = idx >> 9, c = idx & 511;
  int tap = j >> 7, nn = j & 127;
  bt[idx] = f2b(w[(size_t)nn * KCONV + c * 9 + tap]);
}

// ---------------- bf16 MFMA GEMM + bijective XCD-aware block swizzle (T1, m204) ----------------
// Dispatch slot s (x-fastest) lands on XCD s%8; remap so each XCD owns a CONTIGUOUS
// chunk of logical tiles (x-fastest within chunk) -> blocks sharing an A row-tile
// hit the same per-XCD L2.
template<int BM, int BN, typename OutT>
__global__ __launch_bounds__(256) void mgemm(
    int M, int N, int K, int ldb,
    const unsigned short* __restrict__ A, int lda,
    const unsigned short* __restrict__ Bt,
    const float* __restrict__ bias,
    float slope,
    OutT* __restrict__ C, int ldc)
{
  constexpr int WM = BM / 32;
  constexpr int WN = BN / 32;
  constexpr int ACH = BM * 4;
  constexpr int BCH = BN * 4;
  __shared__ unsigned short As[2][BM * 32];
  __shared__ unsigned short Bs[2][BN * 32];
  int tid = threadIdx.x;
  int wid = tid >> 6, lane = tid & 63;
  int wr = wid >> 1, wc = wid & 1;
  int l15 = lane & 15, l4 = lane >> 4;

  // --- XCD swizzle (bijective for any nwg) ---
  int gx = gridDim.x;
  int nwg = gx * gridDim.y;
  int slot = blockIdx.x + blockIdx.y * gx;
  int q = nwg >> 3, r = nwg & 7;
  int xcd = slot & 7, pos = slot >> 3;
  int wg = (xcd < r ? xcd * (q + 1) : r * (q + 1) + (xcd - r) * q) + pos;
  int bx = wg % gx, by = wg / gx;

  int row0 = by * BM;
  int col0 = bx * BN;

  auto stage = [&](int buf, int kt) {
    int k0 = kt * 32;
#pragma unroll
    for (int i = 0; i < ACH / 256; i++) {
      int c = i * 256 + tid;
      int r2 = c >> 2, seg = c & 3;
      int gr = min(row0 + r2, M - 1);
      gload_lds16(A + (size_t)gr * lda + k0 + seg * 8, &As[buf][c * 8]);
    }
#pragma unroll
    for (int i = 0; i < BCH / 256; i++) {
      int c = i * 256 + tid;
      int r2 = c >> 2, seg = c & 3;
      int gn = min(col0 + r2, N - 1);
      gload_lds16(Bt + (size_t)gn * ldb + k0 + seg * 8, &Bs[buf][c * 8]);
    }
  };

  v4f acc[WM][WN];
#pragma unroll
  for (int m = 0; m < WM; m++)
#pragma unroll
    for (int n = 0; n < WN; n++) acc[m][n] = (v4f)0.f;

  int nt = K >> 5;
  stage(0, 0);
  __syncthreads();
  int cur = 0;
  for (int t = 0; t < nt - 1; t++) {
    stage(cur ^ 1, t + 1);
    v8s a[WM], b[WN];
#pragma unroll
    for (int m = 0; m < WM; m++)
      a[m] = *(const v8s*)(&As[cur][(wr * (BM / 2) + m * 16 + l15) * 32 + l4 * 8]);
#pragma unroll
    for (int n = 0; n < WN; n++)
      b[n] = *(const v8s*)(&Bs[cur][(wc * (BN / 2) + n * 16 + l15) * 32 + l4 * 8]);
#pragma unroll
    for (int m = 0; m < WM; m++)
#pragma unroll
      for (int n = 0; n < WN; n++)
        acc[m][n] = __builtin_amdgcn_mfma_f32_16x16x32_bf16(a[m], b[n], acc[m][n], 0, 0, 0);
    __syncthreads();
    cur ^= 1;
  }
  {
    v8s a[WM], b[WN];
#pragma unroll
    for (int m = 0; m < WM; m++)
      a[m] = *(const v8s*)(&As[cur][(wr * (BM / 2) + m * 16 + l15) * 32 + l4 * 8]);
#pragma unroll
    for (int n = 0; n < WN; n++)
      b[n] = *(const v8s*)(&Bs[cur][(wc * (BN / 2) + n * 16 + l15) * 32 + l4 * 8]);
#pragma unroll
    for (int m = 0; m < WM; m++)
#pragma unroll
      for (int n = 0; n < WN; n++)
        acc[m][n] = __builtin_amdgcn_mfma_f32_16x16x32_bf16(a[m], b[n], acc[m][n], 0, 0, 0);
  }
#pragma unroll
  for (int m = 0; m < WM; m++) {
#pragma unroll
    for (int q2 = 0; q2 < 4; q2++) {
      int r2 = row0 + wr * (BM / 2) + m * 16 + l4 * 4 + q2;
      if (r2 >= M) continue;
#pragma unroll
      for (int n = 0; n < WN; n++) {
        int cc = col0 + wc * (BN / 2) + n * 16 + l15;
        if (cc >= N) continue;
        float v = acc[m][n][q2];
        if (bias) v += bias[cc];
        v = leakyf(v, slope);
        if constexpr (std::is_same<OutT, float>::value) {
          C[(size_t)r2 * ldc + cc] = v;
        } else {
          C[(size_t)r2 * ldc + cc] = f2b(v);
        }
      }
    }
  }
}

// ---------------- conv tap-sum stencil: zin[:,512:640] = leaky(BN(bias + Σ_tap H[nbr,tap])) ----------------
__global__ void k_tapsum(const unsigned short* __restrict__ H,
                         const float* __restrict__ convb, const float* __restrict__ bng,
                         const float* __restrict__ bnb, unsigned short* __restrict__ zin) {
  int idx = blockIdx.x * blockDim.x + threadIdx.x;   // NPOS*16
  if (idx >= NPOS * 16) return;
  int r = idx >> 4, seg = idx & 15;
  int n0 = seg * 8;
  int b = r >> 13, pos = r & 8191, i = pos >> 7, j = pos & 127;
  float acc[8] = {0.f, 0.f, 0.f, 0.f, 0.f, 0.f, 0.f, 0.f};
#pragma unroll
  for (int tap = 0; tap < 9; tap++) {
    int di = tap / 3, dj = tap - di * 3;
    int rr = i + di, cc = j + dj;
    int gr, gc;
    if (rr == 0)       { gr = 1;      gc = (63 + cc) & 127; }
    else if (rr == 65) { gr = 62;     gc = (63 + cc) & 127; }
    else               { gr = rr - 1; gc = (cc + 127) & 127; }
    v8s v = *(const v8s*)(H + ((size_t)(b * 8192 + gr * WWW + gc)) * NTAPK + tap * 128 + n0);
#pragma unroll
    for (int q = 0; q < 8; q++) acc[q] += b2f((unsigned short)v[q]);
  }
  unsigned short* o = zin + (size_t)r * 640 + 512 + n0;
  v8s ov;
#pragma unroll
  for (int q = 0; q < 8; q++) {
    int cc = n0 + q;
    float v = acc[q] + convb[cc];
    v = v * (bng[cc] * rsqrtf(1.f + 1e-5f)) + bnb[cc];
    ov[q] = (short)f2b(leakyf(v, 0.01f));
  }
  *(v8s*)o = ov;
}

// ---------------- final: out[b,t,i,j] = z3[(b*8192+p), t] + x[b, 78+t, p] ----------------
__global__ void k_final(const float* __restrict__ z3, const float* __restrict__ x,
                        float* __restrict__ outp) {
  int idx = blockIdx.x * blockDim.x + threadIdx.x;
  if (idx >= NPOS * TGT) return;
  int b = idx / (TGT * 8192);
  int rem = idx - b * (TGT * 8192);
  int t = rem >> 13;
  int p = rem & 8191;
  outp[idx] = z3[((size_t)(b * 8192 + p)) * TGT + t] + x[((size_t)(b * 117 + 78 + t)) * 8192 + p];
}

// ================================================================
extern "C" void kernel_launch(void* const* d_in, const int* in_sizes, int n_in,
                              void* d_out, int out_size, void* d_ws, size_t ws_size,
                              hipStream_t stream) {
  const float* x     = (const float*)d_in[0];
  const float* xcons = (const float*)d_in[1];
  const int*   eidx  = (const int*)d_in[2];
  const float* eattr = (const float*)d_in[3];
  const float* g1W  = (const float*)d_in[4];
  const float* g1as = (const float*)d_in[5];
  const float* g1ad = (const float*)d_in[6];
  const float* g1We = (const float*)d_in[7];
  const float* g1ae = (const float*)d_in[8];
  const float* g1b  = (const float*)d_in[9];
  const float* g2W  = (const float*)d_in[10];
  const float* g2as = (const float*)d_in[11];
  const float* g2ad = (const float*)d_in[12];
  const float* g2We = (const float*)d_in[13];
  const float* g2ae = (const float*)d_in[14];
  const float* g2b  = (const float*)d_in[15];
  const float* convw= (const float*)d_in[16];
  const float* convb= (const float*)d_in[17];
  const float* bng  = (const float*)d_in[18];
  const float* bnb  = (const float*)d_in[19];
  const float* mw1  = (const float*)d_in[20];
  const float* mb1  = (const float*)d_in[21];
  const float* mw2  = (const float*)d_in[22];
  const float* mb2  = (const float*)d_in[23];
  const float* mw3  = (const float*)d_in[24];
  const float* mb3  = (const float*)d_in[25];
  float* outp = (float*)d_out;
  (void)in_sizes; (void)n_in; (void)out_size; (void)ws_size;

  const int* esrc = eidx;
  const int* edst = eidx + NE;

  char* basep = (char*)d_ws;
  size_t off = 0;
  auto alloc = [&](size_t bytes) -> void* {
    void* p = basep + off;
    off += (bytes + 255) & ~(size_t)255;
    return p;
  };
  unsigned short* nodesb = (unsigned short*)alloc((size_t)NNODE * 128 * 2);
  unsigned short* xpb    = (unsigned short*)alloc((size_t)NNODE * HC * 2);
  unsigned short* h1b    = (unsigned short*)alloc((size_t)NNODE * HC * 2);
  unsigned short* zin    = (unsigned short*)alloc((size_t)NPOS * 640 * 2);
  unsigned short* Hb     = (unsigned short*)alloc((size_t)NPOS * NTAPK * 2);
  float* asrc   = (float*)alloc((size_t)NNODE * 4 * sizeof(float));
  float* adst   = (float*)alloc((size_t)NNODE * 4 * sizeof(float));
  float* aedge  = (float*)alloc((size_t)NE * 4 * sizeof(float));
  float* aeloop = (float*)alloc((size_t)NNODE * 4 * sizeof(float));
  float* lattr  = (float*)alloc((size_t)NNODE * 8 * sizeof(float));
  float* Medge  = (float*)alloc(32 * sizeof(float));
  unsigned short* g1Wt  = (unsigned short*)alloc((size_t)512 * 128 * 2);
  unsigned short* g2Wt  = (unsigned short*)alloc((size_t)512 * 512 * 2);
  unsigned short* convWt= (unsigned short*)alloc((size_t)NTAPK * 512 * 2);
  unsigned short* mw1t  = (unsigned short*)alloc((size_t)512 * 640 * 2);
  unsigned short* mw2t  = (unsigned short*)alloc((size_t)256 * 512 * 2);
  unsigned short* mw3t  = (unsigned short*)alloc((size_t)TGT * 256 * 2);
  int* cnt      = (int*)alloc((size_t)NNODE * sizeof(int));
  int* rowptr   = (int*)alloc((size_t)(NNODE + 1) * sizeof(int));
  int* cursor   = (int*)alloc((size_t)NNODE * sizeof(int));
  int* colidx   = (int*)alloc((size_t)NE * sizeof(int));
  unsigned short* z1b = xpb;             // xpb dead after GAT2 aggregation
  unsigned short* z2b = h1b;             // h1b dead after GAT2 xp GEMM
  float*          z3  = (float*)nodesb;  // nodesb dead after GAT1 xp GEMM

  hipMemsetAsync(cnt, 0, NNODE * sizeof(int), stream);
  k_build_nodes<<<NB * 128, 256, 0, stream>>>(x, xcons, nodesb);
  k_hist<<<ceildiv(NE, 256), 256, 0, stream>>>(edst, cnt);
  k_scan<<<1, 512, 0, stream>>>(cnt, rowptr, NNODE);
  k_copy_int<<<ceildiv(NNODE, 256), 256, 0, stream>>>(rowptr, cursor, NNODE);
  k_scatter<<<ceildiv(NE, 256), 256, 0, stream>>>(edst, cursor, colidx);
  k_loop_attr<<<ceildiv(NNODE * 8, 256), 256, 0, stream>>>(eattr, rowptr, colidx, lattr);

  // weight prep
  k_bt<<<ceildiv(512 * 128, 256), 256, 0, stream>>>(g1W, g1Wt, 512, F1, 128);
  k_bt<<<ceildiv(512 * 512, 256), 256, 0, stream>>>(g2W, g2Wt, 512, 512, 512);
  k_convbt<<<ceildiv(NTAPK * 512, 256), 256, 0, stream>>>(convw, convWt);
  k_bt<<<ceildiv(512 * 640, 256), 256, 0, stream>>>(mw1, mw1t, 512, 640, 640);
  k_bt<<<ceildiv(256 * 512, 256), 256, 0, stream>>>(mw2, mw2t, 256, 512, 512);
  k_bt<<<ceildiv(TGT * 256, 256), 256, 0, stream>>>(mw3, mw3t, TGT, 256, 256);

  // ---- GAT layer 1 ----
  k_medge<<<1, 64, 0, stream>>>(g1We, g1ae, Medge);
  k_aedge<<<ceildiv(NE * 4, 256), 256, 0, stream>>>(eattr, Medge, aedge, NE);
  k_aedge<<<ceildiv(NNODE * 4, 256), 256, 0, stream>>>(lattr, Medge, aeloop, NNODE);
  {
    dim3 g(4, ceildiv(NNODE, 128));
    mgemm<128, 128, unsigned short><<<g, 256, 0, stream>>>(
        NNODE, HC, 128, 128, nodesb, 128, g1Wt, nullptr, 1.0f, xpb, HC);
  }
  k_attn_dots<<<ceildiv(NNODE, 4), 256, 0, stream>>>(xpb, g1as, g1ad, asrc, adst);
  k_aggregate<<<ceildiv(NNODE, 4), 256, 0, stream>>>(xpb, asrc, adst, aedge, aeloop, esrc,
                                                     rowptr, colidx, g1b, h1b, HC, 0);

  // ---- GAT layer 2 (aggregation writes zin[:,0:512] directly, poles dropped) ----
  k_medge<<<1, 64, 0, stream>>>(g2We, g2ae, Medge);
  k_aedge<<<ceildiv(NE * 4, 256), 256, 0, stream>>>(eattr, Medge, aedge, NE);
  k_aedge<<<ceildiv(NNODE * 4, 256), 256, 0, stream>>>(lattr, Medge, aeloop, NNODE);
  {
    dim3 g(4, ceildiv(NNODE, 128));
    mgemm<128, 128, unsigned short><<<g, 256, 0, stream>>>(
        NNODE, HC, HC, HC, h1b, HC, g2Wt, nullptr, 1.0f, xpb, HC);
  }
  k_attn_dots<<<ceildiv(NNODE, 4), 256, 0, stream>>>(xpb, g2as, g2ad, asrc, adst);
  k_aggregate<<<ceildiv(NNODE, 4), 256, 0, stream>>>(xpb, asrc, adst, aedge, aeloop, esrc,
                                                     rowptr, colidx, g2b, zin, 640, 1);

  // ---- conv as tap-major GEMM + stencil tap-sum ----
  {
    dim3 g(NTAPK / 128, ceildiv(NPOS, 128));   // 9 x 128 = 1152 blocks
    mgemm<128, 128, unsigned short><<<g, 256, 0, stream>>>(
        NPOS, NTAPK, 512, 512, zin, 640, convWt, nullptr, 1.0f, Hb, NTAPK);
  }
  k_tapsum<<<ceildiv(NPOS * 16, 256), 256, 0, stream>>>(Hb, convb, bng, bnb, zin);

  // ---- MLP ----
  {
    dim3 g(4, ceildiv(NPOS, 128));
    mgemm<128, 128, unsigned short><<<g, 256, 0, stream>>>(
        NPOS, 512, 640, 640, zin, 640, mw1t, mb1, 0.01f, z1b, 512);
  }
  {
    dim3 g(2, ceildiv(NPOS, 64));   // 512 blocks
    mgemm<64, 128, unsigned short><<<g, 256, 0, stream>>>(
        NPOS, 256, 512, 512, z1b, 512, mw2t, mb2, 0.01f, z2b, 256);
  }
  {
    dim3 g(1, ceildiv(NPOS, 64));   // 256 blocks
    mgemm<64, 64, float><<<g, 256, 0, stream>>>(
        NPOS, TGT, 256, 256, z2b, 256, mw3t, mb3, 1.0f, z3, TGT);
  }

  k_final<<<ceildiv(NPOS * TGT, 256), 256, 0, stream>>>(z3, x, outp);
}

// Round 10
// 307.854 us; speedup vs baseline: 5.9070x; 1.0484x over previous
//
#include <hip/hip_runtime.h>
#include <math.h>
#include <type_traits>

// ---- problem constants ----
#define NB    2
#define HHH   64
#define WWW   128
#define F1    123      // 117 + 6
#define HC    512      // heads*hid
#define NE    131072
#define PB    8194     // nodes per batch (8192 + 2 poles)
#define NNODE (NB*PB)  // 16388
#define NPOS  (NB*HHH*WWW) // 16384
#define TGT   39
#define EMBED 128
#define KCONV 4608     // 512*9
#define NTAPK 1152     // 9*128 tap-major conv output width

static inline int ceildiv(int a, int b){ return (a + b - 1) / b; }

typedef short v8s __attribute__((ext_vector_type(8)));
typedef short v4s __attribute__((ext_vector_type(4)));
typedef float v4f __attribute__((ext_vector_type(4)));

__device__ __forceinline__ float leakyf(float x, float s){ return x >= 0.f ? x : s * x; }

__device__ __forceinline__ unsigned short f2b(float f) {
  unsigned u = __builtin_bit_cast(unsigned, f);
  u = (u + 0x7FFFu + ((u >> 16) & 1u)) >> 16;
  return (unsigned short)u;
}
__device__ __forceinline__ float b2f(unsigned short h) {
  unsigned u = ((unsigned)h) << 16;
  return __builtin_bit_cast(float, u);
}

// async global->LDS, 16 bytes per lane (dest = wave-uniform base + lane*16)
__device__ __forceinline__ void gload_lds16(const void* g, void* l) {
  __builtin_amdgcn_global_load_lds((const __attribute__((address_space(1))) void*)g,
                                   (__attribute__((address_space(3))) void*)l, 16, 0, 0);
}

// ---------------- build node features (bf16, K padded 123->128) ----------------
__global__ __launch_bounds__(256) void k_build_nodes(const float* __restrict__ x,
                                                     const float* __restrict__ xc,
                                                     unsigned short* __restrict__ nodes) {
  __shared__ unsigned short lds[64][130];
  int blk = blockIdx.x;             // NB*128 blocks
  int b = blk >> 7, p0 = (blk & 127) * 64;
  int tid = threadIdx.x;
  int pi = tid & 63, cg = tid >> 6;
  for (int c = cg; c < 128; c += 4) {
    float v = 0.f;
    int p = p0 + pi;
    if (c < 117)      v = x[((size_t)(b * 117 + c)) * 8192 + p];
    else if (c < 123) v = xc[((size_t)(b * 6 + (c - 117))) * 8192 + p];
    lds[pi][c] = f2b(v);
  }
  if ((blk & 127) == 0 && tid < 32) {
    int rr = tid >> 4, sg = tid & 15;
    *(v8s*)(nodes + ((size_t)(b * PB + rr)) * 128 + sg * 8) = (v8s)0;
  }
  __syncthreads();
  int seg = tid & 15, r0 = tid >> 4;
  for (int rr = r0; rr < 64; rr += 16) {
    int node = b * PB + 2 + p0 + rr;
    *(v8s*)(nodes + (size_t)node * 128 + seg * 8) = *(const v8s*)(&lds[rr][seg * 8]);
  }
}

// ---------------- CSR build ----------------
__global__ void k_hist(const int* __restrict__ dst, int* __restrict__ cnt) {
  int e = blockIdx.x * blockDim.x + threadIdx.x;
  if (e >= NE) return;
  atomicAdd(&cnt[dst[e]], 1);
}

__global__ void k_scan(const int* __restrict__ cnt, int* __restrict__ rowptr, int n) {
  __shared__ int part[512];
  int t = threadIdx.x;
  int chunk = (n + 511) >> 9;
  int beg = t * chunk, end = min(beg + chunk, n);
  int s = 0;
  for (int i = beg; i < end; i++) s += cnt[i];
  part[t] = s;
  __syncthreads();
  int own = s;
  for (int off = 1; off < 512; off <<= 1) {
    int v = 0;
    if (t >= off) v = part[t - off];
    __syncthreads();
    part[t] += v;
    __syncthreads();
  }
  int run = part[t] - own;   // exclusive prefix
  for (int i = beg; i < end; i++) { rowptr[i] = run; run += cnt[i]; }
  if (t == 511) rowptr[n] = part[511];
}

__global__ void k_copy_int(const int* __restrict__ a, int* __restrict__ b, int n) {
  int i = blockIdx.x * blockDim.x + threadIdx.x;
  if (i < n) b[i] = a[i];
}

__global__ void k_scatter(const int* __restrict__ dst, int* __restrict__ cursor,
                          int* __restrict__ colidx) {
  int e = blockIdx.x * blockDim.x + threadIdx.x;
  if (e >= NE) return;
  int pos = atomicAdd(&cursor[dst[e]], 1);
  colidx[pos] = e;
}

// loop_attr[n][k] = mean over incoming edges of edge_attr (0-safe divide)
__global__ void k_loop_attr(const float* __restrict__ eattr, const int* __restrict__ rowptr,
                            const int* __restrict__ colidx, float* __restrict__ lattr) {
  int idx = blockIdx.x * blockDim.x + threadIdx.x;
  if (idx >= NNODE * 8) return;
  int nn = idx >> 3, k = idx & 7;
  int b = rowptr[nn], e = rowptr[nn + 1];
  float s = 0.f;
  for (int i = b; i < e; i++) s += eattr[(size_t)colidx[i] * 8 + k];
  int c = e - b;
  lattr[idx] = s / (float)max(c, 1);
}

// ---------------- edge attention precompute ----------------
__global__ void k_medge(const float* __restrict__ We, const float* __restrict__ ae,
                        float* __restrict__ M) {
  int t = threadIdx.x;
  if (t >= 32) return;
  int k = t >> 2, h = t & 3;
  float s = 0.f;
  for (int c = 0; c < 128; c++) s += We[k * 512 + h * 128 + c] * ae[h * 128 + c];
  M[t] = s;
}

__global__ void k_aedge(const float* __restrict__ attr, const float* __restrict__ M,
                        float* __restrict__ out, int n) {
  int idx = blockIdx.x * blockDim.x + threadIdx.x;
  if (idx >= n * 4) return;
  int e = idx >> 2, h = idx & 3;
  float s = 0.f;
#pragma unroll
  for (int k = 0; k < 8; k++) s += attr[(size_t)e * 8 + k] * M[k * 4 + h];
  out[idx] = s;
}

// a_src[n,h] = xp[n,h,:].att_src[h,:] from bf16 xp — one wave per node, 16B loads
__global__ void k_attn_dots(const unsigned short* __restrict__ xp, const float* __restrict__ as,
                            const float* __restrict__ ad, float* __restrict__ a_src,
                            float* __restrict__ a_dst) {
  int gw = (blockIdx.x * blockDim.x + threadIdx.x) >> 6;
  int lane = threadIdx.x & 63;
  if (gw >= NNODE) return;
  int h = lane >> 4;
  int c0 = (lane & 15) * 8;
  v8s v = *(const v8s*)(xp + (size_t)gw * HC + h * 128 + c0);
  const float* asr = as + h * 128 + c0;
  const float* adr = ad + h * 128 + c0;
  float s1 = 0.f, s2 = 0.f;
#pragma unroll
  for (int i = 0; i < 8; i++) {
    float f = b2f((unsigned short)v[i]);
    s1 += f * asr[i]; s2 += f * adr[i];
  }
  for (int off = 1; off < 16; off <<= 1) { s1 += __shfl_xor(s1, off); s2 += __shfl_xor(s2, off); }
  if ((lane & 15) == 0) { a_src[gw * 4 + h] = s1; a_dst[gw * 4 + h] = s2; }
}

// ---------------- GAT aggregation v3: one WAVE per node, register-only ----------------
__global__ __launch_bounds__(256) void k_aggregate(
    const unsigned short* __restrict__ xp, const float* __restrict__ a_src,
    const float* __restrict__ a_dst, const float* __restrict__ a_edge,
    const float* __restrict__ a_eloop, const int* __restrict__ srcv,
    const int* __restrict__ rowptr, const int* __restrict__ colidx,
    const float* __restrict__ bias, unsigned short* __restrict__ outp,
    int ldo, int pole) {
  int wid = threadIdx.x >> 6, lane = threadIdx.x & 63;
  int n = blockIdx.x * 4 + wid;
  if (n >= NNODE) return;
  if (pole) {
    int b = n / PB, loc = n - b * PB;
    if (loc < 2) return;
    outp += (size_t)(b * 8192 + loc - 2) * ldo;
  } else {
    outp += (size_t)n * ldo;
  }
  int beg = rowptr[n], deg = rowptr[n + 1] - beg;
  int total = deg + 1;          // + self loop
  int ha = lane & 3;            // alpha-role head
  int ea = lane >> 2;           // alpha-role edge slot (0..15)
  int hh = lane >> 4;           // gather-role head
  int c0 = lane * 8;            // gather-role channels
  float adn = a_dst[(size_t)n * 4 + ha];
  float m0 = -1e30f, m1 = -1e30f, m2 = -1e30f, m3 = -1e30f;
  float l0 = 0.f, l1 = 0.f, l2 = 0.f, l3 = 0.f;
  float acc[8] = {0.f, 0.f, 0.f, 0.f, 0.f, 0.f, 0.f, 0.f};
  for (int base = 0; base < total; base += 16) {
    int cnt = min(16, total - base);
    int ge = base + ea;
    int sn = n;
    float al = -1e30f;
    if (ea < cnt) {
      float aev;
      if (ge < deg) { int eid = colidx[beg + ge]; sn = srcv[eid]; aev = a_edge[(size_t)eid * 4 + ha]; }
      else          { aev = a_eloop[(size_t)n * 4 + ha]; }
      al = leakyf(a_src[(size_t)sn * 4 + ha] + adn + aev, 0.2f);
    }
    float cm = al;
    cm = fmaxf(cm, __shfl_xor(cm, 4));
    cm = fmaxf(cm, __shfl_xor(cm, 8));
    cm = fmaxf(cm, __shfl_xor(cm, 16));
    cm = fmaxf(cm, __shfl_xor(cm, 32));
    float cm0 = __shfl(cm, 0), cm1 = __shfl(cm, 1), cm2 = __shfl(cm, 2), cm3 = __shfl(cm, 3);
    float nm0 = fmaxf(m0, cm0), nm1 = fmaxf(m1, cm1), nm2 = fmaxf(m2, cm2), nm3 = fmaxf(m3, cm3);
    float r0 = __expf(m0 - nm0), r1 = __expf(m1 - nm1), r2 = __expf(m2 - nm2), r3 = __expf(m3 - nm3);
    float nmh = ha == 0 ? nm0 : ha == 1 ? nm1 : ha == 2 ? nm2 : nm3;
    float ex = (ea < cnt) ? __expf(al - nmh) : 0.f;
    float s = ex;
    s += __shfl_xor(s, 4);
    s += __shfl_xor(s, 8);
    s += __shfl_xor(s, 16);
    s += __shfl_xor(s, 32);
    float s0 = __shfl(s, 0), s1 = __shfl(s, 1), s2 = __shfl(s, 2), s3 = __shfl(s, 3);
    l0 = l0 * r0 + s0; l1 = l1 * r1 + s1; l2 = l2 * r2 + s2; l3 = l3 * r3 + s3;
    m0 = nm0; m1 = nm1; m2 = nm2; m3 = nm3;
    float rh = hh == 0 ? r0 : hh == 1 ? r1 : hh == 2 ? r2 : r3;
#pragma unroll
    for (int j = 0; j < 8; j++) acc[j] *= rh;
    for (int e = 0; e < cnt; e++) {
      float wt = __shfl(ex, e * 4 + hh);
      int se = __shfl(sn, e * 4);
      v8s v = *(const v8s*)(xp + (size_t)se * HC + c0);
#pragma unroll
      for (int j = 0; j < 8; j++) acc[j] += wt * b2f((unsigned short)v[j]);
    }
  }
  float lh = hh == 0 ? l0 : hh == 1 ? l1 : hh == 2 ? l2 : l3;
  float inv = 1.f / lh;
  v8s o;
#pragma unroll
  for (int j = 0; j < 8; j++) {
    float v = acc[j] * inv + bias[c0 + j];
    o[j] = (short)f2b(leakyf(v, 0.01f));
  }
  *(v8s*)(outp + c0) = o;
}

// ---------------- weight prep: Bt[n][k] = bf16(src[k*N+n]), K padded ----------------
__global__ void k_bt(const float* __restrict__ src, unsigned short* __restrict__ bt,
                     int N, int Ks, int Kd) {
  int idx = blockIdx.x * blockDim.x + threadIdx.x;
  if (idx >= N * Kd) return;
  int n = idx / Kd, k = idx - n * Kd;
  bt[idx] = (k < Ks) ? f2b(src[(size_t)k * N + n]) : (unsigned short)0;
}

// conv weights, tap-major: bt[j][c], j = tap*128+n  <- convw[n][c][tap]
__global__ void k_convbt(const float* __restrict__ w, unsigned short* __restrict__ bt) {
  int idx = blockIdx.x * blockDim.x + threadIdx.x;
  if (idx >= NTAPK * 512) return;
  int j = idx >> 9, c = idx & 511;
  int tap = j >> 7, nn = j & 127;
  bt[idx] = f2b(w[(size_t)nn * KCONV + c * 9 + tap]);
}

// ---------------- bf16 MFMA GEMM: XCD swizzle + hoisted staging ptrs + LDS-repack epilogue ----------------
template<int BM, int BN, typename OutT>
__global__ __launch_bounds__(256) void mgemm(
    int M, int N, int K, int ldb,
    const unsigned short* __restrict__ A, int lda,
    const unsigned short* __restrict__ Bt,
    const float* __restrict__ bias,
    float slope,
    OutT* __restrict__ C, int ldc)
{
  constexpr int WM = BM / 32;
  constexpr int WN = BN / 32;
  constexpr int NA = BM * 4 / 256;   // A 16B-chunks per thread
  constexpr int NBC = BN * 4 / 256;  // B 16B-chunks per thread
  constexpr int STAGE_USH = 2 * (BM + BN) * 32;
  constexpr int REPACK_USH = 32 * BN * 2;   // 32 x BN floats
  constexpr int SMEM_USH = STAGE_USH > REPACK_USH ? STAGE_USH : REPACK_USH;
  __shared__ unsigned short smem[SMEM_USH];
  int tid = threadIdx.x;
  int wid = tid >> 6, lane = tid & 63;
  int wr = wid >> 1, wc = wid & 1;
  int l15 = lane & 15, l4 = lane >> 4;

  // --- XCD swizzle (bijective for any nwg, m204) ---
  int gx = gridDim.x;
  int nwg = gx * gridDim.y;
  int slot = blockIdx.x + blockIdx.y * gx;
  int qv = nwg >> 3, rv = nwg & 7;
  int xcd = slot & 7, pos = slot >> 3;
  int wg = (xcd < rv ? xcd * (qv + 1) : rv * (qv + 1) + (xcd - rv) * qv) + pos;
  int bx = wg % gx, by = wg / gx;
  int row0 = by * BM, col0 = bx * BN;

  // --- hoisted per-thread staging source pointers (clamp + 64b mul ONCE) ---
  const unsigned short* pa[NA];
  const unsigned short* pb[NBC];
#pragma unroll
  for (int i = 0; i < NA; i++) {
    int c = i * 256 + tid, r2 = c >> 2, seg = c & 3;
    pa[i] = A + (size_t)min(row0 + r2, M - 1) * lda + seg * 8;
  }
#pragma unroll
  for (int i = 0; i < NBC; i++) {
    int c = i * 256 + tid, r2 = c >> 2, seg = c & 3;
    pb[i] = Bt + (size_t)min(col0 + r2, N - 1) * ldb + seg * 8;
  }

  auto stage = [&](int buf, int kt) {
    int k0 = kt * 32;
    unsigned short* as = smem + buf * (BM * 32);
    unsigned short* bs = smem + 2 * BM * 32 + buf * (BN * 32);
#pragma unroll
    for (int i = 0; i < NA; i++)
      gload_lds16(pa[i] + k0, as + (i * 256 + tid) * 8);
#pragma unroll
    for (int i = 0; i < NBC; i++)
      gload_lds16(pb[i] + k0, bs + (i * 256 + tid) * 8);
  };

  v4f acc[WM][WN];
#pragma unroll
  for (int m = 0; m < WM; m++)
#pragma unroll
    for (int n = 0; n < WN; n++) acc[m][n] = (v4f)0.f;

  int nt = K >> 5;
  stage(0, 0);
  __syncthreads();
  int cur = 0;
  for (int t = 0; t < nt - 1; t++) {
    stage(cur ^ 1, t + 1);
    const unsigned short* as = smem + cur * (BM * 32);
    const unsigned short* bs = smem + 2 * BM * 32 + cur * (BN * 32);
    v8s a[WM], b[WN];
#pragma unroll
    for (int m = 0; m < WM; m++)
      a[m] = *(const v8s*)(as + (wr * (BM / 2) + m * 16 + l15) * 32 + l4 * 8);
#pragma unroll
    for (int n = 0; n < WN; n++)
      b[n] = *(const v8s*)(bs + (wc * (BN / 2) + n * 16 + l15) * 32 + l4 * 8);
#pragma unroll
    for (int m = 0; m < WM; m++)
#pragma unroll
      for (int n = 0; n < WN; n++)
        acc[m][n] = __builtin_amdgcn_mfma_f32_16x16x32_bf16(a[m], b[n], acc[m][n], 0, 0, 0);
    __syncthreads();
    cur ^= 1;
  }
  {
    const unsigned short* as = smem + cur * (BM * 32);
    const unsigned short* bs = smem + 2 * BM * 32 + cur * (BN * 32);
    v8s a[WM], b[WN];
#pragma unroll
    for (int m = 0; m < WM; m++)
      a[m] = *(const v8s*)(as + (wr * (BM / 2) + m * 16 + l15) * 32 + l4 * 8);
#pragma unroll
    for (int n = 0; n < WN; n++)
      b[n] = *(const v8s*)(bs + (wc * (BN / 2) + n * 16 + l15) * 32 + l4 * 8);
#pragma unroll
    for (int m = 0; m < WM; m++)
#pragma unroll
      for (int n = 0; n < WN; n++)
        acc[m][n] = __builtin_amdgcn_mfma_f32_16x16x32_bf16(a[m], b[n], acc[m][n], 0, 0, 0);
  }

  if constexpr (std::is_same<OutT, float>::value) {
    // scalar epilogue (fp32 out, small N)
#pragma unroll
    for (int m = 0; m < WM; m++) {
#pragma unroll
      for (int q2 = 0; q2 < 4; q2++) {
        int r2 = row0 + wr * (BM / 2) + m * 16 + l4 * 4 + q2;
        if (r2 >= M) continue;
#pragma unroll
        for (int n = 0; n < WN; n++) {
          int cc = col0 + wc * (BN / 2) + n * 16 + l15;
          if (cc >= N) continue;
          float v = acc[m][n][q2];
          if (bias) v += bias[cc];
          v = leakyf(v, slope);
          C[(size_t)r2 * ldc + cc] = v;
        }
      }
    }
  } else {
    // LDS-repack epilogue: vectorized bf16 stores (requires N % BN == 0)
    __syncthreads();               // all waves done reading stage LDS
    float* rb = (float*)smem;      // 32 x BN floats per m-iter
    for (int m = 0; m < WM; m++) {
#pragma unroll
      for (int n = 0; n < WN; n++)
#pragma unroll
        for (int q2 = 0; q2 < 4; q2++)
          rb[(wr * 16 + l4 * 4 + q2) * BN + wc * (BN / 2) + n * 16 + l15] = acc[m][n][q2];
      __syncthreads();
#pragma unroll
      for (int it = 0; it < (32 * BN) / 1024; it++) {
        int f = it * 1024 + tid * 4;
        int lr = f / BN, lc = f % BN;
        int rr = row0 + (lr >> 4) * (BM / 2) + m * 16 + (lr & 15);
        if (rr < M) {
          v4f vv = *(const v4f*)(rb + lr * BN + lc);
          v4s o;
#pragma unroll
          for (int j = 0; j < 4; j++) {
            float v = vv[j];
            if (bias) v += bias[col0 + lc + j];
            v = leakyf(v, slope);
            o[j] = (short)f2b(v);
          }
          *(v4s*)(C + (size_t)rr * ldc + col0 + lc) = o;
        }
      }
      __syncthreads();
    }
  }
}

// ---------------- conv tap-sum stencil: zin[:,512:640] = leaky(BN(bias + Σ_tap H[nbr,tap])) ----------------
__global__ void k_tapsum(const unsigned short* __restrict__ H,
                         const float* __restrict__ convb, const float* __restrict__ bng,
                         const float* __restrict__ bnb, unsigned short* __restrict__ zin) {
  int idx = blockIdx.x * blockDim.x + threadIdx.x;   // NPOS*16
  if (idx >= NPOS * 16) return;
  int r = idx >> 4, seg = idx & 15;
  int n0 = seg * 8;
  int b = r >> 13, pos = r & 8191, i = pos >> 7, j = pos & 127;
  float acc[8] = {0.f, 0.f, 0.f, 0.f, 0.f, 0.f, 0.f, 0.f};
#pragma unroll
  for (int tap = 0; tap < 9; tap++) {
    int di = tap / 3, dj = tap - di * 3;
    int rr = i + di, cc = j + dj;
    int gr, gc;
    if (rr == 0)       { gr = 1;      gc = (63 + cc) & 127; }
    else if (rr == 65) { gr = 62;     gc = (63 + cc) & 127; }
    else               { gr = rr - 1; gc = (cc + 127) & 127; }
    v8s v = *(const v8s*)(H + ((size_t)(b * 8192 + gr * WWW + gc)) * NTAPK + tap * 128 + n0);
#pragma unroll
    for (int q = 0; q < 8; q++) acc[q] += b2f((unsigned short)v[q]);
  }
  unsigned short* o = zin + (size_t)r * 640 + 512 + n0;
  v8s ov;
#pragma unroll
  for (int q = 0; q < 8; q++) {
    int cc = n0 + q;
    float v = acc[q] + convb[cc];
    v = v * (bng[cc] * rsqrtf(1.f + 1e-5f)) + bnb[cc];
    ov[q] = (short)f2b(leakyf(v, 0.01f));
  }
  *(v8s*)o = ov;
}

// ---------------- final: out[b,t,i,j] = z3[(b*8192+p), t] + x[b, 78+t, p] ----------------
__global__ void k_final(const float* __restrict__ z3, const float* __restrict__ x,
                        float* __restrict__ outp) {
  int idx = blockIdx.x * blockDim.x + threadIdx.x;
  if (idx >= NPOS * TGT) return;
  int b = idx / (TGT * 8192);
  int rem = idx - b * (TGT * 8192);
  int t = rem >> 13;
  int p = rem & 8191;
  outp[idx] = z3[((size_t)(b * 8192 + p)) * TGT + t] + x[((size_t)(b * 117 + 78 + t)) * 8192 + p];
}

// ================================================================
extern "C" void kernel_launch(void* const* d_in, const int* in_sizes, int n_in,
                              void* d_out, int out_size, void* d_ws, size_t ws_size,
                              hipStream_t stream) {
  const float* x     = (const float*)d_in[0];
  const float* xcons = (const float*)d_in[1];
  const int*   eidx  = (const int*)d_in[2];
  const float* eattr = (const float*)d_in[3];
  const float* g1W  = (const float*)d_in[4];
  const float* g1as = (const float*)d_in[5];
  const float* g1ad = (const float*)d_in[6];
  const float* g1We = (const float*)d_in[7];
  const float* g1ae = (const float*)d_in[8];
  const float* g1b  = (const float*)d_in[9];
  const float* g2W  = (const float*)d_in[10];
  const float* g2as = (const float*)d_in[11];
  const float* g2ad = (const float*)d_in[12];
  const float* g2We = (const float*)d_in[13];
  const float* g2ae = (const float*)d_in[14];
  const float* g2b  = (const float*)d_in[15];
  const float* convw= (const float*)d_in[16];
  const float* convb= (const float*)d_in[17];
  const float* bng  = (const float*)d_in[18];
  const float* bnb  = (const float*)d_in[19];
  const float* mw1  = (const float*)d_in[20];
  const float* mb1  = (const float*)d_in[21];
  const float* mw2  = (const float*)d_in[22];
  const float* mb2  = (const float*)d_in[23];
  const float* mw3  = (const float*)d_in[24];
  const float* mb3  = (const float*)d_in[25];
  float* outp = (float*)d_out;
  (void)in_sizes; (void)n_in; (void)out_size; (void)ws_size;

  const int* esrc = eidx;
  const int* edst = eidx + NE;

  char* basep = (char*)d_ws;
  size_t off = 0;
  auto alloc = [&](size_t bytes) -> void* {
    void* p = basep + off;
    off += (bytes + 255) & ~(size_t)255;
    return p;
  };
  unsigned short* nodesb = (unsigned short*)alloc((size_t)NNODE * 128 * 2);
  unsigned short* xpb    = (unsigned short*)alloc((size_t)NNODE * HC * 2);
  unsigned short* h1b    = (unsigned short*)alloc((size_t)NNODE * HC * 2);
  unsigned short* zin    = (unsigned short*)alloc((size_t)NPOS * 640 * 2);
  unsigned short* Hb     = (unsigned short*)alloc((size_t)NPOS * NTAPK * 2);
  float* asrc   = (float*)alloc((size_t)NNODE * 4 * sizeof(float));
  float* adst   = (float*)alloc((size_t)NNODE * 4 * sizeof(float));
  float* aedge  = (float*)alloc((size_t)NE * 4 * sizeof(float));
  float* aeloop = (float*)alloc((size_t)NNODE * 4 * sizeof(float));
  float* lattr  = (float*)alloc((size_t)NNODE * 8 * sizeof(float));
  float* Medge  = (float*)alloc(32 * sizeof(float));
  unsigned short* g1Wt  = (unsigned short*)alloc((size_t)512 * 128 * 2);
  unsigned short* g2Wt  = (unsigned short*)alloc((size_t)512 * 512 * 2);
  unsigned short* convWt= (unsigned short*)alloc((size_t)NTAPK * 512 * 2);
  unsigned short* mw1t  = (unsigned short*)alloc((size_t)512 * 640 * 2);
  unsigned short* mw2t  = (unsigned short*)alloc((size_t)256 * 512 * 2);
  unsigned short* mw3t  = (unsigned short*)alloc((size_t)TGT * 256 * 2);
  int* cnt      = (int*)alloc((size_t)NNODE * sizeof(int));
  int* rowptr   = (int*)alloc((size_t)(NNODE + 1) * sizeof(int));
  int* cursor   = (int*)alloc((size_t)NNODE * sizeof(int));
  int* colidx   = (int*)alloc((size_t)NE * sizeof(int));
  unsigned short* z1b = xpb;             // xpb dead after GAT2 aggregation
  unsigned short* z2b = h1b;             // h1b dead after GAT2 xp GEMM
  float*          z3  = (float*)nodesb;  // nodesb dead after GAT1 xp GEMM

  hipMemsetAsync(cnt, 0, NNODE * sizeof(int), stream);
  k_build_nodes<<<NB * 128, 256, 0, stream>>>(x, xcons, nodesb);
  k_hist<<<ceildiv(NE, 256), 256, 0, stream>>>(edst, cnt);
  k_scan<<<1, 512, 0, stream>>>(cnt, rowptr, NNODE);
  k_copy_int<<<ceildiv(NNODE, 256), 256, 0, stream>>>(rowptr, cursor, NNODE);
  k_scatter<<<ceildiv(NE, 256), 256, 0, stream>>>(edst, cursor, colidx);
  k_loop_attr<<<ceildiv(NNODE * 8, 256), 256, 0, stream>>>(eattr, rowptr, colidx, lattr);

  // weight prep
  k_bt<<<ceildiv(512 * 128, 256), 256, 0, stream>>>(g1W, g1Wt, 512, F1, 128);
  k_bt<<<ceildiv(512 * 512, 256), 256, 0, stream>>>(g2W, g2Wt, 512, 512, 512);
  k_convbt<<<ceildiv(NTAPK * 512, 256), 256, 0, stream>>>(convw, convWt);
  k_bt<<<ceildiv(512 * 640, 256), 256, 0, stream>>>(mw1, mw1t, 512, 640, 640);
  k_bt<<<ceildiv(256 * 512, 256), 256, 0, stream>>>(mw2, mw2t, 256, 512, 512);
  k_bt<<<ceildiv(TGT * 256, 256), 256, 0, stream>>>(mw3, mw3t, TGT, 256, 256);

  // ---- GAT layer 1 ----
  k_medge<<<1, 64, 0, stream>>>(g1We, g1ae, Medge);
  k_aedge<<<ceildiv(NE * 4, 256), 256, 0, stream>>>(eattr, Medge, aedge, NE);
  k_aedge<<<ceildiv(NNODE * 4, 256), 256, 0, stream>>>(lattr, Medge, aeloop, NNODE);
  {
    dim3 g(4, ceildiv(NNODE, 128));
    mgemm<128, 128, unsigned short><<<g, 256, 0, stream>>>(
        NNODE, HC, 128, 128, nodesb, 128, g1Wt, nullptr, 1.0f, xpb, HC);
  }
  k_attn_dots<<<ceildiv(NNODE, 4), 256, 0, stream>>>(xpb, g1as, g1ad, asrc, adst);
  k_aggregate<<<ceildiv(NNODE, 4), 256, 0, stream>>>(xpb, asrc, adst, aedge, aeloop, esrc,
                                                     rowptr, colidx, g1b, h1b, HC, 0);

  // ---- GAT layer 2 (aggregation writes zin[:,0:512] directly, poles dropped) ----
  k_medge<<<1, 64, 0, stream>>>(g2We, g2ae, Medge);
  k_aedge<<<ceildiv(NE * 4, 256), 256, 0, stream>>>(eattr, Medge, aedge, NE);
  k_aedge<<<ceildiv(NNODE * 4, 256), 256, 0, stream>>>(lattr, Medge, aeloop, NNODE);
  {
    dim3 g(4, ceildiv(NNODE, 128));
    mgemm<128, 128, unsigned short><<<g, 256, 0, stream>>>(
        NNODE, HC, HC, HC, h1b, HC, g2Wt, nullptr, 1.0f, xpb, HC);
  }
  k_attn_dots<<<ceildiv(NNODE, 4), 256, 0, stream>>>(xpb, g2as, g2ad, asrc, adst);
  k_aggregate<<<ceildiv(NNODE, 4), 256, 0, stream>>>(xpb, asrc, adst, aedge, aeloop, esrc,
                                                     rowptr, colidx, g2b, zin, 640, 1);

  // ---- conv as tap-major GEMM + stencil tap-sum ----
  {
    dim3 g(NTAPK / 128, ceildiv(NPOS, 128));   // 9 x 128 = 1152 blocks
    mgemm<128, 128, unsigned short><<<g, 256, 0, stream>>>(
        NPOS, NTAPK, 512, 512, zin, 640, convWt, nullptr, 1.0f, Hb, NTAPK);
  }
  k_tapsum<<<ceildiv(NPOS * 16, 256), 256, 0, stream>>>(Hb, convb, bng, bnb, zin);

  // ---- MLP ----
  {
    dim3 g(4, ceildiv(NPOS, 128));
    mgemm<128, 128, unsigned short><<<g, 256, 0, stream>>>(
        NPOS, 512, 640, 640, zin, 640, mw1t, mb1, 0.01f, z1b, 512);
  }
  {
    dim3 g(2, ceildiv(NPOS, 64));   // 512 blocks
    mgemm<64, 128, unsigned short><<<g, 256, 0, stream>>>(
        NPOS, 256, 512, 512, z1b, 512, mw2t, mb2, 0.01f, z2b, 256);
  }
  {
    dim3 g(1, ceildiv(NPOS, 64));   // 256 blocks
    mgemm<64, 64, float><<<g, 256, 0, stream>>>(
        NPOS, TGT, 256, 256, z2b, 256, mw3t, mb3, 1.0f, z3, TGT);
  }

  k_final<<<ceildiv(NPOS * TGT, 256), 256, 0, stream>>>(z3, x, outp);
}

// Round 11
// 304.320 us; speedup vs baseline: 5.9756x; 1.0116x over previous
//
#include <hip/hip_runtime.h>
#include <math.h>
#include <type_traits>

// ---- problem constants ----
#define NB    2
#define HHH   64
#define WWW   128
#define F1    123      // 117 + 6
#define HC    512      // heads*hid
#define NE    131072
#define PB    8194     // nodes per batch (8192 + 2 poles)
#define NNODE (NB*PB)  // 16388
#define NPOS  (NB*HHH*WWW) // 16384
#define TGT   39
#define EMBED 128
#define KCONV 4608     // 512*9
#define NTAPK 1152     // 9*128 tap-major conv output width

static inline int ceildiv(int a, int b){ return (a + b - 1) / b; }

typedef short v8s __attribute__((ext_vector_type(8)));
typedef short v4s __attribute__((ext_vector_type(4)));
typedef float v4f __attribute__((ext_vector_type(4)));

__device__ __forceinline__ float leakyf(float x, float s){ return x >= 0.f ? x : s * x; }

__device__ __forceinline__ unsigned short f2b(float f) {
  unsigned u = __builtin_bit_cast(unsigned, f);
  u = (u + 0x7FFFu + ((u >> 16) & 1u)) >> 16;
  return (unsigned short)u;
}
__device__ __forceinline__ float b2f(unsigned short h) {
  unsigned u = ((unsigned)h) << 16;
  return __builtin_bit_cast(float, u);
}

// async global->LDS, 16 bytes per lane (dest = wave-uniform base + lane*16)
__device__ __forceinline__ void gload_lds16(const void* g, void* l) {
  __builtin_amdgcn_global_load_lds((const __attribute__((address_space(1))) void*)g,
                                   (__attribute__((address_space(3))) void*)l, 16, 0, 0);
}

// ---------------- build node features (bf16, K padded 123->128) ----------------
__global__ __launch_bounds__(256) void k_build_nodes(const float* __restrict__ x,
                                                     const float* __restrict__ xc,
                                                     unsigned short* __restrict__ nodes) {
  __shared__ unsigned short lds[64][130];
  int blk = blockIdx.x;             // NB*128 blocks
  int b = blk >> 7, p0 = (blk & 127) * 64;
  int tid = threadIdx.x;
  int pi = tid & 63, cg = tid >> 6;
  for (int c = cg; c < 128; c += 4) {
    float v = 0.f;
    int p = p0 + pi;
    if (c < 117)      v = x[((size_t)(b * 117 + c)) * 8192 + p];
    else if (c < 123) v = xc[((size_t)(b * 6 + (c - 117))) * 8192 + p];
    lds[pi][c] = f2b(v);
  }
  if ((blk & 127) == 0 && tid < 32) {
    int rr = tid >> 4, sg = tid & 15;
    *(v8s*)(nodes + ((size_t)(b * PB + rr)) * 128 + sg * 8) = (v8s)0;
  }
  __syncthreads();
  int seg = tid & 15, r0 = tid >> 4;
  for (int rr = r0; rr < 64; rr += 16) {
    int node = b * PB + 2 + p0 + rr;
    *(v8s*)(nodes + (size_t)node * 128 + seg * 8) = *(const v8s*)(&lds[rr][seg * 8]);
  }
}

// ---------------- CSR build ----------------
__global__ void k_hist(const int* __restrict__ dst, int* __restrict__ cnt) {
  int e = blockIdx.x * blockDim.x + threadIdx.x;
  if (e >= NE) return;
  atomicAdd(&cnt[dst[e]], 1);
}

__global__ void k_scan(const int* __restrict__ cnt, int* __restrict__ rowptr,
                       int* __restrict__ cursor, int n) {
  __shared__ int part[512];
  int t = threadIdx.x;
  int chunk = (n + 511) >> 9;
  int beg = t * chunk, end = min(beg + chunk, n);
  int s = 0;
  for (int i = beg; i < end; i++) s += cnt[i];
  part[t] = s;
  __syncthreads();
  int own = s;
  for (int off = 1; off < 512; off <<= 1) {
    int v = 0;
    if (t >= off) v = part[t - off];
    __syncthreads();
    part[t] += v;
    __syncthreads();
  }
  int run = part[t] - own;   // exclusive prefix
  for (int i = beg; i < end; i++) { rowptr[i] = run; cursor[i] = run; run += cnt[i]; }
  if (t == 511) rowptr[n] = part[511];
}

__global__ void k_scatter(const int* __restrict__ dst, int* __restrict__ cursor,
                          int* __restrict__ colidx) {
  int e = blockIdx.x * blockDim.x + threadIdx.x;
  if (e >= NE) return;
  int pos = atomicAdd(&cursor[dst[e]], 1);
  colidx[pos] = e;
}

// loop_attr[n][k] = mean over incoming edges of edge_attr (0-safe divide)
__global__ void k_loop_attr(const float* __restrict__ eattr, const int* __restrict__ rowptr,
                            const int* __restrict__ colidx, float* __restrict__ lattr) {
  int idx = blockIdx.x * blockDim.x + threadIdx.x;
  if (idx >= NNODE * 8) return;
  int nn = idx >> 3, k = idx & 7;
  int b = rowptr[nn], e = rowptr[nn + 1];
  float s = 0.f;
  for (int i = b; i < e; i++) s += eattr[(size_t)colidx[i] * 8 + k];
  int c = e - b;
  lattr[idx] = s / (float)max(c, 1);
}

// ---------------- fused weight prep (all 6 transposes in one launch) ----------------
// seg sizes: 65536, 262144, 589824, 327680, 131072, 9984  (total 1386240)
__global__ void k_prep(const float* __restrict__ g1W, const float* __restrict__ g2W,
                       const float* __restrict__ convw, const float* __restrict__ mw1,
                       const float* __restrict__ mw2, const float* __restrict__ mw3,
                       unsigned short* __restrict__ g1Wt, unsigned short* __restrict__ g2Wt,
                       unsigned short* __restrict__ convWt, unsigned short* __restrict__ mw1t,
                       unsigned short* __restrict__ mw2t, unsigned short* __restrict__ mw3t) {
  int idx = blockIdx.x * blockDim.x + threadIdx.x;
  if (idx < 65536) {                       // g1Wt[n][k], Kd=128, Ks=123, N=512
    int n = idx >> 7, k = idx & 127;
    g1Wt[idx] = (k < F1) ? f2b(g1W[(size_t)k * 512 + n]) : (unsigned short)0;
  } else if ((idx -= 65536) < 262144) {    // g2Wt[n][k], Kd=512
    int n = idx >> 9, k = idx & 511;
    g2Wt[idx] = f2b(g2W[(size_t)k * 512 + n]);
  } else if ((idx -= 262144) < 589824) {   // convWt[j][c], j=tap*128+nn
    int j = idx >> 9, c = idx & 511;
    int tap = j >> 7, nn = j & 127;
    convWt[idx] = f2b(convw[(size_t)nn * KCONV + c * 9 + tap]);
  } else if ((idx -= 589824) < 327680) {   // mw1t[n][k], Kd=640
    int n = idx / 640, k = idx - n * 640;
    mw1t[idx] = f2b(mw1[(size_t)k * 512 + n]);
  } else if ((idx -= 327680) < 131072) {   // mw2t[n][k], Kd=512
    int n = idx >> 9, k = idx & 511;
    mw2t[idx] = f2b(mw2[(size_t)k * 256 + n]);
  } else if ((idx -= 131072) < 9984) {     // mw3t[n][k], Kd=256, N=39
    int n = idx >> 8, k = idx & 255;
    mw3t[idx] = f2b(mw3[(size_t)k * TGT + n]);
  }
}

// ---------------- both layers' Medge in one launch: M2[layer*32 + k*4+h] ----------------
__global__ void k_medge2(const float* __restrict__ We1, const float* __restrict__ ae1,
                         const float* __restrict__ We2, const float* __restrict__ ae2,
                         float* __restrict__ M2) {
  int t = threadIdx.x;
  if (t >= 32) return;
  const float* We = blockIdx.x ? We2 : We1;
  const float* ae = blockIdx.x ? ae2 : ae1;
  int k = t >> 2, h = t & 3;
  float s = 0.f;
  for (int c = 0; c < 128; c++) s += We[k * 512 + h * 128 + c] * ae[h * 128 + c];
  M2[blockIdx.x * 32 + t] = s;
}

// ---------------- both layers' edge-alpha (edges + self-loops) in one pass ----------------
__global__ void k_aedge2(const float* __restrict__ eattr, const float* __restrict__ lattr,
                         const float* __restrict__ M2,
                         float* __restrict__ ae1, float* __restrict__ ae2,
                         float* __restrict__ al1, float* __restrict__ al2) {
  int idx = blockIdx.x * blockDim.x + threadIdx.x;
  if (idx >= (NE + NNODE) * 4) return;
  int e = idx >> 2, h = idx & 3;
  const float* src;
  float *o1, *o2;
  if (e < NE) { src = eattr + (size_t)e * 8; o1 = ae1 + idx; o2 = ae2 + idx; }
  else {
    int n = e - NE;
    src = lattr + (size_t)n * 8;
    o1 = al1 + n * 4 + h; o2 = al2 + n * 4 + h;
  }
  float s1 = 0.f, s2 = 0.f;
#pragma unroll
  for (int k = 0; k < 8; k++) {
    float a = src[k];
    s1 += a * M2[k * 4 + h];
    s2 += a * M2[32 + k * 4 + h];
  }
  *o1 = s1; *o2 = s2;
}

// a_src[n,h] = xp[n,h,:].att_src[h,:] from bf16 xp — one wave per node, 16B loads
__global__ void k_attn_dots(const unsigned short* __restrict__ xp, const float* __restrict__ as,
                            const float* __restrict__ ad, float* __restrict__ a_src,
                            float* __restrict__ a_dst) {
  int gw = (blockIdx.x * blockDim.x + threadIdx.x) >> 6;
  int lane = threadIdx.x & 63;
  if (gw >= NNODE) return;
  int h = lane >> 4;
  int c0 = (lane & 15) * 8;
  v8s v = *(const v8s*)(xp + (size_t)gw * HC + h * 128 + c0);
  const float* asr = as + h * 128 + c0;
  const float* adr = ad + h * 128 + c0;
  float s1 = 0.f, s2 = 0.f;
#pragma unroll
  for (int i = 0; i < 8; i++) {
    float f = b2f((unsigned short)v[i]);
    s1 += f * asr[i]; s2 += f * adr[i];
  }
  for (int off = 1; off < 16; off <<= 1) { s1 += __shfl_xor(s1, off); s2 += __shfl_xor(s2, off); }
  if ((lane & 15) == 0) { a_src[gw * 4 + h] = s1; a_dst[gw * 4 + h] = s2; }
}

// ---------------- GAT aggregation v4: one WAVE per node, 4-edge-batched gather ----------------
__global__ __launch_bounds__(256) void k_aggregate(
    const unsigned short* __restrict__ xp, const float* __restrict__ a_src,
    const float* __restrict__ a_dst, const float* __restrict__ a_edge,
    const float* __restrict__ a_eloop, const int* __restrict__ srcv,
    const int* __restrict__ rowptr, const int* __restrict__ colidx,
    const float* __restrict__ bias, unsigned short* __restrict__ outp,
    int ldo, int pole) {
  int wid = threadIdx.x >> 6, lane = threadIdx.x & 63;
  int n = blockIdx.x * 4 + wid;
  if (n >= NNODE) return;
  if (pole) {
    int b = n / PB, loc = n - b * PB;
    if (loc < 2) return;
    outp += (size_t)(b * 8192 + loc - 2) * ldo;
  } else {
    outp += (size_t)n * ldo;
  }
  int beg = rowptr[n], deg = rowptr[n + 1] - beg;
  int total = deg + 1;          // + self loop
  int ha = lane & 3;            // alpha-role head
  int ea = lane >> 2;           // alpha-role edge slot (0..15)
  int hh = lane >> 4;           // gather-role head
  int c0 = lane * 8;            // gather-role channels
  float adn = a_dst[(size_t)n * 4 + ha];
  float m0 = -1e30f, m1 = -1e30f, m2 = -1e30f, m3 = -1e30f;
  float l0 = 0.f, l1 = 0.f, l2 = 0.f, l3 = 0.f;
  float acc[8] = {0.f, 0.f, 0.f, 0.f, 0.f, 0.f, 0.f, 0.f};
  for (int base = 0; base < total; base += 16) {
    int cnt = min(16, total - base);
    int ge = base + ea;
    int sn = n;
    float al = -1e30f;
    if (ea < cnt) {
      float aev;
      if (ge < deg) { int eid = colidx[beg + ge]; sn = srcv[eid]; aev = a_edge[(size_t)eid * 4 + ha]; }
      else          { aev = a_eloop[(size_t)n * 4 + ha]; }
      al = leakyf(a_src[(size_t)sn * 4 + ha] + adn + aev, 0.2f);
    }
    float cm = al;
    cm = fmaxf(cm, __shfl_xor(cm, 4));
    cm = fmaxf(cm, __shfl_xor(cm, 8));
    cm = fmaxf(cm, __shfl_xor(cm, 16));
    cm = fmaxf(cm, __shfl_xor(cm, 32));
    float cm0 = __shfl(cm, 0), cm1 = __shfl(cm, 1), cm2 = __shfl(cm, 2), cm3 = __shfl(cm, 3);
    float nm0 = fmaxf(m0, cm0), nm1 = fmaxf(m1, cm1), nm2 = fmaxf(m2, cm2), nm3 = fmaxf(m3, cm3);
    float r0 = __expf(m0 - nm0), r1 = __expf(m1 - nm1), r2 = __expf(m2 - nm2), r3 = __expf(m3 - nm3);
    float nmh = ha == 0 ? nm0 : ha == 1 ? nm1 : ha == 2 ? nm2 : nm3;
    float ex = (ea < cnt) ? __expf(al - nmh) : 0.f;
    float s = ex;
    s += __shfl_xor(s, 4);
    s += __shfl_xor(s, 8);
    s += __shfl_xor(s, 16);
    s += __shfl_xor(s, 32);
    float s0 = __shfl(s, 0), s1 = __shfl(s, 1), s2 = __shfl(s, 2), s3 = __shfl(s, 3);
    l0 = l0 * r0 + s0; l1 = l1 * r1 + s1; l2 = l2 * r2 + s2; l3 = l3 * r3 + s3;
    m0 = nm0; m1 = nm1; m2 = nm2; m3 = nm3;
    float rh = hh == 0 ? r0 : hh == 1 ? r1 : hh == 2 ? r2 : r3;
#pragma unroll
    for (int j = 0; j < 8; j++) acc[j] *= rh;
    // gather: 4-edge batches — 4 independent 16B loads in flight (uniform branch)
    for (int e0 = 0; e0 < cnt; e0 += 4) {
      int nb = min(4, cnt - e0);
      v8s vv[4]; float wt[4];
#pragma unroll
      for (int u = 0; u < 4; u++) {
        if (u < nb) {
          int e = e0 + u;
          wt[u] = __shfl(ex, e * 4 + hh);
          int se = __shfl(sn, e * 4);
          vv[u] = *(const v8s*)(xp + (size_t)se * HC + c0);
        }
      }
#pragma unroll
      for (int u = 0; u < 4; u++) {
        if (u < nb) {
#pragma unroll
          for (int j = 0; j < 8; j++) acc[j] += wt[u] * b2f((unsigned short)vv[u][j]);
        }
      }
    }
  }
  float lh = hh == 0 ? l0 : hh == 1 ? l1 : hh == 2 ? l2 : l3;
  float inv = 1.f / lh;
  v8s o;
#pragma unroll
  for (int j = 0; j < 8; j++) {
    float v = acc[j] * inv + bias[c0 + j];
    o[j] = (short)f2b(leakyf(v, 0.01f));
  }
  *(v8s*)(outp + c0) = o;
}

// ---------------- bf16 MFMA GEMM: XCD swizzle + hoisted staging ptrs + LDS-repack epilogue ----------------
template<int BM, int BN, typename OutT>
__global__ __launch_bounds__(256) void mgemm(
    int M, int N, int K, int ldb,
    const unsigned short* __restrict__ A, int lda,
    const unsigned short* __restrict__ Bt,
    const float* __restrict__ bias,
    float slope,
    OutT* __restrict__ C, int ldc)
{
  constexpr int WM = BM / 32;
  constexpr int WN = BN / 32;
  constexpr int NA = BM * 4 / 256;   // A 16B-chunks per thread
  constexpr int NBC = BN * 4 / 256;  // B 16B-chunks per thread
  constexpr int STAGE_USH = 2 * (BM + BN) * 32;
  constexpr int REPACK_USH = 32 * BN * 2;   // 32 x BN floats
  constexpr int SMEM_USH = STAGE_USH > REPACK_USH ? STAGE_USH : REPACK_USH;
  __shared__ unsigned short smem[SMEM_USH];
  int tid = threadIdx.x;
  int wid = tid >> 6, lane = tid & 63;
  int wr = wid >> 1, wc = wid & 1;
  int l15 = lane & 15, l4 = lane >> 4;

  // --- XCD swizzle (bijective for any nwg, m204) ---
  int gx = gridDim.x;
  int nwg = gx * gridDim.y;
  int slot = blockIdx.x + blockIdx.y * gx;
  int qv = nwg >> 3, rv = nwg & 7;
  int xcd = slot & 7, pos = slot >> 3;
  int wg = (xcd < rv ? xcd * (qv + 1) : rv * (qv + 1) + (xcd - rv) * qv) + pos;
  int bx = wg % gx, by = wg / gx;
  int row0 = by * BM, col0 = bx * BN;

  // --- hoisted per-thread staging source pointers ---
  const unsigned short* pa[NA];
  const unsigned short* pb[NBC];
#pragma unroll
  for (int i = 0; i < NA; i++) {
    int c = i * 256 + tid, r2 = c >> 2, seg = c & 3;
    pa[i] = A + (size_t)min(row0 + r2, M - 1) * lda + seg * 8;
  }
#pragma unroll
  for (int i = 0; i < NBC; i++) {
    int c = i * 256 + tid, r2 = c >> 2, seg = c & 3;
    pb[i] = Bt + (size_t)min(col0 + r2, N - 1) * ldb + seg * 8;
  }

  auto stage = [&](int buf, int kt) {
    int k0 = kt * 32;
    unsigned short* as = smem + buf * (BM * 32);
    unsigned short* bs = smem + 2 * BM * 32 + buf * (BN * 32);
#pragma unroll
    for (int i = 0; i < NA; i++)
      gload_lds16(pa[i] + k0, as + (i * 256 + tid) * 8);
#pragma unroll
    for (int i = 0; i < NBC; i++)
      gload_lds16(pb[i] + k0, bs + (i * 256 + tid) * 8);
  };

  v4f acc[WM][WN];
#pragma unroll
  for (int m = 0; m < WM; m++)
#pragma unroll
    for (int n = 0; n < WN; n++) acc[m][n] = (v4f)0.f;

  int nt = K >> 5;
  stage(0, 0);
  __syncthreads();
  int cur = 0;
  for (int t = 0; t < nt - 1; t++) {
    stage(cur ^ 1, t + 1);
    const unsigned short* as = smem + cur * (BM * 32);
    const unsigned short* bs = smem + 2 * BM * 32 + cur * (BN * 32);
    v8s a[WM], b[WN];
#pragma unroll
    for (int m = 0; m < WM; m++)
      a[m] = *(const v8s*)(as + (wr * (BM / 2) + m * 16 + l15) * 32 + l4 * 8);
#pragma unroll
    for (int n = 0; n < WN; n++)
      b[n] = *(const v8s*)(bs + (wc * (BN / 2) + n * 16 + l15) * 32 + l4 * 8);
#pragma unroll
    for (int m = 0; m < WM; m++)
#pragma unroll
      for (int n = 0; n < WN; n++)
        acc[m][n] = __builtin_amdgcn_mfma_f32_16x16x32_bf16(a[m], b[n], acc[m][n], 0, 0, 0);
    __syncthreads();
    cur ^= 1;
  }
  {
    const unsigned short* as = smem + cur * (BM * 32);
    const unsigned short* bs = smem + 2 * BM * 32 + cur * (BN * 32);
    v8s a[WM], b[WN];
#pragma unroll
    for (int m = 0; m < WM; m++)
      a[m] = *(const v8s*)(as + (wr * (BM / 2) + m * 16 + l15) * 32 + l4 * 8);
#pragma unroll
    for (int n = 0; n < WN; n++)
      b[n] = *(const v8s*)(bs + (wc * (BN / 2) + n * 16 + l15) * 32 + l4 * 8);
#pragma unroll
    for (int m = 0; m < WM; m++)
#pragma unroll
      for (int n = 0; n < WN; n++)
        acc[m][n] = __builtin_amdgcn_mfma_f32_16x16x32_bf16(a[m], b[n], acc[m][n], 0, 0, 0);
  }

  if constexpr (std::is_same<OutT, float>::value) {
#pragma unroll
    for (int m = 0; m < WM; m++) {
#pragma unroll
      for (int q2 = 0; q2 < 4; q2++) {
        int r2 = row0 + wr * (BM / 2) + m * 16 + l4 * 4 + q2;
        if (r2 >= M) continue;
#pragma unroll
        for (int n = 0; n < WN; n++) {
          int cc = col0 + wc * (BN / 2) + n * 16 + l15;
          if (cc >= N) continue;
          float v = acc[m][n][q2];
          if (bias) v += bias[cc];
          v = leakyf(v, slope);
          C[(size_t)r2 * ldc + cc] = v;
        }
      }
    }
  } else {
    // LDS-repack epilogue: vectorized bf16 stores (requires N % BN == 0)
    __syncthreads();
    float* rb = (float*)smem;
    for (int m = 0; m < WM; m++) {
#pragma unroll
      for (int n = 0; n < WN; n++)
#pragma unroll
        for (int q2 = 0; q2 < 4; q2++)
          rb[(wr * 16 + l4 * 4 + q2) * BN + wc * (BN / 2) + n * 16 + l15] = acc[m][n][q2];
      __syncthreads();
#pragma unroll
      for (int it = 0; it < (32 * BN) / 1024; it++) {
        int f = it * 1024 + tid * 4;
        int lr = f / BN, lc = f % BN;
        int rr = row0 + (lr >> 4) * (BM / 2) + m * 16 + (lr & 15);
        if (rr < M) {
          v4f vv = *(const v4f*)(rb + lr * BN + lc);
          v4s o;
#pragma unroll
          for (int j = 0; j < 4; j++) {
            float v = vv[j];
            if (bias) v += bias[col0 + lc + j];
            v = leakyf(v, slope);
            o[j] = (short)f2b(v);
          }
          *(v4s*)(C + (size_t)rr * ldc + col0 + lc) = o;
        }
      }
      __syncthreads();
    }
  }
}

// ---------------- conv tap-sum stencil: zin[:,512:640] = leaky(BN(bias + Σ_tap H[nbr,tap])) ----------------
__global__ void k_tapsum(const unsigned short* __restrict__ H,
                         const float* __restrict__ convb, const float* __restrict__ bng,
                         const float* __restrict__ bnb, unsigned short* __restrict__ zin) {
  int idx = blockIdx.x * blockDim.x + threadIdx.x;   // NPOS*16
  if (idx >= NPOS * 16) return;
  int r = idx >> 4, seg = idx & 15;
  int n0 = seg * 8;
  int b = r >> 13, pos = r & 8191, i = pos >> 7, j = pos & 127;
  float acc[8] = {0.f, 0.f, 0.f, 0.f, 0.f, 0.f, 0.f, 0.f};
#pragma unroll
  for (int tap = 0; tap < 9; tap++) {
    int di = tap / 3, dj = tap - di * 3;
    int rr = i + di, cc = j + dj;
    int gr, gc;
    if (rr == 0)       { gr = 1;      gc = (63 + cc) & 127; }
    else if (rr == 65) { gr = 62;     gc = (63 + cc) & 127; }
    else               { gr = rr - 1; gc = (cc + 127) & 127; }
    v8s v = *(const v8s*)(H + ((size_t)(b * 8192 + gr * WWW + gc)) * NTAPK + tap * 128 + n0);
#pragma unroll
    for (int q = 0; q < 8; q++) acc[q] += b2f((unsigned short)v[q]);
  }
  unsigned short* o = zin + (size_t)r * 640 + 512 + n0;
  v8s ov;
#pragma unroll
  for (int q = 0; q < 8; q++) {
    int cc = n0 + q;
    float v = acc[q] + convb[cc];
    v = v * (bng[cc] * rsqrtf(1.f + 1e-5f)) + bnb[cc];
    ov[q] = (short)f2b(leakyf(v, 0.01f));
  }
  *(v8s*)o = ov;
}

// ---------------- final: out[b,t,i,j] = z3[(b*8192+p), t] + x[b, 78+t, p] ----------------
__global__ void k_final(const float* __restrict__ z3, const float* __restrict__ x,
                        float* __restrict__ outp) {
  int idx = blockIdx.x * blockDim.x + threadIdx.x;
  if (idx >= NPOS * TGT) return;
  int b = idx / (TGT * 8192);
  int rem = idx - b * (TGT * 8192);
  int t = rem >> 13;
  int p = rem & 8191;
  outp[idx] = z3[((size_t)(b * 8192 + p)) * TGT + t] + x[((size_t)(b * 117 + 78 + t)) * 8192 + p];
}

// ================================================================
extern "C" void kernel_launch(void* const* d_in, const int* in_sizes, int n_in,
                              void* d_out, int out_size, void* d_ws, size_t ws_size,
                              hipStream_t stream) {
  const float* x     = (const float*)d_in[0];
  const float* xcons = (const float*)d_in[1];
  const int*   eidx  = (const int*)d_in[2];
  const float* eattr = (const float*)d_in[3];
  const float* g1W  = (const float*)d_in[4];
  const float* g1as = (const float*)d_in[5];
  const float* g1ad = (const float*)d_in[6];
  const float* g1We = (const float*)d_in[7];
  const float* g1ae = (const float*)d_in[8];
  const float* g1b  = (const float*)d_in[9];
  const float* g2W  = (const float*)d_in[10];
  const float* g2as = (const float*)d_in[11];
  const float* g2ad = (const float*)d_in[12];
  const float* g2We = (const float*)d_in[13];
  const float* g2ae = (const float*)d_in[14];
  const float* g2b  = (const float*)d_in[15];
  const float* convw= (const float*)d_in[16];
  const float* convb= (const float*)d_in[17];
  const float* bng  = (const float*)d_in[18];
  const float* bnb  = (const float*)d_in[19];
  const float* mw1  = (const float*)d_in[20];
  const float* mb1  = (const float*)d_in[21];
  const float* mw2  = (const float*)d_in[22];
  const float* mb2  = (const float*)d_in[23];
  const float* mw3  = (const float*)d_in[24];
  const float* mb3  = (const float*)d_in[25];
  float* outp = (float*)d_out;
  (void)in_sizes; (void)n_in; (void)out_size; (void)ws_size;

  const int* esrc = eidx;
  const int* edst = eidx + NE;

  char* basep = (char*)d_ws;
  size_t off = 0;
  auto alloc = [&](size_t bytes) -> void* {
    void* p = basep + off;
    off += (bytes + 255) & ~(size_t)255;
    return p;
  };
  unsigned short* nodesb = (unsigned short*)alloc((size_t)NNODE * 128 * 2);
  unsigned short* xpb    = (unsigned short*)alloc((size_t)NNODE * HC * 2);
  unsigned short* h1b    = (unsigned short*)alloc((size_t)NNODE * HC * 2);
  unsigned short* zin    = (unsigned short*)alloc((size_t)NPOS * 640 * 2);
  unsigned short* Hb     = (unsigned short*)alloc((size_t)NPOS * NTAPK * 2);
  float* asrc   = (float*)alloc((size_t)NNODE * 4 * sizeof(float));
  float* adst   = (float*)alloc((size_t)NNODE * 4 * sizeof(float));
  float* aedge1 = (float*)alloc((size_t)NE * 4 * sizeof(float));
  float* aedge2 = (float*)alloc((size_t)NE * 4 * sizeof(float));
  float* aeloop1= (float*)alloc((size_t)NNODE * 4 * sizeof(float));
  float* aeloop2= (float*)alloc((size_t)NNODE * 4 * sizeof(float));
  float* lattr  = (float*)alloc((size_t)NNODE * 8 * sizeof(float));
  float* M2     = (float*)alloc(64 * sizeof(float));
  unsigned short* g1Wt  = (unsigned short*)alloc((size_t)512 * 128 * 2);
  unsigned short* g2Wt  = (unsigned short*)alloc((size_t)512 * 512 * 2);
  unsigned short* convWt= (unsigned short*)alloc((size_t)NTAPK * 512 * 2);
  unsigned short* mw1t  = (unsigned short*)alloc((size_t)512 * 640 * 2);
  unsigned short* mw2t  = (unsigned short*)alloc((size_t)256 * 512 * 2);
  unsigned short* mw3t  = (unsigned short*)alloc((size_t)TGT * 256 * 2);
  int* cnt      = (int*)alloc((size_t)NNODE * sizeof(int));
  int* rowptr   = (int*)alloc((size_t)(NNODE + 1) * sizeof(int));
  int* cursor   = (int*)alloc((size_t)NNODE * sizeof(int));
  int* colidx   = (int*)alloc((size_t)NE * sizeof(int));
  unsigned short* z1b = xpb;             // xpb dead after GAT2 aggregation
  unsigned short* z2b = h1b;             // h1b dead after GAT2 xp GEMM
  float*          z3  = (float*)nodesb;  // nodesb dead after GAT1 xp GEMM

  hipMemsetAsync(cnt, 0, NNODE * sizeof(int), stream);
  k_build_nodes<<<NB * 128, 256, 0, stream>>>(x, xcons, nodesb);
  k_hist<<<ceildiv(NE, 256), 256, 0, stream>>>(edst, cnt);
  k_scan<<<1, 512, 0, stream>>>(cnt, rowptr, cursor, NNODE);
  k_scatter<<<ceildiv(NE, 256), 256, 0, stream>>>(edst, cursor, colidx);
  k_loop_attr<<<ceildiv(NNODE * 8, 256), 256, 0, stream>>>(eattr, rowptr, colidx, lattr);

  // fused prep: all weight transposes, both Medges, both layers' edge alphas
  k_prep<<<ceildiv(1386240, 256), 256, 0, stream>>>(g1W, g2W, convw, mw1, mw2, mw3,
                                                    g1Wt, g2Wt, convWt, mw1t, mw2t, mw3t);
  k_medge2<<<2, 64, 0, stream>>>(g1We, g1ae, g2We, g2ae, M2);
  k_aedge2<<<ceildiv((NE + NNODE) * 4, 256), 256, 0, stream>>>(
      eattr, lattr, M2, aedge1, aedge2, aeloop1, aeloop2);

  // ---- GAT layer 1 ----
  {
    dim3 g(4, ceildiv(NNODE, 128));
    mgemm<128, 128, unsigned short><<<g, 256, 0, stream>>>(
        NNODE, HC, 128, 128, nodesb, 128, g1Wt, nullptr, 1.0f, xpb, HC);
  }
  k_attn_dots<<<ceildiv(NNODE, 4), 256, 0, stream>>>(xpb, g1as, g1ad, asrc, adst);
  k_aggregate<<<ceildiv(NNODE, 4), 256, 0, stream>>>(xpb, asrc, adst, aedge1, aeloop1, esrc,
                                                     rowptr, colidx, g1b, h1b, HC, 0);

  // ---- GAT layer 2 (aggregation writes zin[:,0:512] directly, poles dropped) ----
  {
    dim3 g(4, ceildiv(NNODE, 128));
    mgemm<128, 128, unsigned short><<<g, 256, 0, stream>>>(
        NNODE, HC, HC, HC, h1b, HC, g2Wt, nullptr, 1.0f, xpb, HC);
  }
  k_attn_dots<<<ceildiv(NNODE, 4), 256, 0, stream>>>(xpb, g2as, g2ad, asrc, adst);
  k_aggregate<<<ceildiv(NNODE, 4), 256, 0, stream>>>(xpb, asrc, adst, aedge2, aeloop2, esrc,
                                                     rowptr, colidx, g2b, zin, 640, 1);

  // ---- conv as tap-major GEMM + stencil tap-sum ----
  {
    dim3 g(NTAPK / 128, ceildiv(NPOS, 128));   // 9 x 128 = 1152 blocks
    mgemm<128, 128, unsigned short><<<g, 256, 0, stream>>>(
        NPOS, NTAPK, 512, 512, zin, 640, convWt, nullptr, 1.0f, Hb, NTAPK);
  }
  k_tapsum<<<ceildiv(NPOS * 16, 256), 256, 0, stream>>>(Hb, convb, bng, bnb, zin);

  // ---- MLP ----
  {
    dim3 g(4, ceildiv(NPOS, 128));
    mgemm<128, 128, unsigned short><<<g, 256, 0, stream>>>(
        NPOS, 512, 640, 640, zin, 640, mw1t, mb1, 0.01f, z1b, 512);
  }
  {
    dim3 g(2, ceildiv(NPOS, 64));   // 512 blocks
    mgemm<64, 128, unsigned short><<<g, 256, 0, stream>>>(
        NPOS, 256, 512, 512, z1b, 512, mw2t, mb2, 0.01f, z2b, 256);
  }
  {
    dim3 g(1, ceildiv(NPOS, 64));   // 256 blocks
    mgemm<64, 64, float><<<g, 256, 0, stream>>>(
        NPOS, TGT, 256, 256, z2b, 256, mw3t, mb3, 1.0f, z3, TGT);
  }

  k_final<<<ceildiv(NPOS * TGT, 256), 256, 0, stream>>>(z3, x, outp);
}

// Round 12
// 303.397 us; speedup vs baseline: 5.9938x; 1.0030x over previous
//
#include <hip/hip_runtime.h>
#include <math.h>
#include <type_traits>

// ---- problem constants ----
#define NB    2
#define HHH   64
#define WWW   128
#define F1    123      // 117 + 6
#define HC    512      // heads*hid
#define NE    131072
#define PB    8194     // nodes per batch (8192 + 2 poles)
#define NNODE (NB*PB)  // 16388
#define NPOS  (NB*HHH*WWW) // 16384
#define TGT   39
#define EMBED 128
#define KCONV 4608     // 512*9
#define CSPLIT 3

static inline int ceildiv(int a, int b){ return (a + b - 1) / b; }

typedef short v8s __attribute__((ext_vector_type(8)));
typedef short v4s __attribute__((ext_vector_type(4)));
typedef float v4f __attribute__((ext_vector_type(4)));

__device__ __forceinline__ float leakyf(float x, float s){ return x >= 0.f ? x : s * x; }

__device__ __forceinline__ unsigned short f2b(float f) {
  unsigned u = __builtin_bit_cast(unsigned, f);
  u = (u + 0x7FFFu + ((u >> 16) & 1u)) >> 16;
  return (unsigned short)u;
}
__device__ __forceinline__ float b2f(unsigned short h) {
  unsigned u = ((unsigned)h) << 16;
  return __builtin_bit_cast(float, u);
}

// async global->LDS, 16 bytes per lane (dest = wave-uniform base + lane*16)
__device__ __forceinline__ void gload_lds16(const void* g, void* l) {
  __builtin_amdgcn_global_load_lds((const __attribute__((address_space(1))) void*)g,
                                   (__attribute__((address_space(3))) void*)l, 16, 0, 0);
}

// ---------------- build node features (bf16, K padded 123->128) ----------------
__global__ __launch_bounds__(256) void k_build_nodes(const float* __restrict__ x,
                                                     const float* __restrict__ xc,
                                                     unsigned short* __restrict__ nodes) {
  __shared__ unsigned short lds[64][130];
  int blk = blockIdx.x;             // NB*128 blocks
  int b = blk >> 7, p0 = (blk & 127) * 64;
  int tid = threadIdx.x;
  int pi = tid & 63, cg = tid >> 6;
  for (int c = cg; c < 128; c += 4) {
    float v = 0.f;
    int p = p0 + pi;
    if (c < 117)      v = x[((size_t)(b * 117 + c)) * 8192 + p];
    else if (c < 123) v = xc[((size_t)(b * 6 + (c - 117))) * 8192 + p];
    lds[pi][c] = f2b(v);
  }
  if ((blk & 127) == 0 && tid < 32) {
    int rr = tid >> 4, sg = tid & 15;
    *(v8s*)(nodes + ((size_t)(b * PB + rr)) * 128 + sg * 8) = (v8s)0;
  }
  __syncthreads();
  int seg = tid & 15, r0 = tid >> 4;
  for (int rr = r0; rr < 64; rr += 16) {
    int node = b * PB + 2 + p0 + rr;
    *(v8s*)(nodes + (size_t)node * 128 + seg * 8) = *(const v8s*)(&lds[rr][seg * 8]);
  }
}

// ---------------- CSR build ----------------
__global__ void k_hist(const int* __restrict__ dst, int* __restrict__ cnt) {
  int e = blockIdx.x * blockDim.x + threadIdx.x;
  if (e >= NE) return;
  atomicAdd(&cnt[dst[e]], 1);
}

__global__ void k_scan(const int* __restrict__ cnt, int* __restrict__ rowptr,
                       int* __restrict__ cursor, int n) {
  __shared__ int part[512];
  int t = threadIdx.x;
  int chunk = (n + 511) >> 9;
  int beg = t * chunk, end = min(beg + chunk, n);
  int s = 0;
  for (int i = beg; i < end; i++) s += cnt[i];
  part[t] = s;
  __syncthreads();
  int own = s;
  for (int off = 1; off < 512; off <<= 1) {
    int v = 0;
    if (t >= off) v = part[t - off];
    __syncthreads();
    part[t] += v;
    __syncthreads();
  }
  int run = part[t] - own;   // exclusive prefix
  for (int i = beg; i < end; i++) { rowptr[i] = run; cursor[i] = run; run += cnt[i]; }
  if (t == 511) rowptr[n] = part[511];
}

__global__ void k_scatter(const int* __restrict__ dst, int* __restrict__ cursor,
                          int* __restrict__ colidx) {
  int e = blockIdx.x * blockDim.x + threadIdx.x;
  if (e >= NE) return;
  int pos = atomicAdd(&cursor[dst[e]], 1);
  colidx[pos] = e;
}

// loop_attr[n][k] = mean over incoming edges of edge_attr (0-safe divide)
__global__ void k_loop_attr(const float* __restrict__ eattr, const int* __restrict__ rowptr,
                            const int* __restrict__ colidx, float* __restrict__ lattr) {
  int idx = blockIdx.x * blockDim.x + threadIdx.x;
  if (idx >= NNODE * 8) return;
  int nn = idx >> 3, k = idx & 7;
  int b = rowptr[nn], e = rowptr[nn + 1];
  float s = 0.f;
  for (int i = b; i < e; i++) s += eattr[(size_t)colidx[i] * 8 + k];
  int c = e - b;
  lattr[idx] = s / (float)max(c, 1);
}

// ---------------- fused weight prep (all 6 transposes in one launch) ----------------
// seg sizes: 65536, 262144, 589824, 327680, 131072, 9984  (total 1386240)
// convWt layout: bt[n][tap*512+c]  <- convw[n][c*9+tap]   (split-K friendly)
__global__ void k_prep(const float* __restrict__ g1W, const float* __restrict__ g2W,
                       const float* __restrict__ convw, const float* __restrict__ mw1,
                       const float* __restrict__ mw2, const float* __restrict__ mw3,
                       unsigned short* __restrict__ g1Wt, unsigned short* __restrict__ g2Wt,
                       unsigned short* __restrict__ convWt, unsigned short* __restrict__ mw1t,
                       unsigned short* __restrict__ mw2t, unsigned short* __restrict__ mw3t) {
  int idx = blockIdx.x * blockDim.x + threadIdx.x;
  if (idx < 65536) {                       // g1Wt[n][k], Kd=128, Ks=123, N=512
    int n = idx >> 7, k = idx & 127;
    g1Wt[idx] = (k < F1) ? f2b(g1W[(size_t)k * 512 + n]) : (unsigned short)0;
  } else if ((idx -= 65536) < 262144) {    // g2Wt[n][k], Kd=512
    int n = idx >> 9, k = idx & 511;
    g2Wt[idx] = f2b(g2W[(size_t)k * 512 + n]);
  } else if ((idx -= 262144) < 589824) {   // convWt[n][tap*512+c]
    int j = idx >> 9;                      // n*9 + tap
    int n = j / 9, tap = j - n * 9;
    int c = idx & 511;
    convWt[idx] = f2b(convw[(size_t)n * KCONV + c * 9 + tap]);
  } else if ((idx -= 589824) < 327680) {   // mw1t[n][k], Kd=640
    int n = idx / 640, k = idx - n * 640;
    mw1t[idx] = f2b(mw1[(size_t)k * 512 + n]);
  } else if ((idx -= 327680) < 131072) {   // mw2t[n][k], Kd=512
    int n = idx >> 9, k = idx & 511;
    mw2t[idx] = f2b(mw2[(size_t)k * 256 + n]);
  } else if ((idx -= 131072) < 9984) {     // mw3t[n][k], Kd=256, N=39
    int n = idx >> 8, k = idx & 255;
    mw3t[idx] = f2b(mw3[(size_t)k * TGT + n]);
  }
}

// ---------------- both layers' Medge in one launch: M2[layer*32 + k*4+h] ----------------
__global__ void k_medge2(const float* __restrict__ We1, const float* __restrict__ ae1,
                         const float* __restrict__ We2, const float* __restrict__ ae2,
                         float* __restrict__ M2) {
  int t = threadIdx.x;
  if (t >= 32) return;
  const float* We = blockIdx.x ? We2 : We1;
  const float* ae = blockIdx.x ? ae2 : ae1;
  int k = t >> 2, h = t & 3;
  float s = 0.f;
  for (int c = 0; c < 128; c++) s += We[k * 512 + h * 128 + c] * ae[h * 128 + c];
  M2[blockIdx.x * 32 + t] = s;
}

// ---------------- both layers' edge-alpha (edges + self-loops) in one pass ----------------
__global__ void k_aedge2(const float* __restrict__ eattr, const float* __restrict__ lattr,
                         const float* __restrict__ M2,
                         float* __restrict__ ae1, float* __restrict__ ae2,
                         float* __restrict__ al1, float* __restrict__ al2) {
  int idx = blockIdx.x * blockDim.x + threadIdx.x;
  if (idx >= (NE + NNODE) * 4) return;
  int e = idx >> 2, h = idx & 3;
  const float* src;
  float *o1, *o2;
  if (e < NE) { src = eattr + (size_t)e * 8; o1 = ae1 + idx; o2 = ae2 + idx; }
  else {
    int n = e - NE;
    src = lattr + (size_t)n * 8;
    o1 = al1 + n * 4 + h; o2 = al2 + n * 4 + h;
  }
  float s1 = 0.f, s2 = 0.f;
#pragma unroll
  for (int k = 0; k < 8; k++) {
    float a = src[k];
    s1 += a * M2[k * 4 + h];
    s2 += a * M2[32 + k * 4 + h];
  }
  *o1 = s1; *o2 = s2;
}

// a_src[n,h] = xp[n,h,:].att_src[h,:] from bf16 xp — one wave per node, 16B loads
__global__ void k_attn_dots(const unsigned short* __restrict__ xp, const float* __restrict__ as,
                            const float* __restrict__ ad, float* __restrict__ a_src,
                            float* __restrict__ a_dst) {
  int gw = (blockIdx.x * blockDim.x + threadIdx.x) >> 6;
  int lane = threadIdx.x & 63;
  if (gw >= NNODE) return;
  int h = lane >> 4;
  int c0 = (lane & 15) * 8;
  v8s v = *(const v8s*)(xp + (size_t)gw * HC + h * 128 + c0);
  const float* asr = as + h * 128 + c0;
  const float* adr = ad + h * 128 + c0;
  float s1 = 0.f, s2 = 0.f;
#pragma unroll
  for (int i = 0; i < 8; i++) {
    float f = b2f((unsigned short)v[i]);
    s1 += f * asr[i]; s2 += f * adr[i];
  }
  for (int off = 1; off < 16; off <<= 1) { s1 += __shfl_xor(s1, off); s2 += __shfl_xor(s2, off); }
  if ((lane & 15) == 0) { a_src[gw * 4 + h] = s1; a_dst[gw * 4 + h] = s2; }
}

// ---------------- GAT aggregation v4: one WAVE per node, 4-edge-batched gather ----------------
__global__ __launch_bounds__(256) void k_aggregate(
    const unsigned short* __restrict__ xp, const float* __restrict__ a_src,
    const float* __restrict__ a_dst, const float* __restrict__ a_edge,
    const float* __restrict__ a_eloop, const int* __restrict__ srcv,
    const int* __restrict__ rowptr, const int* __restrict__ colidx,
    const float* __restrict__ bias, unsigned short* __restrict__ outp,
    int ldo, int pole) {
  int wid = threadIdx.x >> 6, lane = threadIdx.x & 63;
  int n = blockIdx.x * 4 + wid;
  if (n >= NNODE) return;
  if (pole) {
    int b = n / PB, loc = n - b * PB;
    if (loc < 2) return;
    outp += (size_t)(b * 8192 + loc - 2) * ldo;
  } else {
    outp += (size_t)n * ldo;
  }
  int beg = rowptr[n], deg = rowptr[n + 1] - beg;
  int total = deg + 1;          // + self loop
  int ha = lane & 3;            // alpha-role head
  int ea = lane >> 2;           // alpha-role edge slot (0..15)
  int hh = lane >> 4;           // gather-role head
  int c0 = lane * 8;            // gather-role channels
  float adn = a_dst[(size_t)n * 4 + ha];
  float m0 = -1e30f, m1 = -1e30f, m2 = -1e30f, m3 = -1e30f;
  float l0 = 0.f, l1 = 0.f, l2 = 0.f, l3 = 0.f;
  float acc[8] = {0.f, 0.f, 0.f, 0.f, 0.f, 0.f, 0.f, 0.f};
  for (int base = 0; base < total; base += 16) {
    int cnt = min(16, total - base);
    int ge = base + ea;
    int sn = n;
    float al = -1e30f;
    if (ea < cnt) {
      float aev;
      if (ge < deg) { int eid = colidx[beg + ge]; sn = srcv[eid]; aev = a_edge[(size_t)eid * 4 + ha]; }
      else          { aev = a_eloop[(size_t)n * 4 + ha]; }
      al = leakyf(a_src[(size_t)sn * 4 + ha] + adn + aev, 0.2f);
    }
    float cm = al;
    cm = fmaxf(cm, __shfl_xor(cm, 4));
    cm = fmaxf(cm, __shfl_xor(cm, 8));
    cm = fmaxf(cm, __shfl_xor(cm, 16));
    cm = fmaxf(cm, __shfl_xor(cm, 32));
    float cm0 = __shfl(cm, 0), cm1 = __shfl(cm, 1), cm2 = __shfl(cm, 2), cm3 = __shfl(cm, 3);
    float nm0 = fmaxf(m0, cm0), nm1 = fmaxf(m1, cm1), nm2 = fmaxf(m2, cm2), nm3 = fmaxf(m3, cm3);
    float r0 = __expf(m0 - nm0), r1 = __expf(m1 - nm1), r2 = __expf(m2 - nm2), r3 = __expf(m3 - nm3);
    float nmh = ha == 0 ? nm0 : ha == 1 ? nm1 : ha == 2 ? nm2 : nm3;
    float ex = (ea < cnt) ? __expf(al - nmh) : 0.f;
    float s = ex;
    s += __shfl_xor(s, 4);
    s += __shfl_xor(s, 8);
    s += __shfl_xor(s, 16);
    s += __shfl_xor(s, 32);
    float s0 = __shfl(s, 0), s1 = __shfl(s, 1), s2 = __shfl(s, 2), s3 = __shfl(s, 3);
    l0 = l0 * r0 + s0; l1 = l1 * r1 + s1; l2 = l2 * r2 + s2; l3 = l3 * r3 + s3;
    m0 = nm0; m1 = nm1; m2 = nm2; m3 = nm3;
    float rh = hh == 0 ? r0 : hh == 1 ? r1 : hh == 2 ? r2 : r3;
#pragma unroll
    for (int j = 0; j < 8; j++) acc[j] *= rh;
    // gather: 4-edge batches — 4 independent 16B loads in flight (uniform branch)
    for (int e0 = 0; e0 < cnt; e0 += 4) {
      int nb = min(4, cnt - e0);
      v8s vv[4]; float wt[4];
#pragma unroll
      for (int u = 0; u < 4; u++) {
        if (u < nb) {
          int e = e0 + u;
          wt[u] = __shfl(ex, e * 4 + hh);
          int se = __shfl(sn, e * 4);
          vv[u] = *(const v8s*)(xp + (size_t)se * HC + c0);
        }
      }
#pragma unroll
      for (int u = 0; u < 4; u++) {
        if (u < nb) {
#pragma unroll
          for (int j = 0; j < 8; j++) acc[j] += wt[u] * b2f((unsigned short)vv[u][j]);
        }
      }
    }
  }
  float lh = hh == 0 ? l0 : hh == 1 ? l1 : hh == 2 ? l2 : l3;
  float inv = 1.f / lh;
  v8s o;
#pragma unroll
  for (int j = 0; j < 8; j++) {
    float v = acc[j] * inv + bias[c0 + j];
    o[j] = (short)f2b(leakyf(v, 0.01f));
  }
  *(v8s*)(outp + c0) = o;
}

// ---------------- bf16 MFMA GEMM: XCD swizzle + hoisted staging ptrs + LDS-repack epilogue ----------------
template<int BM, int BN, typename OutT>
__global__ __launch_bounds__(256) void mgemm(
    int M, int N, int K, int ldb,
    const unsigned short* __restrict__ A, int lda,
    const unsigned short* __restrict__ Bt,
    const float* __restrict__ bias,
    float slope,
    OutT* __restrict__ C, int ldc)
{
  constexpr int WM = BM / 32;
  constexpr int WN = BN / 32;
  constexpr int NA = BM * 4 / 256;
  constexpr int NBC = BN * 4 / 256;
  constexpr int STAGE_USH = 2 * (BM + BN) * 32;
  constexpr int REPACK_USH = 32 * BN * 2;
  constexpr int SMEM_USH = STAGE_USH > REPACK_USH ? STAGE_USH : REPACK_USH;
  __shared__ unsigned short smem[SMEM_USH];
  int tid = threadIdx.x;
  int wid = tid >> 6, lane = tid & 63;
  int wr = wid >> 1, wc = wid & 1;
  int l15 = lane & 15, l4 = lane >> 4;

  // --- XCD swizzle (bijective for any nwg, m204) ---
  int gx = gridDim.x;
  int nwg = gx * gridDim.y;
  int slot = blockIdx.x + blockIdx.y * gx;
  int qv = nwg >> 3, rv = nwg & 7;
  int xcd = slot & 7, pos = slot >> 3;
  int wg = (xcd < rv ? xcd * (qv + 1) : rv * (qv + 1) + (xcd - rv) * qv) + pos;
  int bx = wg % gx, by = wg / gx;
  int row0 = by * BM, col0 = bx * BN;

  // --- hoisted per-thread staging source pointers ---
  const unsigned short* pa[NA];
  const unsigned short* pb[NBC];
#pragma unroll
  for (int i = 0; i < NA; i++) {
    int c = i * 256 + tid, r2 = c >> 2, seg = c & 3;
    pa[i] = A + (size_t)min(row0 + r2, M - 1) * lda + seg * 8;
  }
#pragma unroll
  for (int i = 0; i < NBC; i++) {
    int c = i * 256 + tid, r2 = c >> 2, seg = c & 3;
    pb[i] = Bt + (size_t)min(col0 + r2, N - 1) * ldb + seg * 8;
  }

  auto stage = [&](int buf, int kt) {
    int k0 = kt * 32;
    unsigned short* as = smem + buf * (BM * 32);
    unsigned short* bs = smem + 2 * BM * 32 + buf * (BN * 32);
#pragma unroll
    for (int i = 0; i < NA; i++)
      gload_lds16(pa[i] + k0, as + (i * 256 + tid) * 8);
#pragma unroll
    for (int i = 0; i < NBC; i++)
      gload_lds16(pb[i] + k0, bs + (i * 256 + tid) * 8);
  };

  v4f acc[WM][WN];
#pragma unroll
  for (int m = 0; m < WM; m++)
#pragma unroll
    for (int n = 0; n < WN; n++) acc[m][n] = (v4f)0.f;

  int nt = K >> 5;
  stage(0, 0);
  __syncthreads();
  int cur = 0;
  for (int t = 0; t < nt - 1; t++) {
    stage(cur ^ 1, t + 1);
    const unsigned short* as = smem + cur * (BM * 32);
    const unsigned short* bs = smem + 2 * BM * 32 + cur * (BN * 32);
    v8s a[WM], b[WN];
#pragma unroll
    for (int m = 0; m < WM; m++)
      a[m] = *(const v8s*)(as + (wr * (BM / 2) + m * 16 + l15) * 32 + l4 * 8);
#pragma unroll
    for (int n = 0; n < WN; n++)
      b[n] = *(const v8s*)(bs + (wc * (BN / 2) + n * 16 + l15) * 32 + l4 * 8);
#pragma unroll
    for (int m = 0; m < WM; m++)
#pragma unroll
      for (int n = 0; n < WN; n++)
        acc[m][n] = __builtin_amdgcn_mfma_f32_16x16x32_bf16(a[m], b[n], acc[m][n], 0, 0, 0);
    __syncthreads();
    cur ^= 1;
  }
  {
    const unsigned short* as = smem + cur * (BM * 32);
    const unsigned short* bs = smem + 2 * BM * 32 + cur * (BN * 32);
    v8s a[WM], b[WN];
#pragma unroll
    for (int m = 0; m < WM; m++)
      a[m] = *(const v8s*)(as + (wr * (BM / 2) + m * 16 + l15) * 32 + l4 * 8);
#pragma unroll
    for (int n = 0; n < WN; n++)
      b[n] = *(const v8s*)(bs + (wc * (BN / 2) + n * 16 + l15) * 32 + l4 * 8);
#pragma unroll
    for (int m = 0; m < WM; m++)
#pragma unroll
      for (int n = 0; n < WN; n++)
        acc[m][n] = __builtin_amdgcn_mfma_f32_16x16x32_bf16(a[m], b[n], acc[m][n], 0, 0, 0);
  }

  if constexpr (std::is_same<OutT, float>::value) {
#pragma unroll
    for (int m = 0; m < WM; m++) {
#pragma unroll
      for (int q2 = 0; q2 < 4; q2++) {
        int r2 = row0 + wr * (BM / 2) + m * 16 + l4 * 4 + q2;
        if (r2 >= M) continue;
#pragma unroll
        for (int n = 0; n < WN; n++) {
          int cc = col0 + wc * (BN / 2) + n * 16 + l15;
          if (cc >= N) continue;
          float v = acc[m][n][q2];
          if (bias) v += bias[cc];
          v = leakyf(v, slope);
          C[(size_t)r2 * ldc + cc] = v;
        }
      }
    }
  } else {
    // LDS-repack epilogue: vectorized bf16 stores (requires N % BN == 0)
    __syncthreads();
    float* rb = (float*)smem;
    for (int m = 0; m < WM; m++) {
#pragma unroll
      for (int n = 0; n < WN; n++)
#pragma unroll
        for (int q2 = 0; q2 < 4; q2++)
          rb[(wr * 16 + l4 * 4 + q2) * BN + wc * (BN / 2) + n * 16 + l15] = acc[m][n][q2];
      __syncthreads();
#pragma unroll
      for (int it = 0; it < (32 * BN) / 1024; it++) {
        int f = it * 1024 + tid * 4;
        int lr = f / BN, lc = f % BN;
        int rr = row0 + (lr >> 4) * (BM / 2) + m * 16 + (lr & 15);
        if (rr < M) {
          v4f vv = *(const v4f*)(rb + lr * BN + lc);
          v4s o;
#pragma unroll
          for (int j = 0; j < 4; j++) {
            float v = vv[j];
            if (bias) v += bias[col0 + lc + j];
            v = leakyf(v, slope);
            o[j] = (short)f2b(v);
          }
          *(v4s*)(C + (size_t)rr * ldc + col0 + lc) = o;
        }
      }
      __syncthreads();
    }
  }
}

// ---------------- conv split-K implicit-im2col GEMM, direct from zin ----------------
// grid (3, 256): chunk = 3 taps (di = chunk, dj = 0..2), BM=64, BN=128, K=1536/chunk.
// A row p -> zin row nbr(p, tap) with pole/wrap (identical formulas to validated k_lm).
// Output: cpart[chunk][NPOS][128] fp32, reduced by k_creduce.
__global__ __launch_bounds__(256) void cgemm(
    const unsigned short* __restrict__ zin,
    const unsigned short* __restrict__ Wt,   // convWt [128][4608], k = tap*512+c
    float* __restrict__ C)
{
  constexpr int BM = 64, BN = 128, WM = 2, WN = 4;
  __shared__ unsigned short smem[2 * (BM + BN) * 32];
  int tid = threadIdx.x;
  int wid = tid >> 6, lane = tid & 63;
  int wr = wid >> 1, wc = wid & 1;
  int l15 = lane & 15, l4 = lane >> 4;

  // XCD swizzle: adjacent wg (x-fastest) -> same XCD; 3 chunks of a row tile co-locate.
  int gx = gridDim.x;                 // 3
  int nwg = gx * gridDim.y;           // 768
  int slot = blockIdx.x + blockIdx.y * gx;
  int qv = nwg >> 3, rv = nwg & 7;
  int xcd = slot & 7, pos = slot >> 3;
  int wg = (xcd < rv ? xcd * (qv + 1) : rv * (qv + 1) + (xcd - rv) * qv) + pos;
  int chunk = wg % gx, by = wg / gx;
  int row0 = by * BM;

  // A pointers: thread owns (r2, seg); one pointer per local tap (named, rule #20)
  int r2 = tid >> 2, seg = tid & 3;
  int p = row0 + r2;
  int b = p >> 13, pos2 = p & 8191, ii = pos2 >> 7, jj = pos2 & 127;
  int rr = ii + chunk;                // di = chunk
  auto mk = [&](int dj) -> const unsigned short* {
    int cc2 = jj + dj;
    int gr, gc;
    if (rr == 0)       { gr = 1;      gc = (63 + cc2) & 127; }
    else if (rr == 65) { gr = 62;     gc = (63 + cc2) & 127; }
    else               { gr = rr - 1; gc = (cc2 + 127) & 127; }
    return zin + ((size_t)(b * 8192 + gr * WWW + gc)) * 640 + seg * 8;
  };
  const unsigned short* pa0 = mk(0);
  const unsigned short* pa1 = mk(1);
  const unsigned short* pa2 = mk(2);
  // B pointers (2 chunks per thread)
  const unsigned short* pb0;
  const unsigned short* pb1;
  {
    int c = tid, rb2 = c >> 2, sb = c & 3;
    pb0 = Wt + (size_t)rb2 * KCONV + chunk * 1536 + sb * 8;
    c = 256 + tid; rb2 = c >> 2; sb = c & 3;
    pb1 = Wt + (size_t)rb2 * KCONV + chunk * 1536 + sb * 8;
  }

  auto stage = [&](int buf, int kt) {
    int k0 = kt * 32;                        // local K in [0,1536)
    int tl = k0 >> 9, coff = k0 & 511;
    const unsigned short* pA = tl == 0 ? pa0 : (tl == 1 ? pa1 : pa2);
    unsigned short* as = smem + buf * (BM * 32);
    unsigned short* bs = smem + 2 * BM * 32 + buf * (BN * 32);
    gload_lds16(pA + coff, as + tid * 8);
    gload_lds16(pb0 + k0, bs + tid * 8);
    gload_lds16(pb1 + k0, bs + (256 + tid) * 8);
  };

  v4f acc[WM][WN];
#pragma unroll
  for (int m = 0; m < WM; m++)
#pragma unroll
    for (int n = 0; n < WN; n++) acc[m][n] = (v4f)0.f;

  constexpr int nt = 48;                     // 1536/32
  stage(0, 0);
  __syncthreads();
  int cur = 0;
  for (int t = 0; t < nt - 1; t++) {
    stage(cur ^ 1, t + 1);
    const unsigned short* as = smem + cur * (BM * 32);
    const unsigned short* bs = smem + 2 * BM * 32 + cur * (BN * 32);
    v8s a[WM], b[WN];
#pragma unroll
    for (int m = 0; m < WM; m++)
      a[m] = *(const v8s*)(as + (wr * 32 + m * 16 + l15) * 32 + l4 * 8);
#pragma unroll
    for (int n = 0; n < WN; n++)
      b[n] = *(const v8s*)(bs + (wc * 64 + n * 16 + l15) * 32 + l4 * 8);
#pragma unroll
    for (int m = 0; m < WM; m++)
#pragma unroll
      for (int n = 0; n < WN; n++)
        acc[m][n] = __builtin_amdgcn_mfma_f32_16x16x32_bf16(a[m], b[n], acc[m][n], 0, 0, 0);
    __syncthreads();
    cur ^= 1;
  }
  {
    const unsigned short* as = smem + cur * (BM * 32);
    const unsigned short* bs = smem + 2 * BM * 32 + cur * (BN * 32);
    v8s a[WM], b[WN];
#pragma unroll
    for (int m = 0; m < WM; m++)
      a[m] = *(const v8s*)(as + (wr * 32 + m * 16 + l15) * 32 + l4 * 8);
#pragma unroll
    for (int n = 0; n < WN; n++)
      b[n] = *(const v8s*)(bs + (wc * 64 + n * 16 + l15) * 32 + l4 * 8);
#pragma unroll
    for (int m = 0; m < WM; m++)
#pragma unroll
      for (int n = 0; n < WN; n++)
        acc[m][n] = __builtin_amdgcn_mfma_f32_16x16x32_bf16(a[m], b[n], acc[m][n], 0, 0, 0);
  }
  float* Cc = C + (size_t)chunk * NPOS * 128;
#pragma unroll
  for (int m = 0; m < WM; m++) {
#pragma unroll
    for (int q2 = 0; q2 < 4; q2++) {
      int rw = row0 + wr * 32 + m * 16 + l4 * 4 + q2;
#pragma unroll
      for (int n = 0; n < WN; n++) {
        int cc = wc * 64 + n * 16 + l15;
        Cc[(size_t)rw * 128 + cc] = acc[m][n][q2];
      }
    }
  }
}

// ---------------- conv split-K reduce: sum partials + bias + BN + leaky -> zin[:,512:640] ----------------
__global__ void k_creduce(const float* __restrict__ p, const float* __restrict__ convb,
                          const float* __restrict__ bng, const float* __restrict__ bnb,
                          unsigned short* __restrict__ zin) {
  int idx = blockIdx.x * blockDim.x + threadIdx.x;   // over NPOS*32 (x4 floats)
  if (idx >= NPOS * 32) return;
  int r = idx >> 5, c4 = (idx & 31) * 4;
  const float4* p0 = (const float4*)(p + (size_t)r * 128 + c4);
  const float4* p1 = (const float4*)(p + (size_t)(NPOS + r) * 128 + c4);
  const float4* p2 = (const float4*)(p + (size_t)(2 * NPOS + r) * 128 + c4);
  float4 a = *p0, b = *p1, c = *p2;
  unsigned short* o = zin + (size_t)r * 640 + 512 + c4;
#pragma unroll
  for (int j = 0; j < 4; j++) {
    float v = ((const float*)&a)[j] + ((const float*)&b)[j] + ((const float*)&c)[j];
    int cc = c4 + j;
    v += convb[cc];
    v = v * (bng[cc] * rsqrtf(1.f + 1e-5f)) + bnb[cc];
    o[j] = f2b(leakyf(v, 0.01f));
  }
}

// ---------------- final: out[b,t,i,j] = z3[(b*8192+p), t] + x[b, 78+t, p] ----------------
__global__ void k_final(const float* __restrict__ z3, const float* __restrict__ x,
                        float* __restrict__ outp) {
  int idx = blockIdx.x * blockDim.x + threadIdx.x;
  if (idx >= NPOS * TGT) return;
  int b = idx / (TGT * 8192);
  int rem = idx - b * (TGT * 8192);
  int t = rem >> 13;
  int p = rem & 8191;
  outp[idx] = z3[((size_t)(b * 8192 + p)) * TGT + t] + x[((size_t)(b * 117 + 78 + t)) * 8192 + p];
}

// ================================================================
extern "C" void kernel_launch(void* const* d_in, const int* in_sizes, int n_in,
                              void* d_out, int out_size, void* d_ws, size_t ws_size,
                              hipStream_t stream) {
  const float* x     = (const float*)d_in[0];
  const float* xcons = (const float*)d_in[1];
  const int*   eidx  = (const int*)d_in[2];
  const float* eattr = (const float*)d_in[3];
  const float* g1W  = (const float*)d_in[4];
  const float* g1as = (const float*)d_in[5];
  const float* g1ad = (const float*)d_in[6];
  const float* g1We = (const float*)d_in[7];
  const float* g1ae = (const float*)d_in[8];
  const float* g1b  = (const float*)d_in[9];
  const float* g2W  = (const float*)d_in[10];
  const float* g2as = (const float*)d_in[11];
  const float* g2ad = (const float*)d_in[12];
  const float* g2We = (const float*)d_in[13];
  const float* g2ae = (const float*)d_in[14];
  const float* g2b  = (const float*)d_in[15];
  const float* convw= (const float*)d_in[16];
  const float* convb= (const float*)d_in[17];
  const float* bng  = (const float*)d_in[18];
  const float* bnb  = (const float*)d_in[19];
  const float* mw1  = (const float*)d_in[20];
  const float* mb1  = (const float*)d_in[21];
  const float* mw2  = (const float*)d_in[22];
  const float* mb2  = (const float*)d_in[23];
  const float* mw3  = (const float*)d_in[24];
  const float* mb3  = (const float*)d_in[25];
  float* outp = (float*)d_out;
  (void)in_sizes; (void)n_in; (void)out_size; (void)ws_size;

  const int* esrc = eidx;
  const int* edst = eidx + NE;

  char* basep = (char*)d_ws;
  size_t off = 0;
  auto alloc = [&](size_t bytes) -> void* {
    void* p = basep + off;
    off += (bytes + 255) & ~(size_t)255;
    return p;
  };
  unsigned short* nodesb = (unsigned short*)alloc((size_t)NNODE * 128 * 2);
  unsigned short* xpb    = (unsigned short*)alloc((size_t)NNODE * HC * 2);
  unsigned short* h1b    = (unsigned short*)alloc((size_t)NNODE * HC * 2);
  unsigned short* zin    = (unsigned short*)alloc((size_t)NPOS * 640 * 2);
  float* cpart  = (float*)alloc((size_t)CSPLIT * NPOS * 128 * sizeof(float));
  float* asrc   = (float*)alloc((size_t)NNODE * 4 * sizeof(float));
  float* adst   = (float*)alloc((size_t)NNODE * 4 * sizeof(float));
  float* aedge1 = (float*)alloc((size_t)NE * 4 * sizeof(float));
  float* aedge2 = (float*)alloc((size_t)NE * 4 * sizeof(float));
  float* aeloop1= (float*)alloc((size_t)NNODE * 4 * sizeof(float));
  float* aeloop2= (float*)alloc((size_t)NNODE * 4 * sizeof(float));
  float* lattr  = (float*)alloc((size_t)NNODE * 8 * sizeof(float));
  float* M2     = (float*)alloc(64 * sizeof(float));
  unsigned short* g1Wt  = (unsigned short*)alloc((size_t)512 * 128 * 2);
  unsigned short* g2Wt  = (unsigned short*)alloc((size_t)512 * 512 * 2);
  unsigned short* convWt= (unsigned short*)alloc((size_t)EMBED * KCONV * 2);
  unsigned short* mw1t  = (unsigned short*)alloc((size_t)512 * 640 * 2);
  unsigned short* mw2t  = (unsigned short*)alloc((size_t)256 * 512 * 2);
  unsigned short* mw3t  = (unsigned short*)alloc((size_t)TGT * 256 * 2);
  int* cnt      = (int*)alloc((size_t)NNODE * sizeof(int));
  int* rowptr   = (int*)alloc((size_t)(NNODE + 1) * sizeof(int));
  int* cursor   = (int*)alloc((size_t)NNODE * sizeof(int));
  int* colidx   = (int*)alloc((size_t)NE * sizeof(int));
  unsigned short* z1b = xpb;             // xpb dead after GAT2 aggregation
  unsigned short* z2b = h1b;             // h1b dead after GAT2 xp GEMM
  float*          z3  = (float*)nodesb;  // nodesb dead after GAT1 xp GEMM

  hipMemsetAsync(cnt, 0, NNODE * sizeof(int), stream);
  k_build_nodes<<<NB * 128, 256, 0, stream>>>(x, xcons, nodesb);
  k_hist<<<ceildiv(NE, 256), 256, 0, stream>>>(edst, cnt);
  k_scan<<<1, 512, 0, stream>>>(cnt, rowptr, cursor, NNODE);
  k_scatter<<<ceildiv(NE, 256), 256, 0, stream>>>(edst, cursor, colidx);
  k_loop_attr<<<ceildiv(NNODE * 8, 256), 256, 0, stream>>>(eattr, rowptr, colidx, lattr);

  // fused prep: all weight transposes, both Medges, both layers' edge alphas
  k_prep<<<ceildiv(1386240, 256), 256, 0, stream>>>(g1W, g2W, convw, mw1, mw2, mw3,
                                                    g1Wt, g2Wt, convWt, mw1t, mw2t, mw3t);
  k_medge2<<<2, 64, 0, stream>>>(g1We, g1ae, g2We, g2ae, M2);
  k_aedge2<<<ceildiv((NE + NNODE) * 4, 256), 256, 0, stream>>>(
      eattr, lattr, M2, aedge1, aedge2, aeloop1, aeloop2);

  // ---- GAT layer 1 ----
  {
    dim3 g(4, ceildiv(NNODE, 128));
    mgemm<128, 128, unsigned short><<<g, 256, 0, stream>>>(
        NNODE, HC, 128, 128, nodesb, 128, g1Wt, nullptr, 1.0f, xpb, HC);
  }
  k_attn_dots<<<ceildiv(NNODE, 4), 256, 0, stream>>>(xpb, g1as, g1ad, asrc, adst);
  k_aggregate<<<ceildiv(NNODE, 4), 256, 0, stream>>>(xpb, asrc, adst, aedge1, aeloop1, esrc,
                                                     rowptr, colidx, g1b, h1b, HC, 0);

  // ---- GAT layer 2 (aggregation writes zin[:,0:512] directly, poles dropped) ----
  {
    dim3 g(4, ceildiv(NNODE, 128));
    mgemm<128, 128, unsigned short><<<g, 256, 0, stream>>>(
        NNODE, HC, HC, HC, h1b, HC, g2Wt, nullptr, 1.0f, xpb, HC);
  }
  k_attn_dots<<<ceildiv(NNODE, 4), 256, 0, stream>>>(xpb, g2as, g2ad, asrc, adst);
  k_aggregate<<<ceildiv(NNODE, 4), 256, 0, stream>>>(xpb, asrc, adst, aedge2, aeloop2, esrc,
                                                     rowptr, colidx, g2b, zin, 640, 1);

  // ---- conv: split-K implicit-im2col from zin, then reduce+BN+leaky ----
  {
    dim3 g(CSPLIT, NPOS / 64);   // 3 x 256 = 768 blocks
    cgemm<<<g, 256, 0, stream>>>(zin, convWt, cpart);
  }
  k_creduce<<<ceildiv(NPOS * 32, 256), 256, 0, stream>>>(cpart, convb, bng, bnb, zin);

  // ---- MLP ----
  {
    dim3 g(4, ceildiv(NPOS, 128));
    mgemm<128, 128, unsigned short><<<g, 256, 0, stream>>>(
        NPOS, 512, 640, 640, zin, 640, mw1t, mb1, 0.01f, z1b, 512);
  }
  {
    dim3 g(2, ceildiv(NPOS, 64));   // 512 blocks
    mgemm<64, 128, unsigned short><<<g, 256, 0, stream>>>(
        NPOS, 256, 512, 512, z1b, 512, mw2t, mb2, 0.01f, z2b, 256);
  }
  {
    dim3 g(1, ceildiv(NPOS, 64));   // 256 blocks
    mgemm<64, 64, float><<<g, 256, 0, stream>>>(
        NPOS, TGT, 256, 256, z2b, 256, mw3t, mb3, 1.0f, z3, TGT);
  }

  k_final<<<ceildiv(NPOS * TGT, 256), 256, 0, stream>>>(z3, x, outp);
}